// Round 2
// baseline (544.589 us; speedup 1.0000x reference)
//
#include <hip/hip_runtime.h>
#include <hip/hip_bf16.h>

// Problem constants
#define D_MODEL 1024
#define D_INNER 4096
#define D_STATE 16
#define D_CONV 4
#define DT_RANK 64
#define BATCH 2
#define SEQLEN 2048
#define MROWS (BATCH * SEQLEN)          // 4096
#define NPROJ (DT_RANK + 2 * D_STATE)   // 96
#define PST 128                         // proj row stride (padded, fp32)
#define NC 64                           // scan chunks (8 blocks/CU for latency hiding)
#define TC (SEQLEN / NC)                // 32 steps per chunk
#define KSPLIT 8                        // split-K for proj gemm
#define KSP6 4                          // split-K for out gemm

typedef unsigned short u16;
typedef unsigned int u32;
typedef __attribute__((ext_vector_type(8))) short short8;
typedef __attribute__((ext_vector_type(4))) float floatx4;

#define LOG2E 1.44269504089f

__device__ __forceinline__ float bf2f(u16 u) {
    union { u32 i; float f; } v; v.i = ((u32)u) << 16; return v.f;
}
__device__ __forceinline__ u16 f2bf(float f) {
    union { float f; u32 i; } v; v.f = f;
    u32 x = v.i;
    u32 r = x + 0x7fffu + ((x >> 16) & 1u);   // round to nearest even
    return (u16)(r >> 16);
}
// fast softplus: hardware exp/log; |err| << bf16 ulp for all finite x
__device__ __forceinline__ float softplus_fast(float x) {
    float l = __logf(1.f + __expf(-fabsf(x)));
    return x > 0.f ? x + l : l;
}
// fast sigmoid: v_exp + v_rcp (1 ulp), no exact-division sequence
__device__ __forceinline__ float sigmoid_fast(float x) {
    return __builtin_amdgcn_rcpf(1.f + __expf(-x));
}
// async global->LDS 16B DMA (dest = wave-uniform base + lane*16)
__device__ __forceinline__ void async_cp16(const u16* g, u16* l) {
    __builtin_amdgcn_global_load_lds((const __attribute__((address_space(1))) void*)g,
                                     (__attribute__((address_space(3))) void*)l, 16, 0, 0);
}

// ---------------------------------------------------------------------------
// D0: detect input dtype (bf16 vs fp32) from exponent-field statistics.
__global__ __launch_bounds__(256) void detect_dtype(const u16* __restrict__ x, int* __restrict__ flag) {
    __shared__ int cnt;
    if (threadIdx.x == 0) cnt = 0;
    __syncthreads();
    int local = 0;
    for (int k = 0; k < 16; k++) {
        int e = threadIdx.x * 8192 + k * 512;
        u16 v = x[2 * e];
        int ex = (v >> 7) & 0xFF;
        if (ex >= 0x68 && ex <= 0x8F) local++;
    }
    atomicAdd(&cnt, local);
    __syncthreads();
    if (threadIdx.x == 0) *flag = (cnt >= 2458) ? 1 : 0;
}

// ---------------------------------------------------------------------------
__global__ __launch_bounds__(256) void ingest16(const void* __restrict__ src, u16* __restrict__ dst,
                                                int n, const int* __restrict__ flag) {
    int i = blockIdx.x * 256 + threadIdx.x;
    if (i >= n) return;
    if (*flag) dst[i] = ((const u16*)src)[i];
    else       dst[i] = f2bf(((const float*)src)[i]);
}

// ---------------------------------------------------------------------------
// Fused small-tensor prologue: conv_w, conv_b, dt_proj_b, D ingest + A=-exp(A_log).
__global__ __launch_bounds__(256) void prep_small(const void* __restrict__ cw, const void* __restrict__ cb,
                                                  const void* __restrict__ dtb, const void* __restrict__ Dv,
                                                  const void* __restrict__ Alog,
                                                  u16* __restrict__ cw16, u16* __restrict__ cb16,
                                                  u16* __restrict__ dtb16, u16* __restrict__ D16,
                                                  float* __restrict__ A, const int* __restrict__ flag) {
    int i = blockIdx.x * 256 + threadIdx.x;   // grid covers 65536
    int isb = *flag;
    if (i < D_INNER * D_CONV)
        cw16[i] = isb ? ((const u16*)cw)[i] : f2bf(((const float*)cw)[i]);
    if (i < D_INNER) {
        cb16[i]  = isb ? ((const u16*)cb)[i]  : f2bf(((const float*)cb)[i]);
        dtb16[i] = isb ? ((const u16*)dtb)[i] : f2bf(((const float*)dtb)[i]);
        D16[i]   = isb ? ((const u16*)Dv)[i]  : f2bf(((const float*)Dv)[i]);
    }
    if (i < D_INNER * D_STATE) {
        float v = isb ? bf2f(((const u16*)Alog)[i]) : ((const float*)Alog)[i];
        A[i] = -expf(v);
    }
}

// ---------------------------------------------------------------------------
// Transpose-ingest: W [K][N] (dual dtype) -> WT [N][K] bf16.
__global__ __launch_bounds__(256) void transpose_w(const void* __restrict__ W, u16* __restrict__ WT,
                                                   int K, int N, const int* __restrict__ flag) {
    __shared__ float t[32][33];
    int k0 = blockIdx.y * 32, n0 = blockIdx.x * 32;
    int tid = threadIdx.x;
    int r = tid >> 3, c4 = (tid & 7) * 4;
    int isb = *flag;
    size_t base = (size_t)(k0 + r) * N + n0 + c4;
    float4 v;
    if (isb) { ushort4 u4 = *(const ushort4*)((const u16*)W + base);
               v = make_float4(bf2f(u4.x), bf2f(u4.y), bf2f(u4.z), bf2f(u4.w)); }
    else     { v = *(const float4*)((const float*)W + base); }
    t[c4 + 0][r] = v.x; t[c4 + 1][r] = v.y; t[c4 + 2][r] = v.z; t[c4 + 3][r] = v.w;
    __syncthreads();
    u16* o = WT + (size_t)(n0 + r) * K + k0 + c4;
    o[0] = f2bf(t[r][c4 + 0]);
    o[1] = f2bf(t[r][c4 + 1]);
    o[2] = f2bf(t[r][c4 + 2]);
    o[3] = f2bf(t[r][c4 + 3]);
}

// ---------------------------------------------------------------------------
// 256x256-tile 8-phase GEMM (HK-style schedule in plain HIP).
//
// A [M][KS] bf16 row-major, Bt [N][KS] bf16 row-major.
// 512 threads = 8 waves (2M x 4N); per-wave output 128x64, chunk-interleaved:
//   M-frag i: row = wr*64 + (i&3)*16 + (i>>2)*128  -> A-chunk (i>>2)
//   N-frag j: col = wc*32 + (j&1)*16 + (j>>1)*128  -> B-chunk (j>>1)
// K-tile = 64; each tile = 4 chunks (A0,A1,B0,B1) of 128x64 bf16 = 16 KB.
// Phase order per tile: (A0,B0) (A0,B1) (A1,B1) (A1,B0) — each phase reads at
// most one new chunk, stages one chunk of tile t+1 into the dead buffer, does
// 16 MFMA under setprio(1), then counted vmcnt + raw s_barrier (never vmcnt 0
// in the steady loop; ledger gives 4/4/6/4, epilogue drains 2/0).
// LDS reads XOR-swizzled (col ^= (row&7)*8 elems); global_load_lds dest stays
// linear, the *global source* is inverse-swizzled (both-sides rule, m173).
//
// MODE 0: C bf16, split to o0/o1 at col D_INNER (in-proj). KS=1024, grid 512,
//         bijective XCD swizzle. MODE 1: fp32 split-K partials Pp[z][M][1024]
//         (out-proj). KS=4096, grid (4,16,KSP6).
template<int KS, int MODE>
__global__ __launch_bounds__(512, 2) void gemm8p(const u16* __restrict__ A, const u16* __restrict__ Bt,
                                                 u16* __restrict__ o0, u16* __restrict__ o1,
                                                 float* __restrict__ Pp) {
    __shared__ __align__(16) u16 lds[65536];   // 128 KB: A = 2buf x 2chunk x 8192 u16; B at +32768
    const int tid = threadIdx.x;
    const int lane = tid & 63;
    const int wave = tid >> 6;
    const int wr = wave >> 2, wc = wave & 3;
    const int quad = lane >> 4, l15 = lane & 15;

    int m0, n0, kbase, kz;
    if (MODE == 0) {
        int wgid = (blockIdx.x & 7) * 64 + (blockIdx.x >> 3);   // bijective (512 % 8 == 0)
        m0 = (wgid & 15) * 256;
        n0 = (wgid >> 4) * 256;
        kbase = 0; kz = 0;
    } else {
        m0 = blockIdx.y * 256;
        n0 = blockIdx.x * 256;
        kz = blockIdx.z;
        kbase = kz * 1024;
    }
    const int NT = 1024 / 64;   // 16 k-tiles per block (both modes sweep 1024 of K)

    // ---- staging addressing: linear LDS dest, inverse-swizzled global source
    const int srow = tid >> 3;                              // 0..63 (chunk row, rho adds 64)
    const int kswz = (((tid & 7) ^ (srow & 7)) << 3);       // element offset within 64-wide k
    const u16* pA = A + (size_t)(m0 + srow) * KS + kbase + kswz;
    const u16* pB = Bt + (size_t)(n0 + srow) * KS + kbase + kswz;

    // ---- fragment-read addressing (swizzle term is per-thread constant)
    const int rsw = (l15 & 7) << 3;
    const int ksel0 = (quad * 8) ^ rsw;
    const int ksel1 = (32 + quad * 8) ^ rsw;
    const int aoff = (wr * 64 + l15) * 64;
    const int boff = (wc * 32 + l15) * 64;

    floatx4 acc[8][4];
#pragma unroll
    for (int i = 0; i < 8; i++)
#pragma unroll
        for (int j = 0; j < 4; j++) acc[i][j] = (floatx4)0.f;
    short8 af[4][2];        // current A-chunk frags [ii][ksub]
    short8 bf[2][2][2];     // both B-chunk frags    [chunk][jj][ksub]

#define STAGE_A(nb, h, kt) do { \
    const u16* g_ = pA + (size_t)(h) * 128 * KS + (kt) * 64; \
    u16* l_ = &lds[((nb) * 2 + (h)) * 8192 + tid * 8]; \
    async_cp16(g_, l_); \
    async_cp16(g_ + (size_t)64 * KS, l_ + 4096); \
} while (0)
#define STAGE_B(nb, h, kt) do { \
    const u16* g_ = pB + (size_t)(h) * 128 * KS + (kt) * 64; \
    u16* l_ = &lds[32768 + ((nb) * 2 + (h)) * 8192 + tid * 8]; \
    async_cp16(g_, l_); \
    async_cp16(g_ + (size_t)64 * KS, l_ + 4096); \
} while (0)
#define LOADA(b, h) do { \
    const u16* p_ = &lds[((b) * 2 + (h)) * 8192 + aoff]; \
    _Pragma("unroll") \
    for (int ii = 0; ii < 4; ii++) { \
        af[ii][0] = *(const short8*)(p_ + ii * 1024 + ksel0); \
        af[ii][1] = *(const short8*)(p_ + ii * 1024 + ksel1); \
    } \
} while (0)
#define LOADB(b, h) do { \
    const u16* p_ = &lds[32768 + ((b) * 2 + (h)) * 8192 + boff]; \
    _Pragma("unroll") \
    for (int jj = 0; jj < 2; jj++) { \
        bf[h][jj][0] = *(const short8*)(p_ + jj * 1024 + ksel0); \
        bf[h][jj][1] = *(const short8*)(p_ + jj * 1024 + ksel1); \
    } \
} while (0)
#define MFMAQ(qa, qb) do { \
    __builtin_amdgcn_s_setprio(1); \
    _Pragma("unroll") \
    for (int ii = 0; ii < 4; ii++) \
    _Pragma("unroll") \
    for (int jj = 0; jj < 2; jj++) { \
        floatx4 c_ = acc[(qa) * 4 + ii][(qb) * 2 + jj]; \
        c_ = __builtin_amdgcn_mfma_f32_16x16x32_bf16(af[ii][0], bf[qb][jj][0], c_, 0, 0, 0); \
        c_ = __builtin_amdgcn_mfma_f32_16x16x32_bf16(af[ii][1], bf[qb][jj][1], c_, 0, 0, 0); \
        acc[(qa) * 4 + ii][(qb) * 2 + jj] = c_; \
    } \
    __builtin_amdgcn_s_setprio(0); \
} while (0)
#define VMW(N) asm volatile("s_waitcnt vmcnt(" #N ")" ::: "memory")
#define BARX() do { __builtin_amdgcn_s_barrier(); asm volatile("" ::: "memory"); } while (0)

    // prologue: tile 0 -> buf 0, issue order [A0, B0, B1, A1]
    STAGE_A(0, 0, 0);
    STAGE_B(0, 0, 0);
    STAGE_B(0, 1, 0);
    STAGE_A(0, 1, 0);
    VMW(4); BARX();                 // A0,B0 resident; B1,A1 (4 loads) in flight

    for (int t = 0; t < NT - 1; ++t) {
        const int b = t & 1, nb = b ^ 1;
        // phase 0: quadrant (A0,B0); prefetch A0(t+1)
        LOADA(b, 0);
        LOADB(b, 0);
        STAGE_A(nb, 0, t + 1);
        MFMAQ(0, 0);
        VMW(4); BARX();             // forces B1(t) complete
        // phase 1: quadrant (A0,B1); prefetch B0(t+1)
        LOADB(b, 1);
        STAGE_B(nb, 0, t + 1);
        MFMAQ(0, 1);
        VMW(4); BARX();             // forces A1(t) complete
        // phase 2: quadrant (A1,B1); prefetch B1(t+1)
        LOADA(b, 1);
        STAGE_B(nb, 1, t + 1);
        MFMAQ(1, 1);
        VMW(6); BARX();             // nothing needed at phase 3; keep <=3 chunks in flight
        // phase 3: quadrant (A1,B0); prefetch A1(t+1)
        STAGE_A(nb, 1, t + 1);
        MFMAQ(1, 0);
        VMW(4); BARX();             // forces A0(t+1),B0(t+1) complete for next tile
    }
    {   // last k-tile: no stages, drain 2 -> 0
        const int b = (NT - 1) & 1;
        LOADA(b, 0);
        LOADB(b, 0);
        MFMAQ(0, 0);
        VMW(2); BARX();             // forces B1 complete
        LOADB(b, 1);
        MFMAQ(0, 1);
        VMW(0); BARX();             // forces A1 complete
        LOADA(b, 1);
        MFMAQ(1, 1);
        MFMAQ(1, 0);
    }

    if constexpr (MODE == 0) {
        (void)kz; (void)Pp;
        u16* d = (n0 < D_INNER) ? o0 : o1;
        const int nb0 = (n0 < D_INNER) ? n0 : n0 - D_INNER;
#pragma unroll
        for (int i = 0; i < 8; i++) {
            const int mrow = m0 + wr * 64 + (i & 3) * 16 + (i >> 2) * 128 + quad * 4;
#pragma unroll
            for (int j = 0; j < 4; j++) {
                const int ncol = nb0 + wc * 32 + (j & 1) * 16 + (j >> 1) * 128 + l15;
#pragma unroll
                for (int r = 0; r < 4; r++)
                    d[(size_t)(mrow + r) * D_INNER + ncol] = f2bf(acc[i][j][r]);
            }
        }
    } else {
        (void)o0; (void)o1;
        float* d = Pp + (size_t)kz * MROWS * D_MODEL;
#pragma unroll
        for (int i = 0; i < 8; i++) {
            const int mrow = m0 + wr * 64 + (i & 3) * 16 + (i >> 2) * 128 + quad * 4;
#pragma unroll
            for (int j = 0; j < 4; j++) {
                const int ncol = n0 + wc * 32 + (j & 1) * 16 + (j >> 1) * 128 + l15;
#pragma unroll
                for (int r = 0; r < 4; r++)
                    d[(size_t)(mrow + r) * D_MODEL + ncol] = acc[i][j][r];
            }
        }
    }
#undef STAGE_A
#undef STAGE_B
#undef LOADA
#undef LOADB
#undef MFMAQ
#undef VMW
#undef BARX
}

// ---------------------------------------------------------------------------
__global__ __launch_bounds__(256) void reduce_out(const float* __restrict__ Pp, void* __restrict__ out,
                                                  const int* __restrict__ flag) {
    int i = blockIdx.x * 256 + threadIdx.x;   // < MROWS*D_MODEL
    float s = 0.f;
#pragma unroll
    for (int z = 0; z < KSP6; z++) s += Pp[(size_t)z * MROWS * D_MODEL + i];
    if (*flag) ((u16*)out)[i] = f2bf(s);
    else       ((float*)out)[i] = s;
}

// ---------------------------------------------------------------------------
// K3: proj split-K MFMA.  A = xs [4096][4096], Bt = xpwT [128(pad)][4096].
__global__ __launch_bounds__(256) void gemm_proj(const u16* __restrict__ A, const u16* __restrict__ Bt,
                                                 float* __restrict__ Pp) {
    const int K = D_INNER;
    __shared__ __align__(16) u16 sA[128 * 32];
    __shared__ __align__(16) u16 sB[128 * 32];
    int tid = threadIdx.x;
    int lane = tid & 63;
    int wave = tid >> 6;
    int wm = (wave >> 1) * 64, wn = (wave & 1) * 64;
    int quad = lane >> 4, l15 = lane & 15;
    int m0 = blockIdx.y * 128;
    int kz = blockIdx.x;
    int kbase = kz * (K / KSPLIT);

    floatx4 acc[4][4];
#pragma unroll
    for (int i = 0; i < 4; i++)
#pragma unroll
        for (int j = 0; j < 4; j++) acc[i][j] = (floatx4)0.f;

    const u16* ga0 = A + (size_t)(m0 + (tid >> 2)) * K + (tid & 3) * 8;
    const u16* ga1 = A + (size_t)(m0 + 64 + (tid >> 2)) * K + (tid & 3) * 8;
    const u16* gb0 = Bt + (size_t)(tid >> 2) * K + (tid & 3) * 8;
    const u16* gb1 = Bt + (size_t)(64 + (tid >> 2)) * K + (tid & 3) * 8;
    u16* la0 = &sA[tid * 8];
    u16* la1 = &sA[(256 + tid) * 8];
    u16* lb0 = &sB[tid * 8];
    u16* lb1 = &sB[(256 + tid) * 8];

    for (int k0 = kbase; k0 < kbase + K / KSPLIT; k0 += 32) {
        async_cp16(ga0 + k0, la0);
        async_cp16(ga1 + k0, la1);
        async_cp16(gb0 + k0, lb0);
        async_cp16(gb1 + k0, lb1);
        __syncthreads();
        short8 af[4], bf[4];
#pragma unroll
        for (int i = 0; i < 4; i++) {
            af[i] = *(const short8*)&sA[(wm + i * 16 + l15) * 32 + quad * 8];
            bf[i] = *(const short8*)&sB[(wn + i * 16 + l15) * 32 + quad * 8];
        }
#pragma unroll
        for (int i = 0; i < 4; i++)
#pragma unroll
            for (int j = 0; j < 4; j++)
                acc[i][j] = __builtin_amdgcn_mfma_f32_16x16x32_bf16(af[i], bf[j], acc[i][j], 0, 0, 0);
        __syncthreads();
    }

    float* d = Pp + (size_t)kz * MROWS * PST;
#pragma unroll
    for (int i = 0; i < 4; i++)
#pragma unroll
        for (int j = 0; j < 4; j++)
#pragma unroll
            for (int r = 0; r < 4; r++) {
                int mm = m0 + wm + i * 16 + quad * 4 + r;
                int nn = wn + j * 16 + l15;
                d[(size_t)mm * PST + nn] = acc[i][j][r];
            }
}

// ---------------------------------------------------------------------------
// reduce split-K partials -> proj fp32 [4096][PST]; also emit proj_lo bf16.
__global__ __launch_bounds__(256) void reduce_proj(const float* __restrict__ Pp, float* __restrict__ proj,
                                                   u16* __restrict__ proj_lo) {
    int i = blockIdx.x * 256 + threadIdx.x;    // < MROWS*PST
    float s = 0.f;
#pragma unroll
    for (int z = 0; z < KSPLIT; z++) s += Pp[(size_t)z * MROWS * PST + i];
    proj[i] = s;
    int col = i & (PST - 1);
    if (col < DT_RANK) proj_lo[(size_t)(i >> 7) * DT_RANK + col] = f2bf(s);
}

// ---------------------------------------------------------------------------
// K4: dt = softplus(proj_lo @ dtwT^T + b) via MFMA.  M=4096, N=4096, K=64.
// Epilogue: fast softplus + LDS bounce (stride-132 pad) -> coalesced 16B stores.
__global__ __launch_bounds__(256) void gemm_dt(const u16* __restrict__ A, const u16* __restrict__ Bt,
                                               const u16* __restrict__ dtb, u16* __restrict__ dt) {
    const int K = DT_RANK;   // 64
    __shared__ __align__(16) u16 smem[64 * 132];   // 16.9 KB; k-loop uses first 16 KB
    u16* sA = smem;
    u16* sB = smem + 128 * 32;
    int tid = threadIdx.x;
    int lane = tid & 63;
    int wave = tid >> 6;
    int wm = (wave >> 1) * 64, wn = (wave & 1) * 64;
    int quad = lane >> 4, l15 = lane & 15;
    int m0 = blockIdx.y * 128, n0 = blockIdx.x * 128;

    floatx4 acc[4][4];
#pragma unroll
    for (int i = 0; i < 4; i++)
#pragma unroll
        for (int j = 0; j < 4; j++) acc[i][j] = (floatx4)0.f;

    const u16* ga0 = A + (size_t)(m0 + (tid >> 2)) * K + (tid & 3) * 8;
    const u16* ga1 = A + (size_t)(m0 + 64 + (tid >> 2)) * K + (tid & 3) * 8;
    const u16* gb0 = Bt + (size_t)(n0 + (tid >> 2)) * K + (tid & 3) * 8;
    const u16* gb1 = Bt + (size_t)(n0 + 64 + (tid >> 2)) * K + (tid & 3) * 8;
    u16* la0 = &sA[tid * 8];
    u16* la1 = &sA[(256 + tid) * 8];
    u16* lb0 = &sB[tid * 8];
    u16* lb1 = &sB[(256 + tid) * 8];

    for (int k0 = 0; k0 < K; k0 += 32) {
        async_cp16(ga0 + k0, la0);
        async_cp16(ga1 + k0, la1);
        async_cp16(gb0 + k0, lb0);
        async_cp16(gb1 + k0, lb1);
        __syncthreads();
        short8 af[4], bf[4];
#pragma unroll
        for (int i = 0; i < 4; i++) {
            af[i] = *(const short8*)&sA[(wm + i * 16 + l15) * 32 + quad * 8];
            bf[i] = *(const short8*)&sB[(wn + i * 16 + l15) * 32 + quad * 8];
        }
#pragma unroll
        for (int i = 0; i < 4; i++)
#pragma unroll
            for (int j = 0; j < 4; j++)
                acc[i][j] = __builtin_amdgcn_mfma_f32_16x16x32_bf16(af[i], bf[j], acc[i][j], 0, 0, 0);
        __syncthreads();
    }

#pragma unroll
    for (int h = 0; h < 2; h++) {
        __syncthreads();
        if (wm == h * 64) {
#pragma unroll
            for (int j = 0; j < 4; j++) {
                int col = wn + j * 16 + l15;
                float b = bf2f(dtb[n0 + col]);
#pragma unroll
                for (int i = 0; i < 4; i++)
#pragma unroll
                    for (int r = 0; r < 4; r++) {
                        int row = i * 16 + quad * 4 + r;   // 0..63 within half
                        smem[row * 132 + col] = f2bf(softplus_fast(acc[i][j][r] + b));
                    }
            }
        }
        __syncthreads();
#pragma unroll
        for (int p = 0; p < 4; p++) {
            int row = p * 16 + (tid >> 4);
            int chunk = tid & 15;
            uint4 v = *(const uint4*)&smem[row * 132 + chunk * 8];
            *(uint4*)&dt[(size_t)(m0 + h * 64 + row) * D_INNER + n0 + chunk * 8] = v;
        }
    }
}

// ---------------------------------------------------------------------------
// K2: causal depthwise conv1d + silu (bf16 in/out)
__global__ __launch_bounds__(256) void conv_silu(const u16* __restrict__ xc, const u16* __restrict__ cw,
                                                 const u16* __restrict__ cb, u16* __restrict__ xs) {
    int idx = blockIdx.x * 256 + threadIdx.x;
    int d = idx & (D_INNER - 1);
    int t = (idx >> 12) & (SEQLEN - 1);
    int b = idx >> 23;
    float w0 = bf2f(cw[d * 4 + 0]), w1 = bf2f(cw[d * 4 + 1]);
    float w2 = bf2f(cw[d * 4 + 2]), w3 = bf2f(cw[d * 4 + 3]);
    float acc = bf2f(cb[d]);
    size_t base = (size_t)b * SEQLEN * D_INNER + d;
    if (t >= 3) acc += bf2f(xc[base + (size_t)(t - 3) * D_INNER]) * w0;
    if (t >= 2) acc += bf2f(xc[base + (size_t)(t - 2) * D_INNER]) * w1;
    if (t >= 1) acc += bf2f(xc[base + (size_t)(t - 1) * D_INNER]) * w2;
    acc += bf2f(xc[base + (size_t)t * D_INNER]) * w3;
    xs[idx] = f2bf(acc * sigmoid_fast(acc));
}

// ---------------------------------------------------------------------------
// K5a: chunked scan phase 1 — per (b,d,chunk) thread, 16 states in registers.
// exp via exp2 with prescaled A (A*log2e) to drop the per-call internal mul.
__global__ __launch_bounds__(256) void scan_phase1(const float* __restrict__ proj, const u16* __restrict__ dt,
                                                   const float* __restrict__ A, const u16* __restrict__ xs,
                                                   float* __restrict__ hloc, float* __restrict__ Ssum) {
    __shared__ float Bsh[TC][16];
    int d = blockIdx.x * 256 + threadIdx.x;
    int c = blockIdx.y, b = blockIdx.z;
    int t0 = c * TC;
    {
        int i = threadIdx.x >> 2;
        int q = threadIdx.x & 3;
        if (i < TC) {
            const float* src = proj + ((size_t)b * SEQLEN + t0 + i) * PST + DT_RANK + q * 4;
            *(float4*)&Bsh[i][q * 4] = *(const float4*)src;
        }
    }
    __syncthreads();
    float Aexp[16];
#pragma unroll
    for (int n = 0; n < 16; n++) Aexp[n] = A[d * 16 + n] * LOG2E;
    float h[16];
#pragma unroll
    for (int n = 0; n < 16; n++) h[n] = 0.f;
    float S = 0.f;
    size_t base = ((size_t)b * SEQLEN + t0) * D_INNER + d;
    for (int t = 0; t < TC; t++) {
        size_t idx = base + (size_t)t * D_INNER;
        float dtv = bf2f(dt[idx]);
        float u = bf2f(xs[idx]);
        S += dtv;
        float du = dtv * u;
#pragma unroll
        for (int n = 0; n < 16; n++) {
            h[n] = h[n] * exp2f(dtv * Aexp[n]) + du * Bsh[t][n];
        }
    }
    float* hp = &hloc[(((size_t)b * NC + c) * D_INNER + d) * 16];
#pragma unroll
    for (int n = 0; n < 16; n += 4)
        *(float4*)&hp[n] = make_float4(h[n], h[n + 1], h[n + 2], h[n + 3]);
    Ssum[((size_t)b * NC + c) * D_INNER + d] = S;
}

// ---------------------------------------------------------------------------
// K5b: combine chunks serially (in place: hloc becomes h_init per chunk).
__global__ __launch_bounds__(256) void scan_phase2(const float* __restrict__ A, const float* __restrict__ Ssum,
                                                   float* __restrict__ hloc) {
    int tid = blockIdx.x * 256 + threadIdx.x;
    int n = tid & 15;
    int d = (tid >> 4) & (D_INNER - 1);
    int b = tid >> 16;
    float An2 = A[d * 16 + n] * LOG2E;
    float h = 0.f;
    for (int c = 0; c < NC; c++) {
        size_t idx = (((size_t)b * NC + c) * D_INNER + d) * 16 + n;
        float hl = hloc[idx];
        float S = Ssum[((size_t)b * NC + c) * D_INNER + d];
        hloc[idx] = h;
        h = hl + h * exp2f(An2 * S);
    }
}

// ---------------------------------------------------------------------------
// K5c: phase 3 — rerun chunk with h_init, compute y, D-residual, silu(z) gate.
__global__ __launch_bounds__(256) void scan_phase3(const float* __restrict__ proj, const u16* __restrict__ dt,
                                                   const float* __restrict__ A, const u16* __restrict__ D16,
                                                   const float* __restrict__ hinit, const u16* __restrict__ z16,
                                                   u16* __restrict__ xs) {
    __shared__ float BC[TC][32];
    int d = blockIdx.x * 256 + threadIdx.x;
    int c = blockIdx.y, b = blockIdx.z;
    int t0 = c * TC;
    {
        int i = threadIdx.x >> 2;
        int q = threadIdx.x & 3;
        if (i < TC) {
            const float* src = proj + ((size_t)b * SEQLEN + t0 + i) * PST + DT_RANK + q * 8;
            *(float4*)&BC[i][q * 8 + 0] = *(const float4*)(src + 0);
            *(float4*)&BC[i][q * 8 + 4] = *(const float4*)(src + 4);
        }
    }
    __syncthreads();
    float Aexp[16];
#pragma unroll
    for (int n = 0; n < 16; n++) Aexp[n] = A[d * 16 + n] * LOG2E;
    float h[16];
    {
        const float* hp = &hinit[(((size_t)b * NC + c) * D_INNER + d) * 16];
#pragma unroll
        for (int n = 0; n < 16; n += 4) {
            float4 v = *(const float4*)&hp[n];
            h[n] = v.x; h[n + 1] = v.y; h[n + 2] = v.z; h[n + 3] = v.w;
        }
    }
    float Dd = bf2f(D16[d]);
    size_t base = ((size_t)b * SEQLEN + t0) * D_INNER + d;
    for (int t = 0; t < TC; t++) {
        size_t idx = base + (size_t)t * D_INNER;
        float dtv = bf2f(dt[idx]);
        float u = bf2f(xs[idx]);
        float zv = bf2f(z16[idx]);
        float du = dtv * u;
        float y = 0.f;
#pragma unroll
        for (int n = 0; n < 16; n++) {
            h[n] = h[n] * exp2f(dtv * Aexp[n]) + du * BC[t][n];
            y += h[n] * BC[t][16 + n];
        }
        float gate = zv * sigmoid_fast(zv);
        xs[idx] = f2bf((y + u * Dd) * gate);
    }
}

// ---------------------------------------------------------------------------
extern "C" void kernel_launch(void* const* d_in, const int* in_sizes, int n_in,
                              void* d_out, int out_size, void* d_ws, size_t ws_size,
                              hipStream_t stream) {
    const void* x          = d_in[0];
    const void* in_proj_w  = d_in[1];
    const void* conv_w     = d_in[2];
    const void* conv_b     = d_in[3];
    const void* x_proj_w   = d_in[4];
    const void* dt_proj_w  = d_in[5];
    const void* dt_proj_b  = d_in[6];
    const void* A_log      = d_in[7];
    const void* Dvec       = d_in[8];
    const void* out_proj_w = d_in[9];

    char* w = (char*)d_ws;
    const size_t MB = 1024 * 1024;
    const size_t KB = 1024;
    // Overlay plan (stream order guarantees safety):
    //   5-37 MB  : xc (K1 out, dead after conv) -> dt16 -> Pp6 lower half
    //  37-69 MB  : z (dead after scan_phase3)   -> Pp6 upper half
    //  69-101 MB : xs (conv out) -> gated y (K6 A operand)
    // 101-133 MB : x16+ipwT (dead after K1) -> Pp (dead after reduce) -> hloc(32MB)
    int*   flag    = (int*)(w + 0);
    float* Aws     = (float*)(w + 1 * KB);          // 256 KB
    float* proj    = (float*)(w + 1 * MB);          // 2 MB fp32 [4096][PST=128]
    u16*   cw16    = (u16*)(w + 3 * MB);            // 32 KB
    u16*   cb16    = (u16*)(w + 3 * MB + 64 * KB);  // 8 KB
    u16*   dtb16   = (u16*)(w + 3 * MB + 128 * KB); // 8 KB
    u16*   D16     = (u16*)(w + 3 * MB + 192 * KB); // 8 KB
    u16*   proj_lo = (u16*)(w + 3 * MB + 512 * KB); // 512 KB bf16 [4096][64]
    u16*   dtwT    = (u16*)(w + 4 * MB);            // 512 KB bf16 [4096][64]
    u16*   buf1    = (u16*)(w + 5 * MB);            // 32 MB: xc then dt16
    u16*   dt16    = buf1;
    u16*   zbuf    = (u16*)(w + 37 * MB);           // 32 MB: z
    float* Pp6     = (float*)(w + 5 * MB);          // 64 MB: K6 partials (post-scan)
    u16*   xs      = (u16*)(w + 69 * MB);           // 32 MB: xs then gated y
    u16*   x16     = (u16*)(w + 101 * MB);          // 8.4 MB  (dead after K1)
    u16*   ipwT    = (u16*)(w + 110 * MB);          // 16.8 MB (dead after K1)
    float* Pp      = (float*)(w + 101 * MB);        // 16 MB (post-K1, dead after reduce)
    float* hloc    = (float*)(w + 101 * MB);        // 32 MB (post-reduce, NC=64)
    float* Ssum    = (float*)(w + 133 * MB);        // 2 MB  (post-K1)
    u16*   opwT    = (u16*)(w + 136 * MB);          // 8.4 MB: out_proj_w^T [1024][4096]
    u16*   xpwT    = (u16*)(w + 145 * MB);          // 1 MB: x_proj_w^T [96(pad128)][4096]
    // total 146 MB (<150 MB proven available)

    detect_dtype<<<dim3(1), dim3(256), 0, stream>>>((const u16*)x, flag);
    prep_small<<<dim3(256), dim3(256), 0, stream>>>(conv_w, conv_b, dt_proj_b, Dvec, A_log,
                                                    cw16, cb16, dtb16, D16, Aws, flag);
    ingest16<<<dim3(MROWS * D_MODEL / 256), dim3(256), 0, stream>>>(x, x16, MROWS * D_MODEL, flag);
    transpose_w<<<dim3(2 * D_INNER / 32, D_MODEL / 32), dim3(256), 0, stream>>>(in_proj_w, ipwT, D_MODEL, 2 * D_INNER, flag);
    transpose_w<<<dim3(D_MODEL / 32, D_INNER / 32), dim3(256), 0, stream>>>(out_proj_w, opwT, D_INNER, D_MODEL, flag);
    transpose_w<<<dim3(NPROJ / 32, D_INNER / 32), dim3(256), 0, stream>>>(x_proj_w, xpwT, D_INNER, NPROJ, flag);
    transpose_w<<<dim3(D_INNER / 32, DT_RANK / 32), dim3(256), 0, stream>>>(dt_proj_w, dtwT, DT_RANK, D_INNER, flag);

    // K1: xz = x @ Win -> xc (buf1) + z (zbuf); 256^2-tile 8-phase, 512 blocks
    gemm8p<1024, 0><<<dim3(512), dim3(512), 0, stream>>>(x16, ipwT, buf1, zbuf, nullptr);
    // K2: conv + silu -> xs
    conv_silu<<<dim3(MROWS * D_INNER / 256), dim3(256), 0, stream>>>(buf1, cw16, cb16, xs);
    // K3: proj via split-K MFMA + reduce (also emits proj_lo bf16)
    gemm_proj<<<dim3(KSPLIT, MROWS / 128), dim3(256), 0, stream>>>(xs, xpwT, Pp);
    reduce_proj<<<dim3(MROWS * PST / 256), dim3(256), 0, stream>>>(Pp, proj, proj_lo);
    // K4: dt via MFMA, fused bias+fast-softplus (dt16 overlays dead xc)
    gemm_dt<<<dim3(D_INNER / 128, MROWS / 128), dim3(256), 0, stream>>>(proj_lo, dtwT, dtb16, dt16);
    // K5: chunked scan (NC=64 chunks -> 8 blocks/CU for exp-latency hiding)
    scan_phase1<<<dim3(D_INNER / 256, NC, BATCH), dim3(256), 0, stream>>>(proj, dt16, Aws, xs, hloc, Ssum);
    scan_phase2<<<dim3(BATCH * D_INNER * D_STATE / 256), dim3(256), 0, stream>>>(Aws, Ssum, hloc);
    scan_phase3<<<dim3(D_INNER / 256, NC, BATCH), dim3(256), 0, stream>>>(proj, dt16, Aws, D16, hloc, zbuf, xs);
    // K6: out = y @ out_proj_w; 256^2-tile 8-phase split-K (dt16/zbuf dead -> Pp6) + reduce
    gemm8p<4096, 1><<<dim3(D_MODEL / 256, MROWS / 256, KSP6), dim3(512), 0, stream>>>(xs, opwT, nullptr, nullptr, Pp6);
    reduce_out<<<dim3(MROWS * D_MODEL / 256), dim3(256), 0, stream>>>(Pp6, d_out, flag);
}

// Round 3
// 504.643 us; speedup vs baseline: 1.0792x; 1.0792x over previous
//
#include <hip/hip_runtime.h>
#include <hip/hip_bf16.h>

// Problem constants
#define D_MODEL 1024
#define D_INNER 4096
#define D_STATE 16
#define D_CONV 4
#define DT_RANK 64
#define BATCH 2
#define SEQLEN 2048
#define MROWS (BATCH * SEQLEN)          // 4096
#define NPROJ (DT_RANK + 2 * D_STATE)   // 96
#define PST 128                         // proj row stride (padded, fp32)
#define NC 32                           // scan chunks
#define TC (SEQLEN / NC)                // 64 steps per chunk
#define KSPLIT 8                        // split-K for proj gemm
#define KSP6 4                          // split-K for out gemm

typedef unsigned short u16;
typedef unsigned int u32;
typedef __attribute__((ext_vector_type(8))) short short8;
typedef __attribute__((ext_vector_type(4))) float floatx4;

#define LOG2E 1.44269504089f

__device__ __forceinline__ float bf2f(u16 u) {
    union { u32 i; float f; } v; v.i = ((u32)u) << 16; return v.f;
}
__device__ __forceinline__ u16 f2bf(float f) {
    union { float f; u32 i; } v; v.f = f;
    u32 x = v.i;
    u32 r = x + 0x7fffu + ((x >> 16) & 1u);   // round to nearest even
    return (u16)(r >> 16);
}
// fast softplus: hardware exp/log; |err| << bf16 ulp for all finite x
__device__ __forceinline__ float softplus_fast(float x) {
    float l = __logf(1.f + __expf(-fabsf(x)));
    return x > 0.f ? x + l : l;
}
// fast sigmoid: v_exp + v_rcp (1 ulp), no exact-division sequence
__device__ __forceinline__ float sigmoid_fast(float x) {
    return __builtin_amdgcn_rcpf(1.f + __expf(-x));
}
// raw hardware 2^x (single v_exp_f32; caller pre-scales by log2e)
__device__ __forceinline__ float exp2_hw(float x) {
    float r;
    asm("v_exp_f32 %0, %1" : "=v"(r) : "v"(x));
    return r;
}
// async global->LDS 16B DMA (dest = wave-uniform base + lane*16)
__device__ __forceinline__ void async_cp16(const u16* g, u16* l) {
    __builtin_amdgcn_global_load_lds((const __attribute__((address_space(1))) void*)g,
                                     (__attribute__((address_space(3))) void*)l, 16, 0, 0);
}

// ---------------------------------------------------------------------------
// D0: detect input dtype (bf16 vs fp32) from exponent-field statistics.
__global__ __launch_bounds__(256) void detect_dtype(const u16* __restrict__ x, int* __restrict__ flag) {
    __shared__ int cnt;
    if (threadIdx.x == 0) cnt = 0;
    __syncthreads();
    int local = 0;
    for (int k = 0; k < 16; k++) {
        int e = threadIdx.x * 8192 + k * 512;
        u16 v = x[2 * e];
        int ex = (v >> 7) & 0xFF;
        if (ex >= 0x68 && ex <= 0x8F) local++;
    }
    atomicAdd(&cnt, local);
    __syncthreads();
    if (threadIdx.x == 0) *flag = (cnt >= 2458) ? 1 : 0;
}

// ---------------------------------------------------------------------------
__global__ __launch_bounds__(256) void ingest16(const void* __restrict__ src, u16* __restrict__ dst,
                                                int n, const int* __restrict__ flag) {
    int i = blockIdx.x * 256 + threadIdx.x;
    if (i >= n) return;
    if (*flag) dst[i] = ((const u16*)src)[i];
    else       dst[i] = f2bf(((const float*)src)[i]);
}

// ---------------------------------------------------------------------------
// Fused small-tensor prologue: conv_w, conv_b, dt_proj_b, D ingest + A=-exp(A_log).
__global__ __launch_bounds__(256) void prep_small(const void* __restrict__ cw, const void* __restrict__ cb,
                                                  const void* __restrict__ dtb, const void* __restrict__ Dv,
                                                  const void* __restrict__ Alog,
                                                  u16* __restrict__ cw16, u16* __restrict__ cb16,
                                                  u16* __restrict__ dtb16, u16* __restrict__ D16,
                                                  float* __restrict__ A, const int* __restrict__ flag) {
    int i = blockIdx.x * 256 + threadIdx.x;   // grid covers 65536
    int isb = *flag;
    if (i < D_INNER * D_CONV)
        cw16[i] = isb ? ((const u16*)cw)[i] : f2bf(((const float*)cw)[i]);
    if (i < D_INNER) {
        cb16[i]  = isb ? ((const u16*)cb)[i]  : f2bf(((const float*)cb)[i]);
        dtb16[i] = isb ? ((const u16*)dtb)[i] : f2bf(((const float*)dtb)[i]);
        D16[i]   = isb ? ((const u16*)Dv)[i]  : f2bf(((const float*)Dv)[i]);
    }
    if (i < D_INNER * D_STATE) {
        float v = isb ? bf2f(((const u16*)Alog)[i]) : ((const float*)Alog)[i];
        A[i] = -expf(v);
    }
}

// ---------------------------------------------------------------------------
// Transpose-ingest: W [K][N] (dual dtype) -> WT [N][K] bf16.
__global__ __launch_bounds__(256) void transpose_w(const void* __restrict__ W, u16* __restrict__ WT,
                                                   int K, int N, const int* __restrict__ flag) {
    __shared__ float t[32][33];
    int k0 = blockIdx.y * 32, n0 = blockIdx.x * 32;
    int tid = threadIdx.x;
    int r = tid >> 3, c4 = (tid & 7) * 4;
    int isb = *flag;
    size_t base = (size_t)(k0 + r) * N + n0 + c4;
    float4 v;
    if (isb) { ushort4 u4 = *(const ushort4*)((const u16*)W + base);
               v = make_float4(bf2f(u4.x), bf2f(u4.y), bf2f(u4.z), bf2f(u4.w)); }
    else     { v = *(const float4*)((const float*)W + base); }
    t[c4 + 0][r] = v.x; t[c4 + 1][r] = v.y; t[c4 + 2][r] = v.z; t[c4 + 3][r] = v.w;
    __syncthreads();
    u16* o = WT + (size_t)(n0 + r) * K + k0 + c4;
    o[0] = f2bf(t[r][c4 + 0]);
    o[1] = f2bf(t[r][c4 + 1]);
    o[2] = f2bf(t[r][c4 + 2]);
    o[3] = f2bf(t[r][c4 + 3]);
}

// ---------------------------------------------------------------------------
// 256x256-tile 8-phase GEMM (HK-style schedule in plain HIP).
//
// A [M][KS] bf16 row-major, Bt [N][KS] bf16 row-major.
// 512 threads = 8 waves (2M x 4N); per-wave output 128x64, chunk-interleaved:
//   M-frag i: row = wr*64 + (i&3)*16 + (i>>2)*128  -> A-chunk (i>>2)
//   N-frag j: col = wc*32 + (j&1)*16 + (j>>1)*128  -> B-chunk (j>>1)
// K-tile = 64; each tile = 4 chunks (A0,A1,B0,B1) of 128x64 bf16 = 16 KB.
// Phase order per tile: (A0,B0) (A0,B1) (A1,B1) (A1,B0) — each phase reads at
// most one new chunk, stages one chunk of tile t+1 into the dead buffer, does
// 16 MFMA under setprio(1), then counted vmcnt + raw s_barrier (never vmcnt 0
// in the steady loop; ledger gives 4/4/6/4, epilogue drains 2/0).
// LDS reads XOR-swizzled (col ^= (row&7)*8 elems); global_load_lds dest stays
// linear, the *global source* is inverse-swizzled (both-sides rule, m173).
//
// MODE 0: C bf16, split to o0/o1 at col D_INNER (in-proj). KS=1024, grid 512,
//         bijective XCD swizzle. MODE 1: fp32 split-K partials Pp[z][M][1024]
//         (out-proj). KS=4096, grid (4,16,KSP6).
template<int KS, int MODE>
__global__ __launch_bounds__(512, 2) void gemm8p(const u16* __restrict__ A, const u16* __restrict__ Bt,
                                                 u16* __restrict__ o0, u16* __restrict__ o1,
                                                 float* __restrict__ Pp) {
    __shared__ __align__(16) u16 lds[65536];   // 128 KB: A = 2buf x 2chunk x 8192 u16; B at +32768
    const int tid = threadIdx.x;
    const int lane = tid & 63;
    const int wave = tid >> 6;
    const int wr = wave >> 2, wc = wave & 3;
    const int quad = lane >> 4, l15 = lane & 15;

    int m0, n0, kbase, kz;
    if (MODE == 0) {
        int wgid = (blockIdx.x & 7) * 64 + (blockIdx.x >> 3);   // bijective (512 % 8 == 0)
        m0 = (wgid & 15) * 256;
        n0 = (wgid >> 4) * 256;
        kbase = 0; kz = 0;
    } else {
        m0 = blockIdx.y * 256;
        n0 = blockIdx.x * 256;
        kz = blockIdx.z;
        kbase = kz * 1024;
    }
    const int NT = 1024 / 64;   // 16 k-tiles per block (both modes sweep 1024 of K)

    // ---- staging addressing: linear LDS dest, inverse-swizzled global source
    const int srow = tid >> 3;                              // 0..63 (chunk row, rho adds 64)
    const int kswz = (((tid & 7) ^ (srow & 7)) << 3);       // element offset within 64-wide k
    const u16* pA = A + (size_t)(m0 + srow) * KS + kbase + kswz;
    const u16* pB = Bt + (size_t)(n0 + srow) * KS + kbase + kswz;

    // ---- fragment-read addressing (swizzle term is per-thread constant)
    const int rsw = (l15 & 7) << 3;
    const int ksel0 = (quad * 8) ^ rsw;
    const int ksel1 = (32 + quad * 8) ^ rsw;
    const int aoff = (wr * 64 + l15) * 64;
    const int boff = (wc * 32 + l15) * 64;

    floatx4 acc[8][4];
#pragma unroll
    for (int i = 0; i < 8; i++)
#pragma unroll
        for (int j = 0; j < 4; j++) acc[i][j] = (floatx4)0.f;
    short8 af[4][2];        // current A-chunk frags [ii][ksub]
    short8 bf[2][2][2];     // both B-chunk frags    [chunk][jj][ksub]

#define STAGE_A(nb, h, kt) do { \
    const u16* g_ = pA + (size_t)(h) * 128 * KS + (kt) * 64; \
    u16* l_ = &lds[((nb) * 2 + (h)) * 8192 + tid * 8]; \
    async_cp16(g_, l_); \
    async_cp16(g_ + (size_t)64 * KS, l_ + 4096); \
} while (0)
#define STAGE_B(nb, h, kt) do { \
    const u16* g_ = pB + (size_t)(h) * 128 * KS + (kt) * 64; \
    u16* l_ = &lds[32768 + ((nb) * 2 + (h)) * 8192 + tid * 8]; \
    async_cp16(g_, l_); \
    async_cp16(g_ + (size_t)64 * KS, l_ + 4096); \
} while (0)
#define LOADA(b, h) do { \
    const u16* p_ = &lds[((b) * 2 + (h)) * 8192 + aoff]; \
    _Pragma("unroll") \
    for (int ii = 0; ii < 4; ii++) { \
        af[ii][0] = *(const short8*)(p_ + ii * 1024 + ksel0); \
        af[ii][1] = *(const short8*)(p_ + ii * 1024 + ksel1); \
    } \
} while (0)
#define LOADB(b, h) do { \
    const u16* p_ = &lds[32768 + ((b) * 2 + (h)) * 8192 + boff]; \
    _Pragma("unroll") \
    for (int jj = 0; jj < 2; jj++) { \
        bf[h][jj][0] = *(const short8*)(p_ + jj * 1024 + ksel0); \
        bf[h][jj][1] = *(const short8*)(p_ + jj * 1024 + ksel1); \
    } \
} while (0)
#define MFMAQ(qa, qb) do { \
    __builtin_amdgcn_s_setprio(1); \
    _Pragma("unroll") \
    for (int ii = 0; ii < 4; ii++) \
    _Pragma("unroll") \
    for (int jj = 0; jj < 2; jj++) { \
        floatx4 c_ = acc[(qa) * 4 + ii][(qb) * 2 + jj]; \
        c_ = __builtin_amdgcn_mfma_f32_16x16x32_bf16(af[ii][0], bf[qb][jj][0], c_, 0, 0, 0); \
        c_ = __builtin_amdgcn_mfma_f32_16x16x32_bf16(af[ii][1], bf[qb][jj][1], c_, 0, 0, 0); \
        acc[(qa) * 4 + ii][(qb) * 2 + jj] = c_; \
    } \
    __builtin_amdgcn_s_setprio(0); \
} while (0)
#define VMW(N) asm volatile("s_waitcnt vmcnt(" #N ")" ::: "memory")
#define BARX() do { __builtin_amdgcn_s_barrier(); asm volatile("" ::: "memory"); } while (0)

    // prologue: tile 0 -> buf 0, issue order [A0, B0, B1, A1]
    STAGE_A(0, 0, 0);
    STAGE_B(0, 0, 0);
    STAGE_B(0, 1, 0);
    STAGE_A(0, 1, 0);
    VMW(4); BARX();                 // A0,B0 resident; B1,A1 (4 loads) in flight

    for (int t = 0; t < NT - 1; ++t) {
        const int b = t & 1, nb = b ^ 1;
        // phase 0: quadrant (A0,B0); prefetch A0(t+1)
        LOADA(b, 0);
        LOADB(b, 0);
        STAGE_A(nb, 0, t + 1);
        MFMAQ(0, 0);
        VMW(4); BARX();             // forces B1(t) complete
        // phase 1: quadrant (A0,B1); prefetch B0(t+1)
        LOADB(b, 1);
        STAGE_B(nb, 0, t + 1);
        MFMAQ(0, 1);
        VMW(4); BARX();             // forces A1(t) complete
        // phase 2: quadrant (A1,B1); prefetch B1(t+1)
        LOADA(b, 1);
        STAGE_B(nb, 1, t + 1);
        MFMAQ(1, 1);
        VMW(6); BARX();             // nothing needed at phase 3; keep <=3 chunks in flight
        // phase 3: quadrant (A1,B0); prefetch A1(t+1)
        STAGE_A(nb, 1, t + 1);
        MFMAQ(1, 0);
        VMW(4); BARX();             // forces A0(t+1),B0(t+1) complete for next tile
    }
    {   // last k-tile: no stages, drain 2 -> 0
        const int b = (NT - 1) & 1;
        LOADA(b, 0);
        LOADB(b, 0);
        MFMAQ(0, 0);
        VMW(2); BARX();             // forces B1 complete
        LOADB(b, 1);
        MFMAQ(0, 1);
        VMW(0); BARX();             // forces A1 complete
        LOADA(b, 1);
        MFMAQ(1, 1);
        MFMAQ(1, 0);
    }

    if constexpr (MODE == 0) {
        (void)kz; (void)Pp;
        u16* d = (n0 < D_INNER) ? o0 : o1;
        const int nb0 = (n0 < D_INNER) ? n0 : n0 - D_INNER;
#pragma unroll
        for (int i = 0; i < 8; i++) {
            const int mrow = m0 + wr * 64 + (i & 3) * 16 + (i >> 2) * 128 + quad * 4;
#pragma unroll
            for (int j = 0; j < 4; j++) {
                const int ncol = nb0 + wc * 32 + (j & 1) * 16 + (j >> 1) * 128 + l15;
#pragma unroll
                for (int r = 0; r < 4; r++)
                    d[(size_t)(mrow + r) * D_INNER + ncol] = f2bf(acc[i][j][r]);
            }
        }
    } else {
        (void)o0; (void)o1;
        float* d = Pp + (size_t)kz * MROWS * D_MODEL;
#pragma unroll
        for (int i = 0; i < 8; i++) {
            const int mrow = m0 + wr * 64 + (i & 3) * 16 + (i >> 2) * 128 + quad * 4;
#pragma unroll
            for (int j = 0; j < 4; j++) {
                const int ncol = n0 + wc * 32 + (j & 1) * 16 + (j >> 1) * 128 + l15;
#pragma unroll
                for (int r = 0; r < 4; r++)
                    d[(size_t)(mrow + r) * D_MODEL + ncol] = acc[i][j][r];
            }
        }
    }
#undef STAGE_A
#undef STAGE_B
#undef LOADA
#undef LOADB
#undef MFMAQ
#undef VMW
#undef BARX
}

// ---------------------------------------------------------------------------
__global__ __launch_bounds__(256) void reduce_out(const float* __restrict__ Pp, void* __restrict__ out,
                                                  const int* __restrict__ flag) {
    int i = blockIdx.x * 256 + threadIdx.x;   // < MROWS*D_MODEL
    float s = 0.f;
#pragma unroll
    for (int z = 0; z < KSP6; z++) s += Pp[(size_t)z * MROWS * D_MODEL + i];
    if (*flag) ((u16*)out)[i] = f2bf(s);
    else       ((float*)out)[i] = s;
}

// ---------------------------------------------------------------------------
// K3: proj split-K MFMA.  A = xs [4096][4096], Bt = xpwT [128(pad)][4096].
__global__ __launch_bounds__(256) void gemm_proj(const u16* __restrict__ A, const u16* __restrict__ Bt,
                                                 float* __restrict__ Pp) {
    const int K = D_INNER;
    __shared__ __align__(16) u16 sA[128 * 32];
    __shared__ __align__(16) u16 sB[128 * 32];
    int tid = threadIdx.x;
    int lane = tid & 63;
    int wave = tid >> 6;
    int wm = (wave >> 1) * 64, wn = (wave & 1) * 64;
    int quad = lane >> 4, l15 = lane & 15;
    int m0 = blockIdx.y * 128;
    int kz = blockIdx.x;
    int kbase = kz * (K / KSPLIT);

    floatx4 acc[4][4];
#pragma unroll
    for (int i = 0; i < 4; i++)
#pragma unroll
        for (int j = 0; j < 4; j++) acc[i][j] = (floatx4)0.f;

    const u16* ga0 = A + (size_t)(m0 + (tid >> 2)) * K + (tid & 3) * 8;
    const u16* ga1 = A + (size_t)(m0 + 64 + (tid >> 2)) * K + (tid & 3) * 8;
    const u16* gb0 = Bt + (size_t)(tid >> 2) * K + (tid & 3) * 8;
    const u16* gb1 = Bt + (size_t)(64 + (tid >> 2)) * K + (tid & 3) * 8;
    u16* la0 = &sA[tid * 8];
    u16* la1 = &sA[(256 + tid) * 8];
    u16* lb0 = &sB[tid * 8];
    u16* lb1 = &sB[(256 + tid) * 8];

    for (int k0 = kbase; k0 < kbase + K / KSPLIT; k0 += 32) {
        async_cp16(ga0 + k0, la0);
        async_cp16(ga1 + k0, la1);
        async_cp16(gb0 + k0, lb0);
        async_cp16(gb1 + k0, lb1);
        __syncthreads();
        short8 af[4], bf[4];
#pragma unroll
        for (int i = 0; i < 4; i++) {
            af[i] = *(const short8*)&sA[(wm + i * 16 + l15) * 32 + quad * 8];
            bf[i] = *(const short8*)&sB[(wn + i * 16 + l15) * 32 + quad * 8];
        }
#pragma unroll
        for (int i = 0; i < 4; i++)
#pragma unroll
            for (int j = 0; j < 4; j++)
                acc[i][j] = __builtin_amdgcn_mfma_f32_16x16x32_bf16(af[i], bf[j], acc[i][j], 0, 0, 0);
        __syncthreads();
    }

    float* d = Pp + (size_t)kz * MROWS * PST;
#pragma unroll
    for (int i = 0; i < 4; i++)
#pragma unroll
        for (int j = 0; j < 4; j++)
#pragma unroll
            for (int r = 0; r < 4; r++) {
                int mm = m0 + wm + i * 16 + quad * 4 + r;
                int nn = wn + j * 16 + l15;
                d[(size_t)mm * PST + nn] = acc[i][j][r];
            }
}

// ---------------------------------------------------------------------------
// reduce split-K partials -> proj fp32 [4096][PST]; also emit proj_lo bf16.
__global__ __launch_bounds__(256) void reduce_proj(const float* __restrict__ Pp, float* __restrict__ proj,
                                                   u16* __restrict__ proj_lo) {
    int i = blockIdx.x * 256 + threadIdx.x;    // < MROWS*PST
    float s = 0.f;
#pragma unroll
    for (int z = 0; z < KSPLIT; z++) s += Pp[(size_t)z * MROWS * PST + i];
    proj[i] = s;
    int col = i & (PST - 1);
    if (col < DT_RANK) proj_lo[(size_t)(i >> 7) * DT_RANK + col] = f2bf(s);
}

// ---------------------------------------------------------------------------
// K4: dt = softplus(proj_lo @ dtwT^T + b) via MFMA.  M=4096, N=4096, K=64.
// Epilogue: fast softplus + LDS bounce (stride-132 pad) -> coalesced 16B stores.
__global__ __launch_bounds__(256) void gemm_dt(const u16* __restrict__ A, const u16* __restrict__ Bt,
                                               const u16* __restrict__ dtb, u16* __restrict__ dt) {
    const int K = DT_RANK;   // 64
    __shared__ __align__(16) u16 smem[64 * 132];   // 16.9 KB; k-loop uses first 16 KB
    u16* sA = smem;
    u16* sB = smem + 128 * 32;
    int tid = threadIdx.x;
    int lane = tid & 63;
    int wave = tid >> 6;
    int wm = (wave >> 1) * 64, wn = (wave & 1) * 64;
    int quad = lane >> 4, l15 = lane & 15;
    int m0 = blockIdx.y * 128, n0 = blockIdx.x * 128;

    floatx4 acc[4][4];
#pragma unroll
    for (int i = 0; i < 4; i++)
#pragma unroll
        for (int j = 0; j < 4; j++) acc[i][j] = (floatx4)0.f;

    const u16* ga0 = A + (size_t)(m0 + (tid >> 2)) * K + (tid & 3) * 8;
    const u16* ga1 = A + (size_t)(m0 + 64 + (tid >> 2)) * K + (tid & 3) * 8;
    const u16* gb0 = Bt + (size_t)(n0 + (tid >> 2)) * K + (tid & 3) * 8;
    const u16* gb1 = Bt + (size_t)(n0 + 64 + (tid >> 2)) * K + (tid & 3) * 8;
    u16* la0 = &sA[tid * 8];
    u16* la1 = &sA[(256 + tid) * 8];
    u16* lb0 = &sB[tid * 8];
    u16* lb1 = &sB[(256 + tid) * 8];

    for (int k0 = 0; k0 < K; k0 += 32) {
        async_cp16(ga0 + k0, la0);
        async_cp16(ga1 + k0, la1);
        async_cp16(gb0 + k0, lb0);
        async_cp16(gb1 + k0, lb1);
        __syncthreads();
        short8 af[4], bf[4];
#pragma unroll
        for (int i = 0; i < 4; i++) {
            af[i] = *(const short8*)&sA[(wm + i * 16 + l15) * 32 + quad * 8];
            bf[i] = *(const short8*)&sB[(wn + i * 16 + l15) * 32 + quad * 8];
        }
#pragma unroll
        for (int i = 0; i < 4; i++)
#pragma unroll
            for (int j = 0; j < 4; j++)
                acc[i][j] = __builtin_amdgcn_mfma_f32_16x16x32_bf16(af[i], bf[j], acc[i][j], 0, 0, 0);
        __syncthreads();
    }

#pragma unroll
    for (int h = 0; h < 2; h++) {
        __syncthreads();
        if (wm == h * 64) {
#pragma unroll
            for (int j = 0; j < 4; j++) {
                int col = wn + j * 16 + l15;
                float b = bf2f(dtb[n0 + col]);
#pragma unroll
                for (int i = 0; i < 4; i++)
#pragma unroll
                    for (int r = 0; r < 4; r++) {
                        int row = i * 16 + quad * 4 + r;   // 0..63 within half
                        smem[row * 132 + col] = f2bf(softplus_fast(acc[i][j][r] + b));
                    }
            }
        }
        __syncthreads();
#pragma unroll
        for (int p = 0; p < 4; p++) {
            int row = p * 16 + (tid >> 4);
            int chunk = tid & 15;
            uint4 v = *(const uint4*)&smem[row * 132 + chunk * 8];
            *(uint4*)&dt[(size_t)(m0 + h * 64 + row) * D_INNER + n0 + chunk * 8] = v;
        }
    }
}

// ---------------------------------------------------------------------------
// K2: causal depthwise conv1d + silu (bf16 in/out)
__global__ __launch_bounds__(256) void conv_silu(const u16* __restrict__ xc, const u16* __restrict__ cw,
                                                 const u16* __restrict__ cb, u16* __restrict__ xs) {
    int idx = blockIdx.x * 256 + threadIdx.x;
    int d = idx & (D_INNER - 1);
    int t = (idx >> 12) & (SEQLEN - 1);
    int b = idx >> 23;
    float w0 = bf2f(cw[d * 4 + 0]), w1 = bf2f(cw[d * 4 + 1]);
    float w2 = bf2f(cw[d * 4 + 2]), w3 = bf2f(cw[d * 4 + 3]);
    float acc = bf2f(cb[d]);
    size_t base = (size_t)b * SEQLEN * D_INNER + d;
    if (t >= 3) acc += bf2f(xc[base + (size_t)(t - 3) * D_INNER]) * w0;
    if (t >= 2) acc += bf2f(xc[base + (size_t)(t - 2) * D_INNER]) * w1;
    if (t >= 1) acc += bf2f(xc[base + (size_t)(t - 1) * D_INNER]) * w2;
    acc += bf2f(xc[base + (size_t)t * D_INNER]) * w3;
    xs[idx] = f2bf(acc * sigmoid_fast(acc));
}

// ---------------------------------------------------------------------------
// K5a: chunked scan phase 1 — per (b,d,chunk) thread, 16 states in registers.
// B row is wave-uniform (depends on t only) -> read direct from global
// (compiler promotes to s_load); dt/xs HBM streams prefetched 1 step ahead.
__global__ __launch_bounds__(256) void scan_phase1(const float* __restrict__ proj, const u16* __restrict__ dt,
                                                   const float* __restrict__ A, const u16* __restrict__ xs,
                                                   float* __restrict__ hloc, float* __restrict__ Ssum) {
    int d = blockIdx.x * 256 + threadIdx.x;
    int c = blockIdx.y, b = blockIdx.z;
    int t0 = c * TC;
    float Areg[16];   // prescaled by log2e for raw v_exp_f32
    {
        const float4* Ap = (const float4*)(A + (size_t)d * 16);
#pragma unroll
        for (int n = 0; n < 4; n++) {
            float4 v = Ap[n];
            Areg[n * 4 + 0] = v.x * LOG2E; Areg[n * 4 + 1] = v.y * LOG2E;
            Areg[n * 4 + 2] = v.z * LOG2E; Areg[n * 4 + 3] = v.w * LOG2E;
        }
    }
    float h[16];
#pragma unroll
    for (int n = 0; n < 16; n++) h[n] = 0.f;
    float S = 0.f;
    size_t base = ((size_t)b * SEQLEN + t0) * D_INNER + d;
    const float* prow = proj + ((size_t)b * SEQLEN + t0) * PST + DT_RANK;
    u16 dcur = dt[base], ucur = xs[base];
    for (int t = 0; t < TC; t++) {
        size_t nidx = base + (size_t)((t + 1 < TC) ? t + 1 : t) * D_INNER;
        u16 dnxt = dt[nidx];
        u16 unxt = xs[nidx];
        float4 B0 = *(const float4*)(prow + t * PST + 0);
        float4 B1 = *(const float4*)(prow + t * PST + 4);
        float4 B2 = *(const float4*)(prow + t * PST + 8);
        float4 B3 = *(const float4*)(prow + t * PST + 12);
        float dtv = bf2f(dcur), u = bf2f(ucur);
        S += dtv;
        float du = dtv * u;
        float Bf[16] = {B0.x, B0.y, B0.z, B0.w, B1.x, B1.y, B1.z, B1.w,
                        B2.x, B2.y, B2.z, B2.w, B3.x, B3.y, B3.z, B3.w};
#pragma unroll
        for (int n = 0; n < 16; n++)
            h[n] = h[n] * exp2_hw(dtv * Areg[n]) + du * Bf[n];
        dcur = dnxt; ucur = unxt;
    }
    float* hp = &hloc[(((size_t)b * NC + c) * D_INNER + d) * 16];
#pragma unroll
    for (int n = 0; n < 16; n += 4)
        *(float4*)&hp[n] = make_float4(h[n], h[n + 1], h[n + 2], h[n + 3]);
    Ssum[((size_t)b * NC + c) * D_INNER + d] = S;
}

// ---------------------------------------------------------------------------
// K5b: combine chunks serially (in place: hloc becomes h_init per chunk).
__global__ __launch_bounds__(256) void scan_phase2(const float* __restrict__ A, const float* __restrict__ Ssum,
                                                   float* __restrict__ hloc) {
    int tid = blockIdx.x * 256 + threadIdx.x;
    int n = tid & 15;
    int d = (tid >> 4) & (D_INNER - 1);
    int b = tid >> 16;
    float An2 = A[d * 16 + n] * LOG2E;
    float h = 0.f;
    for (int c = 0; c < NC; c++) {
        size_t idx = (((size_t)b * NC + c) * D_INNER + d) * 16 + n;
        float hl = hloc[idx];
        float S = Ssum[((size_t)b * NC + c) * D_INNER + d];
        hloc[idx] = h;
        h = hl + h * exp2_hw(An2 * S);
    }
}

// ---------------------------------------------------------------------------
// K5c: phase 3 — rerun chunk with h_init, compute y, D-residual, silu(z) gate.
// B/C rows wave-uniform -> direct global (s_load); dt/xs/z prefetched 1 ahead.
__global__ __launch_bounds__(256) void scan_phase3(const float* __restrict__ proj, const u16* __restrict__ dt,
                                                   const float* __restrict__ A, const u16* __restrict__ D16,
                                                   const float* __restrict__ hinit, const u16* __restrict__ z16,
                                                   u16* __restrict__ xs) {
    int d = blockIdx.x * 256 + threadIdx.x;
    int c = blockIdx.y, b = blockIdx.z;
    int t0 = c * TC;
    float Areg[16];   // prescaled by log2e
    {
        const float4* Ap = (const float4*)(A + (size_t)d * 16);
#pragma unroll
        for (int n = 0; n < 4; n++) {
            float4 v = Ap[n];
            Areg[n * 4 + 0] = v.x * LOG2E; Areg[n * 4 + 1] = v.y * LOG2E;
            Areg[n * 4 + 2] = v.z * LOG2E; Areg[n * 4 + 3] = v.w * LOG2E;
        }
    }
    float h[16];
    {
        const float* hp = &hinit[(((size_t)b * NC + c) * D_INNER + d) * 16];
#pragma unroll
        for (int n = 0; n < 16; n += 4) {
            float4 v = *(const float4*)&hp[n];
            h[n] = v.x; h[n + 1] = v.y; h[n + 2] = v.z; h[n + 3] = v.w;
        }
    }
    float Dd = bf2f(D16[d]);
    size_t base = ((size_t)b * SEQLEN + t0) * D_INNER + d;
    const float* prow = proj + ((size_t)b * SEQLEN + t0) * PST + DT_RANK;
    u16 dcur = dt[base], ucur = xs[base], zcur = z16[base];
    for (int t = 0; t < TC; t++) {
        size_t nidx = base + (size_t)((t + 1 < TC) ? t + 1 : t) * D_INNER;
        u16 dnxt = dt[nidx];
        u16 unxt = xs[nidx];
        u16 znxt = z16[nidx];
        float4 B0 = *(const float4*)(prow + t * PST + 0);
        float4 B1 = *(const float4*)(prow + t * PST + 4);
        float4 B2 = *(const float4*)(prow + t * PST + 8);
        float4 B3 = *(const float4*)(prow + t * PST + 12);
        float4 C0 = *(const float4*)(prow + t * PST + 16);
        float4 C1 = *(const float4*)(prow + t * PST + 20);
        float4 C2 = *(const float4*)(prow + t * PST + 24);
        float4 C3 = *(const float4*)(prow + t * PST + 28);
        float dtv = bf2f(dcur), u = bf2f(ucur), zv = bf2f(zcur);
        float du = dtv * u;
        float Bf[16] = {B0.x, B0.y, B0.z, B0.w, B1.x, B1.y, B1.z, B1.w,
                        B2.x, B2.y, B2.z, B2.w, B3.x, B3.y, B3.z, B3.w};
        float Cf[16] = {C0.x, C0.y, C0.z, C0.w, C1.x, C1.y, C1.z, C1.w,
                        C2.x, C2.y, C2.z, C2.w, C3.x, C3.y, C3.z, C3.w};
        float y = 0.f;
#pragma unroll
        for (int n = 0; n < 16; n++) {
            h[n] = h[n] * exp2_hw(dtv * Areg[n]) + du * Bf[n];
            y += h[n] * Cf[n];
        }
        float gate = zv * sigmoid_fast(zv);
        xs[base + (size_t)t * D_INNER] = f2bf((y + u * Dd) * gate);
        dcur = dnxt; ucur = unxt; zcur = znxt;
    }
}

// ---------------------------------------------------------------------------
extern "C" void kernel_launch(void* const* d_in, const int* in_sizes, int n_in,
                              void* d_out, int out_size, void* d_ws, size_t ws_size,
                              hipStream_t stream) {
    const void* x          = d_in[0];
    const void* in_proj_w  = d_in[1];
    const void* conv_w     = d_in[2];
    const void* conv_b     = d_in[3];
    const void* x_proj_w   = d_in[4];
    const void* dt_proj_w  = d_in[5];
    const void* dt_proj_b  = d_in[6];
    const void* A_log      = d_in[7];
    const void* Dvec       = d_in[8];
    const void* out_proj_w = d_in[9];

    char* w = (char*)d_ws;
    const size_t MB = 1024 * 1024;
    const size_t KB = 1024;
    // Overlay plan (stream order guarantees safety):
    //   5-37 MB  : xc (K1 out, dead after conv) -> dt16 -> Pp6 lower half
    //  37-69 MB  : z (dead after scan_phase3)   -> Pp6 upper half
    //  69-101 MB : xs (conv out) -> gated y (K6 A operand)
    // 101-126 MB : x16+ipwT (dead after K1) -> Pp (dead after reduce) -> hloc
    int*   flag    = (int*)(w + 0);
    float* Aws     = (float*)(w + 1 * KB);          // 256 KB
    float* proj    = (float*)(w + 1 * MB);          // 2 MB fp32 [4096][PST=128]
    u16*   cw16    = (u16*)(w + 3 * MB);            // 32 KB
    u16*   cb16    = (u16*)(w + 3 * MB + 64 * KB);  // 8 KB
    u16*   dtb16   = (u16*)(w + 3 * MB + 128 * KB); // 8 KB
    u16*   D16     = (u16*)(w + 3 * MB + 192 * KB); // 8 KB
    u16*   proj_lo = (u16*)(w + 3 * MB + 512 * KB); // 512 KB bf16 [4096][64]
    u16*   dtwT    = (u16*)(w + 4 * MB);            // 512 KB bf16 [4096][64]
    u16*   buf1    = (u16*)(w + 5 * MB);            // 32 MB: xc then dt16
    u16*   dt16    = buf1;
    u16*   zbuf    = (u16*)(w + 37 * MB);           // 32 MB: z
    float* Pp6     = (float*)(w + 5 * MB);          // 64 MB: K6 partials (post-scan)
    u16*   xs      = (u16*)(w + 69 * MB);           // 32 MB: xs then gated y
    u16*   x16     = (u16*)(w + 101 * MB);          // 8.4 MB  (dead after K1)
    u16*   ipwT    = (u16*)(w + 110 * MB);          // 16.8 MB (dead after K1)
    float* Pp      = (float*)(w + 101 * MB);        // 16 MB (post-K1, dead after reduce)
    float* hloc    = (float*)(w + 101 * MB);        // 16 MB (post-reduce, NC=32)
    float* Ssum    = (float*)(w + 117 * MB);        // 1 MB  (post-K1)
    u16*   opwT    = (u16*)(w + 127 * MB);          // 8.4 MB: out_proj_w^T [1024][4096]
    u16*   xpwT    = (u16*)(w + 136 * MB);          // 1 MB: x_proj_w^T [96(pad128)][4096]
    // total 137 MB (<150 MB proven available)

    detect_dtype<<<dim3(1), dim3(256), 0, stream>>>((const u16*)x, flag);
    prep_small<<<dim3(256), dim3(256), 0, stream>>>(conv_w, conv_b, dt_proj_b, Dvec, A_log,
                                                    cw16, cb16, dtb16, D16, Aws, flag);
    ingest16<<<dim3(MROWS * D_MODEL / 256), dim3(256), 0, stream>>>(x, x16, MROWS * D_MODEL, flag);
    transpose_w<<<dim3(2 * D_INNER / 32, D_MODEL / 32), dim3(256), 0, stream>>>(in_proj_w, ipwT, D_MODEL, 2 * D_INNER, flag);
    transpose_w<<<dim3(D_MODEL / 32, D_INNER / 32), dim3(256), 0, stream>>>(out_proj_w, opwT, D_INNER, D_MODEL, flag);
    transpose_w<<<dim3(NPROJ / 32, D_INNER / 32), dim3(256), 0, stream>>>(x_proj_w, xpwT, D_INNER, NPROJ, flag);
    transpose_w<<<dim3(D_INNER / 32, DT_RANK / 32), dim3(256), 0, stream>>>(dt_proj_w, dtwT, DT_RANK, D_INNER, flag);

    // K1: xz = x @ Win -> xc (buf1) + z (zbuf); 256^2-tile 8-phase, 512 blocks
    gemm8p<1024, 0><<<dim3(512), dim3(512), 0, stream>>>(x16, ipwT, buf1, zbuf, nullptr);
    // K2: conv + silu -> xs
    conv_silu<<<dim3(MROWS * D_INNER / 256), dim3(256), 0, stream>>>(buf1, cw16, cb16, xs);
    // K3: proj via split-K MFMA + reduce (also emits proj_lo bf16)
    gemm_proj<<<dim3(KSPLIT, MROWS / 128), dim3(256), 0, stream>>>(xs, xpwT, Pp);
    reduce_proj<<<dim3(MROWS * PST / 256), dim3(256), 0, stream>>>(Pp, proj, proj_lo);
    // K4: dt via MFMA, fused bias+fast-softplus (dt16 overlays dead xc)
    gemm_dt<<<dim3(D_INNER / 128, MROWS / 128), dim3(256), 0, stream>>>(proj_lo, dtwT, dtb16, dt16);
    // K5: chunked scan (NC=32; uniform B/C reads, no LDS, 1-step prefetch)
    scan_phase1<<<dim3(D_INNER / 256, NC, BATCH), dim3(256), 0, stream>>>(proj, dt16, Aws, xs, hloc, Ssum);
    scan_phase2<<<dim3(BATCH * D_INNER * D_STATE / 256), dim3(256), 0, stream>>>(Aws, Ssum, hloc);
    scan_phase3<<<dim3(D_INNER / 256, NC, BATCH), dim3(256), 0, stream>>>(proj, dt16, Aws, D16, hloc, zbuf, xs);
    // K6: out = y @ out_proj_w; 256^2-tile 8-phase split-K (dt16/zbuf dead -> Pp6) + reduce
    gemm8p<4096, 1><<<dim3(D_MODEL / 256, MROWS / 256, KSP6), dim3(512), 0, stream>>>(xs, opwT, nullptr, nullptr, Pp6);
    reduce_out<<<dim3(MROWS * D_MODEL / 256), dim3(256), 0, stream>>>(Pp6, d_out, flag);
}

// Round 4
// 500.081 us; speedup vs baseline: 1.0890x; 1.0091x over previous
//
#include <hip/hip_runtime.h>
#include <hip/hip_bf16.h>

// Problem constants
#define D_MODEL 1024
#define D_INNER 4096
#define D_STATE 16
#define D_CONV 4
#define DT_RANK 64
#define BATCH 2
#define SEQLEN 2048
#define MROWS (BATCH * SEQLEN)          // 4096
#define NPROJ (DT_RANK + 2 * D_STATE)   // 96
#define PST 128                         // proj row stride (padded, fp32)
#define NC 32                           // scan chunks
#define TC (SEQLEN / NC)                // 64 steps per chunk
#define KSPLIT 8                        // split-K for proj gemm
#define KSP6 4                          // split-K for out gemm

typedef unsigned short u16;
typedef unsigned int u32;
typedef __attribute__((ext_vector_type(8))) short short8;
typedef __attribute__((ext_vector_type(4))) float floatx4;

#define LOG2E 1.44269504089f

__device__ __forceinline__ float bf2f(u16 u) {
    union { u32 i; float f; } v; v.i = ((u32)u) << 16; return v.f;
}
__device__ __forceinline__ u16 f2bf(float f) {
    union { float f; u32 i; } v; v.f = f;
    u32 x = v.i;
    u32 r = x + 0x7fffu + ((x >> 16) & 1u);   // round to nearest even
    return (u16)(r >> 16);
}
// fast softplus: hardware exp/log; |err| << bf16 ulp for all finite x
__device__ __forceinline__ float softplus_fast(float x) {
    float l = __logf(1.f + __expf(-fabsf(x)));
    return x > 0.f ? x + l : l;
}
// fast sigmoid: v_exp + v_rcp (1 ulp), no exact-division sequence
__device__ __forceinline__ float sigmoid_fast(float x) {
    return __builtin_amdgcn_rcpf(1.f + __expf(-x));
}
// raw hardware 2^x (single v_exp_f32; caller pre-scales by log2e)
__device__ __forceinline__ float exp2_hw(float x) {
    float r;
    asm("v_exp_f32 %0, %1" : "=v"(r) : "v"(x));
    return r;
}
// async global->LDS 16B DMA (dest = wave-uniform base + lane*16)
__device__ __forceinline__ void async_cp16(const u16* g, u16* l) {
    __builtin_amdgcn_global_load_lds((const __attribute__((address_space(1))) void*)g,
                                     (__attribute__((address_space(3))) void*)l, 16, 0, 0);
}

// ---------------------------------------------------------------------------
// D0: detect input dtype (bf16 vs fp32) from exponent-field statistics.
__global__ __launch_bounds__(256) void detect_dtype(const u16* __restrict__ x, int* __restrict__ flag) {
    __shared__ int cnt;
    if (threadIdx.x == 0) cnt = 0;
    __syncthreads();
    int local = 0;
    for (int k = 0; k < 16; k++) {
        int e = threadIdx.x * 8192 + k * 512;
        u16 v = x[2 * e];
        int ex = (v >> 7) & 0xFF;
        if (ex >= 0x68 && ex <= 0x8F) local++;
    }
    atomicAdd(&cnt, local);
    __syncthreads();
    if (threadIdx.x == 0) *flag = (cnt >= 2458) ? 1 : 0;
}

// ---------------------------------------------------------------------------
__global__ __launch_bounds__(256) void ingest16(const void* __restrict__ src, u16* __restrict__ dst,
                                                int n, const int* __restrict__ flag) {
    int i = blockIdx.x * 256 + threadIdx.x;
    if (i >= n) return;
    if (*flag) dst[i] = ((const u16*)src)[i];
    else       dst[i] = f2bf(((const float*)src)[i]);
}

// ---------------------------------------------------------------------------
// Fused small-tensor prologue: conv_w, conv_b, dt_proj_b, D ingest + A=-exp(A_log).
__global__ __launch_bounds__(256) void prep_small(const void* __restrict__ cw, const void* __restrict__ cb,
                                                  const void* __restrict__ dtb, const void* __restrict__ Dv,
                                                  const void* __restrict__ Alog,
                                                  u16* __restrict__ cw16, u16* __restrict__ cb16,
                                                  u16* __restrict__ dtb16, u16* __restrict__ D16,
                                                  float* __restrict__ A, const int* __restrict__ flag) {
    int i = blockIdx.x * 256 + threadIdx.x;   // grid covers 65536
    int isb = *flag;
    if (i < D_INNER * D_CONV)
        cw16[i] = isb ? ((const u16*)cw)[i] : f2bf(((const float*)cw)[i]);
    if (i < D_INNER) {
        cb16[i]  = isb ? ((const u16*)cb)[i]  : f2bf(((const float*)cb)[i]);
        dtb16[i] = isb ? ((const u16*)dtb)[i] : f2bf(((const float*)dtb)[i]);
        D16[i]   = isb ? ((const u16*)Dv)[i]  : f2bf(((const float*)Dv)[i]);
    }
    if (i < D_INNER * D_STATE) {
        float v = isb ? bf2f(((const u16*)Alog)[i]) : ((const float*)Alog)[i];
        A[i] = -expf(v);
    }
}

// ---------------------------------------------------------------------------
// Transpose-ingest: W [K][N] (dual dtype) -> WT [N][K] bf16.
__global__ __launch_bounds__(256) void transpose_w(const void* __restrict__ W, u16* __restrict__ WT,
                                                   int K, int N, const int* __restrict__ flag) {
    __shared__ float t[32][33];
    int k0 = blockIdx.y * 32, n0 = blockIdx.x * 32;
    int tid = threadIdx.x;
    int r = tid >> 3, c4 = (tid & 7) * 4;
    int isb = *flag;
    size_t base = (size_t)(k0 + r) * N + n0 + c4;
    float4 v;
    if (isb) { ushort4 u4 = *(const ushort4*)((const u16*)W + base);
               v = make_float4(bf2f(u4.x), bf2f(u4.y), bf2f(u4.z), bf2f(u4.w)); }
    else     { v = *(const float4*)((const float*)W + base); }
    t[c4 + 0][r] = v.x; t[c4 + 1][r] = v.y; t[c4 + 2][r] = v.z; t[c4 + 3][r] = v.w;
    __syncthreads();
    u16* o = WT + (size_t)(n0 + r) * K + k0 + c4;
    o[0] = f2bf(t[r][c4 + 0]);
    o[1] = f2bf(t[r][c4 + 1]);
    o[2] = f2bf(t[r][c4 + 2]);
    o[3] = f2bf(t[r][c4 + 3]);
}

// ---------------------------------------------------------------------------
// 256x256-tile 8-phase GEMM (HK-style schedule in plain HIP).
//
// A [M][KS] bf16 row-major, Bt [N][KS] bf16 row-major.
// 512 threads = 8 waves (2M x 4N); per-wave output 128x64, chunk-interleaved:
//   M-frag i: row = wr*64 + (i&3)*16 + (i>>2)*128  -> A-chunk (i>>2)
//   N-frag j: col = wc*32 + (j&1)*16 + (j>>1)*128  -> B-chunk (j>>1)
// K-tile = 64; each tile = 4 chunks (A0,A1,B0,B1) of 128x64 bf16 = 16 KB.
//
// BURST-STAGE schedule (round 3): with double-buffering, buffer nb is fully
// free at the start of tile t (consumed during t-1), so ALL 8 loads of tile
// t+1 are issued at phase 0 of tile t. Ledger (vmcnt retires in issue order;
// burst order A0,B0,B1,A1):
//   boundary VMW(4): forces A0',B0'   (slack 4 phases)
//   phase0  VMW(10): forces B1(t)     (slack ~4 phases)
//   phase1  VMW(8) : forces A1(t)     (slack ~5 phases)
//   phase2  : no wait, no barrier (phase 3 reads no new LDS)
// Min slack ~4 phases (~1000 cyc) >= HBM miss latency; 3 waits + 3 barriers
// per k-tile (was 4+4 with 2-phase slack -> per-phase stalls at 35% MfmaUtil).
// Cross-wave visibility: every consuming phase is preceded in ALL waves by a
// wait forcing the producer loads, then s_barrier.
// LDS reads XOR-swizzled (col ^= (row&7)*8 elems); global_load_lds dest stays
// linear, the *global source* is inverse-swizzled (both-sides rule, m173).
//
// MODE 0: C bf16, split to o0/o1 at col D_INNER (in-proj). KS=1024, grid 512,
//         bijective XCD swizzle. MODE 1: fp32 split-K partials Pp[z][M][1024]
//         (out-proj). KS=4096, grid (4,16,KSP6).
template<int KS, int MODE>
__global__ __launch_bounds__(512, 2) void gemm8p(const u16* __restrict__ A, const u16* __restrict__ Bt,
                                                 u16* __restrict__ o0, u16* __restrict__ o1,
                                                 float* __restrict__ Pp) {
    __shared__ __align__(16) u16 lds[65536];   // 128 KB: A = 2buf x 2chunk x 8192 u16; B at +32768
    const int tid = threadIdx.x;
    const int lane = tid & 63;
    const int wave = tid >> 6;
    const int wr = wave >> 2, wc = wave & 3;
    const int quad = lane >> 4, l15 = lane & 15;

    int m0, n0, kbase, kz;
    if (MODE == 0) {
        int wgid = (blockIdx.x & 7) * 64 + (blockIdx.x >> 3);   // bijective (512 % 8 == 0)
        m0 = (wgid & 15) * 256;
        n0 = (wgid >> 4) * 256;
        kbase = 0; kz = 0;
    } else {
        m0 = blockIdx.y * 256;
        n0 = blockIdx.x * 256;
        kz = blockIdx.z;
        kbase = kz * 1024;
    }
    const int NT = 1024 / 64;   // 16 k-tiles per block (both modes sweep 1024 of K)

    // ---- staging addressing: linear LDS dest, inverse-swizzled global source
    const int srow = tid >> 3;                              // 0..63 (chunk row, rho adds 64)
    const int kswz = (((tid & 7) ^ (srow & 7)) << 3);       // element offset within 64-wide k
    const u16* pA = A + (size_t)(m0 + srow) * KS + kbase + kswz;
    const u16* pB = Bt + (size_t)(n0 + srow) * KS + kbase + kswz;

    // ---- fragment-read addressing (swizzle term is per-thread constant)
    const int rsw = (l15 & 7) << 3;
    const int ksel0 = (quad * 8) ^ rsw;
    const int ksel1 = (32 + quad * 8) ^ rsw;
    const int aoff = (wr * 64 + l15) * 64;
    const int boff = (wc * 32 + l15) * 64;

    floatx4 acc[8][4];
#pragma unroll
    for (int i = 0; i < 8; i++)
#pragma unroll
        for (int j = 0; j < 4; j++) acc[i][j] = (floatx4)0.f;
    short8 af[4][2];        // current A-chunk frags [ii][ksub]
    short8 bf[2][2][2];     // both B-chunk frags    [chunk][jj][ksub]

#define STAGE_A(nb, h, kt) do { \
    const u16* g_ = pA + (size_t)(h) * 128 * KS + (kt) * 64; \
    u16* l_ = &lds[((nb) * 2 + (h)) * 8192 + tid * 8]; \
    async_cp16(g_, l_); \
    async_cp16(g_ + (size_t)64 * KS, l_ + 4096); \
} while (0)
#define STAGE_B(nb, h, kt) do { \
    const u16* g_ = pB + (size_t)(h) * 128 * KS + (kt) * 64; \
    u16* l_ = &lds[32768 + ((nb) * 2 + (h)) * 8192 + tid * 8]; \
    async_cp16(g_, l_); \
    async_cp16(g_ + (size_t)64 * KS, l_ + 4096); \
} while (0)
// burst: all 4 chunks (8 loads) of k-tile kt into buffer nb.
// issue order A0,B0,B1,A1 matches the wait ledger (oldest-first forcing).
#define BURST(nb, kt) do { \
    STAGE_A(nb, 0, kt); \
    STAGE_B(nb, 0, kt); \
    STAGE_B(nb, 1, kt); \
    STAGE_A(nb, 1, kt); \
} while (0)
#define LOADA(b, h) do { \
    const u16* p_ = &lds[((b) * 2 + (h)) * 8192 + aoff]; \
    _Pragma("unroll") \
    for (int ii = 0; ii < 4; ii++) { \
        af[ii][0] = *(const short8*)(p_ + ii * 1024 + ksel0); \
        af[ii][1] = *(const short8*)(p_ + ii * 1024 + ksel1); \
    } \
} while (0)
#define LOADB(b, h) do { \
    const u16* p_ = &lds[32768 + ((b) * 2 + (h)) * 8192 + boff]; \
    _Pragma("unroll") \
    for (int jj = 0; jj < 2; jj++) { \
        bf[h][jj][0] = *(const short8*)(p_ + jj * 1024 + ksel0); \
        bf[h][jj][1] = *(const short8*)(p_ + jj * 1024 + ksel1); \
    } \
} while (0)
#define MFMAQ(qa, qb) do { \
    __builtin_amdgcn_s_setprio(1); \
    _Pragma("unroll") \
    for (int ii = 0; ii < 4; ii++) \
    _Pragma("unroll") \
    for (int jj = 0; jj < 2; jj++) { \
        floatx4 c_ = acc[(qa) * 4 + ii][(qb) * 2 + jj]; \
        c_ = __builtin_amdgcn_mfma_f32_16x16x32_bf16(af[ii][0], bf[qb][jj][0], c_, 0, 0, 0); \
        c_ = __builtin_amdgcn_mfma_f32_16x16x32_bf16(af[ii][1], bf[qb][jj][1], c_, 0, 0, 0); \
        acc[(qa) * 4 + ii][(qb) * 2 + jj] = c_; \
    } \
    __builtin_amdgcn_s_setprio(0); \
} while (0)
#define VMW(N) asm volatile("s_waitcnt vmcnt(" #N ")" ::: "memory")
#define BARX() do { __builtin_amdgcn_s_barrier(); asm volatile("" ::: "memory"); } while (0)

    // prologue: burst tile 0 -> buf 0
    BURST(0, 0);
    VMW(4); BARX();                 // A0,B0 resident; B1,A1 (4 loads) in flight

    for (int t = 0; t < NT - 1; ++t) {
        const int b = t & 1, nb = b ^ 1;
        // phase 0: quadrant (A0,B0); burst ALL of tile t+1
        LOADA(b, 0);
        LOADB(b, 0);
        BURST(nb, t + 1);           // outstanding: 4 + 8 = 12
        MFMAQ(0, 0);
        VMW(10); BARX();            // forces B1(t)
        // phase 1: quadrant (A0,B1)
        LOADB(b, 1);
        MFMAQ(0, 1);
        VMW(8); BARX();             // forces A1(t)
        // phase 2: quadrant (A1,B1); no wait/barrier (phase 3 reads no new LDS)
        LOADA(b, 1);
        MFMAQ(1, 1);
        // phase 3: quadrant (A1,B0)
        MFMAQ(1, 0);
        VMW(4); BARX();             // forces A0(t+1),B0(t+1) for next tile
    }
    {   // last k-tile: no burst, drain 2 -> 0
        const int b = (NT - 1) & 1;
        LOADA(b, 0);
        LOADB(b, 0);
        MFMAQ(0, 0);
        VMW(2); BARX();             // forces B1
        LOADB(b, 1);
        MFMAQ(0, 1);
        VMW(0); BARX();             // forces A1
        LOADA(b, 1);
        MFMAQ(1, 1);
        MFMAQ(1, 0);
    }

    if constexpr (MODE == 0) {
        (void)kz; (void)Pp;
        u16* d = (n0 < D_INNER) ? o0 : o1;
        const int nb0 = (n0 < D_INNER) ? n0 : n0 - D_INNER;
#pragma unroll
        for (int i = 0; i < 8; i++) {
            const int mrow = m0 + wr * 64 + (i & 3) * 16 + (i >> 2) * 128 + quad * 4;
#pragma unroll
            for (int j = 0; j < 4; j++) {
                const int ncol = nb0 + wc * 32 + (j & 1) * 16 + (j >> 1) * 128 + l15;
#pragma unroll
                for (int r = 0; r < 4; r++)
                    d[(size_t)(mrow + r) * D_INNER + ncol] = f2bf(acc[i][j][r]);
            }
        }
    } else {
        (void)o0; (void)o1;
        float* d = Pp + (size_t)kz * MROWS * D_MODEL;
#pragma unroll
        for (int i = 0; i < 8; i++) {
            const int mrow = m0 + wr * 64 + (i & 3) * 16 + (i >> 2) * 128 + quad * 4;
#pragma unroll
            for (int j = 0; j < 4; j++) {
                const int ncol = n0 + wc * 32 + (j & 1) * 16 + (j >> 1) * 128 + l15;
#pragma unroll
                for (int r = 0; r < 4; r++)
                    d[(size_t)(mrow + r) * D_MODEL + ncol] = acc[i][j][r];
            }
        }
    }
#undef STAGE_A
#undef STAGE_B
#undef BURST
#undef LOADA
#undef LOADB
#undef MFMAQ
#undef VMW
#undef BARX
}

// ---------------------------------------------------------------------------
__global__ __launch_bounds__(256) void reduce_out(const float* __restrict__ Pp, void* __restrict__ out,
                                                  const int* __restrict__ flag) {
    int i = blockIdx.x * 256 + threadIdx.x;   // < MROWS*D_MODEL
    float s = 0.f;
#pragma unroll
    for (int z = 0; z < KSP6; z++) s += Pp[(size_t)z * MROWS * D_MODEL + i];
    if (*flag) ((u16*)out)[i] = f2bf(s);
    else       ((float*)out)[i] = s;
}

// ---------------------------------------------------------------------------
// K3: proj split-K MFMA.  A = xs [4096][4096], Bt = xpwT [128(pad)][4096].
__global__ __launch_bounds__(256) void gemm_proj(const u16* __restrict__ A, const u16* __restrict__ Bt,
                                                 float* __restrict__ Pp) {
    const int K = D_INNER;
    __shared__ __align__(16) u16 sA[128 * 32];
    __shared__ __align__(16) u16 sB[128 * 32];
    int tid = threadIdx.x;
    int lane = tid & 63;
    int wave = tid >> 6;
    int wm = (wave >> 1) * 64, wn = (wave & 1) * 64;
    int quad = lane >> 4, l15 = lane & 15;
    int m0 = blockIdx.y * 128;
    int kz = blockIdx.x;
    int kbase = kz * (K / KSPLIT);

    floatx4 acc[4][4];
#pragma unroll
    for (int i = 0; i < 4; i++)
#pragma unroll
        for (int j = 0; j < 4; j++) acc[i][j] = (floatx4)0.f;

    const u16* ga0 = A + (size_t)(m0 + (tid >> 2)) * K + (tid & 3) * 8;
    const u16* ga1 = A + (size_t)(m0 + 64 + (tid >> 2)) * K + (tid & 3) * 8;
    const u16* gb0 = Bt + (size_t)(tid >> 2) * K + (tid & 3) * 8;
    const u16* gb1 = Bt + (size_t)(64 + (tid >> 2)) * K + (tid & 3) * 8;
    u16* la0 = &sA[tid * 8];
    u16* la1 = &sA[(256 + tid) * 8];
    u16* lb0 = &sB[tid * 8];
    u16* lb1 = &sB[(256 + tid) * 8];

    for (int k0 = kbase; k0 < kbase + K / KSPLIT; k0 += 32) {
        async_cp16(ga0 + k0, la0);
        async_cp16(ga1 + k0, la1);
        async_cp16(gb0 + k0, lb0);
        async_cp16(gb1 + k0, lb1);
        __syncthreads();
        short8 af[4], bf[4];
#pragma unroll
        for (int i = 0; i < 4; i++) {
            af[i] = *(const short8*)&sA[(wm + i * 16 + l15) * 32 + quad * 8];
            bf[i] = *(const short8*)&sB[(wn + i * 16 + l15) * 32 + quad * 8];
        }
#pragma unroll
        for (int i = 0; i < 4; i++)
#pragma unroll
            for (int j = 0; j < 4; j++)
                acc[i][j] = __builtin_amdgcn_mfma_f32_16x16x32_bf16(af[i], bf[j], acc[i][j], 0, 0, 0);
        __syncthreads();
    }

    float* d = Pp + (size_t)kz * MROWS * PST;
#pragma unroll
    for (int i = 0; i < 4; i++)
#pragma unroll
        for (int j = 0; j < 4; j++)
#pragma unroll
            for (int r = 0; r < 4; r++) {
                int mm = m0 + wm + i * 16 + quad * 4 + r;
                int nn = wn + j * 16 + l15;
                d[(size_t)mm * PST + nn] = acc[i][j][r];
            }
}

// ---------------------------------------------------------------------------
// reduce split-K partials -> proj fp32 [4096][PST]; also emit proj_lo bf16.
__global__ __launch_bounds__(256) void reduce_proj(const float* __restrict__ Pp, float* __restrict__ proj,
                                                   u16* __restrict__ proj_lo) {
    int i = blockIdx.x * 256 + threadIdx.x;    // < MROWS*PST
    float s = 0.f;
#pragma unroll
    for (int z = 0; z < KSPLIT; z++) s += Pp[(size_t)z * MROWS * PST + i];
    proj[i] = s;
    int col = i & (PST - 1);
    if (col < DT_RANK) proj_lo[(size_t)(i >> 7) * DT_RANK + col] = f2bf(s);
}

// ---------------------------------------------------------------------------
// K4: dt = softplus(proj_lo @ dtwT^T + b) via MFMA.  M=4096, N=4096, K=64.
// Epilogue: fast softplus + LDS bounce (stride-132 pad) -> coalesced 16B stores.
__global__ __launch_bounds__(256) void gemm_dt(const u16* __restrict__ A, const u16* __restrict__ Bt,
                                               const u16* __restrict__ dtb, u16* __restrict__ dt) {
    const int K = DT_RANK;   // 64
    __shared__ __align__(16) u16 smem[64 * 132];   // 16.9 KB; k-loop uses first 16 KB
    u16* sA = smem;
    u16* sB = smem + 128 * 32;
    int tid = threadIdx.x;
    int lane = tid & 63;
    int wave = tid >> 6;
    int wm = (wave >> 1) * 64, wn = (wave & 1) * 64;
    int quad = lane >> 4, l15 = lane & 15;
    int m0 = blockIdx.y * 128, n0 = blockIdx.x * 128;

    floatx4 acc[4][4];
#pragma unroll
    for (int i = 0; i < 4; i++)
#pragma unroll
        for (int j = 0; j < 4; j++) acc[i][j] = (floatx4)0.f;

    const u16* ga0 = A + (size_t)(m0 + (tid >> 2)) * K + (tid & 3) * 8;
    const u16* ga1 = A + (size_t)(m0 + 64 + (tid >> 2)) * K + (tid & 3) * 8;
    const u16* gb0 = Bt + (size_t)(n0 + (tid >> 2)) * K + (tid & 3) * 8;
    const u16* gb1 = Bt + (size_t)(n0 + 64 + (tid >> 2)) * K + (tid & 3) * 8;
    u16* la0 = &sA[tid * 8];
    u16* la1 = &sA[(256 + tid) * 8];
    u16* lb0 = &sB[tid * 8];
    u16* lb1 = &sB[(256 + tid) * 8];

    for (int k0 = 0; k0 < K; k0 += 32) {
        async_cp16(ga0 + k0, la0);
        async_cp16(ga1 + k0, la1);
        async_cp16(gb0 + k0, lb0);
        async_cp16(gb1 + k0, lb1);
        __syncthreads();
        short8 af[4], bf[4];
#pragma unroll
        for (int i = 0; i < 4; i++) {
            af[i] = *(const short8*)&sA[(wm + i * 16 + l15) * 32 + quad * 8];
            bf[i] = *(const short8*)&sB[(wn + i * 16 + l15) * 32 + quad * 8];
        }
#pragma unroll
        for (int i = 0; i < 4; i++)
#pragma unroll
            for (int j = 0; j < 4; j++)
                acc[i][j] = __builtin_amdgcn_mfma_f32_16x16x32_bf16(af[i], bf[j], acc[i][j], 0, 0, 0);
        __syncthreads();
    }

#pragma unroll
    for (int h = 0; h < 2; h++) {
        __syncthreads();
        if (wm == h * 64) {
#pragma unroll
            for (int j = 0; j < 4; j++) {
                int col = wn + j * 16 + l15;
                float b = bf2f(dtb[n0 + col]);
#pragma unroll
                for (int i = 0; i < 4; i++)
#pragma unroll
                    for (int r = 0; r < 4; r++) {
                        int row = i * 16 + quad * 4 + r;   // 0..63 within half
                        smem[row * 132 + col] = f2bf(softplus_fast(acc[i][j][r] + b));
                    }
            }
        }
        __syncthreads();
#pragma unroll
        for (int p = 0; p < 4; p++) {
            int row = p * 16 + (tid >> 4);
            int chunk = tid & 15;
            uint4 v = *(const uint4*)&smem[row * 132 + chunk * 8];
            *(uint4*)&dt[(size_t)(m0 + h * 64 + row) * D_INNER + n0 + chunk * 8] = v;
        }
    }
}

// ---------------------------------------------------------------------------
// K2: causal depthwise conv1d + silu (bf16 in/out)
__global__ __launch_bounds__(256) void conv_silu(const u16* __restrict__ xc, const u16* __restrict__ cw,
                                                 const u16* __restrict__ cb, u16* __restrict__ xs) {
    int idx = blockIdx.x * 256 + threadIdx.x;
    int d = idx & (D_INNER - 1);
    int t = (idx >> 12) & (SEQLEN - 1);
    int b = idx >> 23;
    float w0 = bf2f(cw[d * 4 + 0]), w1 = bf2f(cw[d * 4 + 1]);
    float w2 = bf2f(cw[d * 4 + 2]), w3 = bf2f(cw[d * 4 + 3]);
    float acc = bf2f(cb[d]);
    size_t base = (size_t)b * SEQLEN * D_INNER + d;
    if (t >= 3) acc += bf2f(xc[base + (size_t)(t - 3) * D_INNER]) * w0;
    if (t >= 2) acc += bf2f(xc[base + (size_t)(t - 2) * D_INNER]) * w1;
    if (t >= 1) acc += bf2f(xc[base + (size_t)(t - 1) * D_INNER]) * w2;
    acc += bf2f(xc[base + (size_t)t * D_INNER]) * w3;
    xs[idx] = f2bf(acc * sigmoid_fast(acc));
}

// ---------------------------------------------------------------------------
// K5a: chunked scan phase 1 — per (b,d,chunk) thread, 16 states in registers.
// B row is wave-uniform (depends on t only) -> read direct from global
// (compiler promotes to s_load); dt/xs HBM streams prefetched 1 step ahead.
__global__ __launch_bounds__(256) void scan_phase1(const float* __restrict__ proj, const u16* __restrict__ dt,
                                                   const float* __restrict__ A, const u16* __restrict__ xs,
                                                   float* __restrict__ hloc, float* __restrict__ Ssum) {
    int d = blockIdx.x * 256 + threadIdx.x;
    int c = blockIdx.y, b = blockIdx.z;
    int t0 = c * TC;
    float Areg[16];   // prescaled by log2e for raw v_exp_f32
    {
        const float4* Ap = (const float4*)(A + (size_t)d * 16);
#pragma unroll
        for (int n = 0; n < 4; n++) {
            float4 v = Ap[n];
            Areg[n * 4 + 0] = v.x * LOG2E; Areg[n * 4 + 1] = v.y * LOG2E;
            Areg[n * 4 + 2] = v.z * LOG2E; Areg[n * 4 + 3] = v.w * LOG2E;
        }
    }
    float h[16];
#pragma unroll
    for (int n = 0; n < 16; n++) h[n] = 0.f;
    float S = 0.f;
    size_t base = ((size_t)b * SEQLEN + t0) * D_INNER + d;
    const float* prow = proj + ((size_t)b * SEQLEN + t0) * PST + DT_RANK;
    u16 dcur = dt[base], ucur = xs[base];
    for (int t = 0; t < TC; t++) {
        size_t nidx = base + (size_t)((t + 1 < TC) ? t + 1 : t) * D_INNER;
        u16 dnxt = dt[nidx];
        u16 unxt = xs[nidx];
        float4 B0 = *(const float4*)(prow + t * PST + 0);
        float4 B1 = *(const float4*)(prow + t * PST + 4);
        float4 B2 = *(const float4*)(prow + t * PST + 8);
        float4 B3 = *(const float4*)(prow + t * PST + 12);
        float dtv = bf2f(dcur), u = bf2f(ucur);
        S += dtv;
        float du = dtv * u;
        float Bf[16] = {B0.x, B0.y, B0.z, B0.w, B1.x, B1.y, B1.z, B1.w,
                        B2.x, B2.y, B2.z, B2.w, B3.x, B3.y, B3.z, B3.w};
#pragma unroll
        for (int n = 0; n < 16; n++)
            h[n] = h[n] * exp2_hw(dtv * Areg[n]) + du * Bf[n];
        dcur = dnxt; ucur = unxt;
    }
    float* hp = &hloc[(((size_t)b * NC + c) * D_INNER + d) * 16];
#pragma unroll
    for (int n = 0; n < 16; n += 4)
        *(float4*)&hp[n] = make_float4(h[n], h[n + 1], h[n + 2], h[n + 3]);
    Ssum[((size_t)b * NC + c) * D_INNER + d] = S;
}

// ---------------------------------------------------------------------------
// K5b: combine chunks serially (in place: hloc becomes h_init per chunk).
__global__ __launch_bounds__(256) void scan_phase2(const float* __restrict__ A, const float* __restrict__ Ssum,
                                                   float* __restrict__ hloc) {
    int tid = blockIdx.x * 256 + threadIdx.x;
    int n = tid & 15;
    int d = (tid >> 4) & (D_INNER - 1);
    int b = tid >> 16;
    float An2 = A[d * 16 + n] * LOG2E;
    float h = 0.f;
    for (int c = 0; c < NC; c++) {
        size_t idx = (((size_t)b * NC + c) * D_INNER + d) * 16 + n;
        float hl = hloc[idx];
        float S = Ssum[((size_t)b * NC + c) * D_INNER + d];
        hloc[idx] = h;
        h = hl + h * exp2_hw(An2 * S);
    }
}

// ---------------------------------------------------------------------------
// K5c: phase 3 — rerun chunk with h_init, compute y, D-residual, silu(z) gate.
// B/C rows wave-uniform -> direct global (s_load); dt/xs/z prefetched 1 ahead.
__global__ __launch_bounds__(256) void scan_phase3(const float* __restrict__ proj, const u16* __restrict__ dt,
                                                   const float* __restrict__ A, const u16* __restrict__ D16,
                                                   const float* __restrict__ hinit, const u16* __restrict__ z16,
                                                   u16* __restrict__ xs) {
    int d = blockIdx.x * 256 + threadIdx.x;
    int c = blockIdx.y, b = blockIdx.z;
    int t0 = c * TC;
    float Areg[16];   // prescaled by log2e
    {
        const float4* Ap = (const float4*)(A + (size_t)d * 16);
#pragma unroll
        for (int n = 0; n < 4; n++) {
            float4 v = Ap[n];
            Areg[n * 4 + 0] = v.x * LOG2E; Areg[n * 4 + 1] = v.y * LOG2E;
            Areg[n * 4 + 2] = v.z * LOG2E; Areg[n * 4 + 3] = v.w * LOG2E;
        }
    }
    float h[16];
    {
        const float* hp = &hinit[(((size_t)b * NC + c) * D_INNER + d) * 16];
#pragma unroll
        for (int n = 0; n < 16; n += 4) {
            float4 v = *(const float4*)&hp[n];
            h[n] = v.x; h[n + 1] = v.y; h[n + 2] = v.z; h[n + 3] = v.w;
        }
    }
    float Dd = bf2f(D16[d]);
    size_t base = ((size_t)b * SEQLEN + t0) * D_INNER + d;
    const float* prow = proj + ((size_t)b * SEQLEN + t0) * PST + DT_RANK;
    u16 dcur = dt[base], ucur = xs[base], zcur = z16[base];
    for (int t = 0; t < TC; t++) {
        size_t nidx = base + (size_t)((t + 1 < TC) ? t + 1 : t) * D_INNER;
        u16 dnxt = dt[nidx];
        u16 unxt = xs[nidx];
        u16 znxt = z16[nidx];
        float4 B0 = *(const float4*)(prow + t * PST + 0);
        float4 B1 = *(const float4*)(prow + t * PST + 4);
        float4 B2 = *(const float4*)(prow + t * PST + 8);
        float4 B3 = *(const float4*)(prow + t * PST + 12);
        float4 C0 = *(const float4*)(prow + t * PST + 16);
        float4 C1 = *(const float4*)(prow + t * PST + 20);
        float4 C2 = *(const float4*)(prow + t * PST + 24);
        float4 C3 = *(const float4*)(prow + t * PST + 28);
        float dtv = bf2f(dcur), u = bf2f(ucur), zv = bf2f(zcur);
        float du = dtv * u;
        float Bf[16] = {B0.x, B0.y, B0.z, B0.w, B1.x, B1.y, B1.z, B1.w,
                        B2.x, B2.y, B2.z, B2.w, B3.x, B3.y, B3.z, B3.w};
        float Cf[16] = {C0.x, C0.y, C0.z, C0.w, C1.x, C1.y, C1.z, C1.w,
                        C2.x, C2.y, C2.z, C2.w, C3.x, C3.y, C3.z, C3.w};
        float y = 0.f;
#pragma unroll
        for (int n = 0; n < 16; n++) {
            h[n] = h[n] * exp2_hw(dtv * Areg[n]) + du * Bf[n];
            y += h[n] * Cf[n];
        }
        float gate = zv * sigmoid_fast(zv);
        xs[base + (size_t)t * D_INNER] = f2bf((y + u * Dd) * gate);
        dcur = dnxt; ucur = unxt; zcur = znxt;
    }
}

// ---------------------------------------------------------------------------
extern "C" void kernel_launch(void* const* d_in, const int* in_sizes, int n_in,
                              void* d_out, int out_size, void* d_ws, size_t ws_size,
                              hipStream_t stream) {
    const void* x          = d_in[0];
    const void* in_proj_w  = d_in[1];
    const void* conv_w     = d_in[2];
    const void* conv_b     = d_in[3];
    const void* x_proj_w   = d_in[4];
    const void* dt_proj_w  = d_in[5];
    const void* dt_proj_b  = d_in[6];
    const void* A_log      = d_in[7];
    const void* Dvec       = d_in[8];
    const void* out_proj_w = d_in[9];

    char* w = (char*)d_ws;
    const size_t MB = 1024 * 1024;
    const size_t KB = 1024;
    // Overlay plan (stream order guarantees safety):
    //   5-37 MB  : xc (K1 out, dead after conv) -> dt16 -> Pp6 lower half
    //  37-69 MB  : z (dead after scan_phase3)   -> Pp6 upper half
    //  69-101 MB : xs (conv out) -> gated y (K6 A operand)
    // 101-126 MB : x16+ipwT (dead after K1) -> Pp (dead after reduce) -> hloc
    int*   flag    = (int*)(w + 0);
    float* Aws     = (float*)(w + 1 * KB);          // 256 KB
    float* proj    = (float*)(w + 1 * MB);          // 2 MB fp32 [4096][PST=128]
    u16*   cw16    = (u16*)(w + 3 * MB);            // 32 KB
    u16*   cb16    = (u16*)(w + 3 * MB + 64 * KB);  // 8 KB
    u16*   dtb16   = (u16*)(w + 3 * MB + 128 * KB); // 8 KB
    u16*   D16     = (u16*)(w + 3 * MB + 192 * KB); // 8 KB
    u16*   proj_lo = (u16*)(w + 3 * MB + 512 * KB); // 512 KB bf16 [4096][64]
    u16*   dtwT    = (u16*)(w + 4 * MB);            // 512 KB bf16 [4096][64]
    u16*   buf1    = (u16*)(w + 5 * MB);            // 32 MB: xc then dt16
    u16*   dt16    = buf1;
    u16*   zbuf    = (u16*)(w + 37 * MB);           // 32 MB: z
    float* Pp6     = (float*)(w + 5 * MB);          // 64 MB: K6 partials (post-scan)
    u16*   xs      = (u16*)(w + 69 * MB);           // 32 MB: xs then gated y
    u16*   x16     = (u16*)(w + 101 * MB);          // 8.4 MB  (dead after K1)
    u16*   ipwT    = (u16*)(w + 110 * MB);          // 16.8 MB (dead after K1)
    float* Pp      = (float*)(w + 101 * MB);        // 16 MB (post-K1, dead after reduce)
    float* hloc    = (float*)(w + 101 * MB);        // 16 MB (post-reduce, NC=32)
    float* Ssum    = (float*)(w + 117 * MB);        // 1 MB  (post-K1)
    u16*   opwT    = (u16*)(w + 127 * MB);          // 8.4 MB: out_proj_w^T [1024][4096]
    u16*   xpwT    = (u16*)(w + 136 * MB);          // 1 MB: x_proj_w^T [96(pad128)][4096]
    // total 137 MB (<150 MB proven available)

    detect_dtype<<<dim3(1), dim3(256), 0, stream>>>((const u16*)x, flag);
    prep_small<<<dim3(256), dim3(256), 0, stream>>>(conv_w, conv_b, dt_proj_b, Dvec, A_log,
                                                    cw16, cb16, dtb16, D16, Aws, flag);
    ingest16<<<dim3(MROWS * D_MODEL / 256), dim3(256), 0, stream>>>(x, x16, MROWS * D_MODEL, flag);
    transpose_w<<<dim3(2 * D_INNER / 32, D_MODEL / 32), dim3(256), 0, stream>>>(in_proj_w, ipwT, D_MODEL, 2 * D_INNER, flag);
    transpose_w<<<dim3(D_MODEL / 32, D_INNER / 32), dim3(256), 0, stream>>>(out_proj_w, opwT, D_INNER, D_MODEL, flag);
    transpose_w<<<dim3(NPROJ / 32, D_INNER / 32), dim3(256), 0, stream>>>(x_proj_w, xpwT, D_INNER, NPROJ, flag);
    transpose_w<<<dim3(D_INNER / 32, DT_RANK / 32), dim3(256), 0, stream>>>(dt_proj_w, dtwT, DT_RANK, D_INNER, flag);

    // K1: xz = x @ Win -> xc (buf1) + z (zbuf); 256^2-tile burst-stage, 512 blocks
    gemm8p<1024, 0><<<dim3(512), dim3(512), 0, stream>>>(x16, ipwT, buf1, zbuf, nullptr);
    // K2: conv + silu -> xs
    conv_silu<<<dim3(MROWS * D_INNER / 256), dim3(256), 0, stream>>>(buf1, cw16, cb16, xs);
    // K3: proj via split-K MFMA + reduce (also emits proj_lo bf16)
    gemm_proj<<<dim3(KSPLIT, MROWS / 128), dim3(256), 0, stream>>>(xs, xpwT, Pp);
    reduce_proj<<<dim3(MROWS * PST / 256), dim3(256), 0, stream>>>(Pp, proj, proj_lo);
    // K4: dt via MFMA, fused bias+fast-softplus (dt16 overlays dead xc)
    gemm_dt<<<dim3(D_INNER / 128, MROWS / 128), dim3(256), 0, stream>>>(proj_lo, dtwT, dtb16, dt16);
    // K5: chunked scan (NC=32; uniform B/C reads, no LDS, 1-step prefetch)
    scan_phase1<<<dim3(D_INNER / 256, NC, BATCH), dim3(256), 0, stream>>>(proj, dt16, Aws, xs, hloc, Ssum);
    scan_phase2<<<dim3(BATCH * D_INNER * D_STATE / 256), dim3(256), 0, stream>>>(Aws, Ssum, hloc);
    scan_phase3<<<dim3(D_INNER / 256, NC, BATCH), dim3(256), 0, stream>>>(proj, dt16, Aws, D16, hloc, zbuf, xs);
    // K6: out = y @ out_proj_w; 256^2-tile burst-stage split-K (dt16/zbuf dead -> Pp6) + reduce
    gemm8p<4096, 1><<<dim3(D_MODEL / 256, MROWS / 256, KSP6), dim3(512), 0, stream>>>(xs, opwT, nullptr, nullptr, Pp6);
    reduce_out<<<dim3(MROWS * D_MODEL / 256), dim3(256), 0, stream>>>(Pp6, d_out, flag);
}

// Round 5
// 490.207 us; speedup vs baseline: 1.1109x; 1.0201x over previous
//
#include <hip/hip_runtime.h>
#include <hip/hip_bf16.h>

// Problem constants
#define D_MODEL 1024
#define D_INNER 4096
#define D_STATE 16
#define D_CONV 4
#define DT_RANK 64
#define BATCH 2
#define SEQLEN 2048
#define MROWS (BATCH * SEQLEN)          // 4096
#define NPROJ (DT_RANK + 2 * D_STATE)   // 96
#define PST 128                         // proj row stride (padded, fp32)
#define NC 32                           // scan chunks
#define TC (SEQLEN / NC)                // 64 steps per chunk
#define KSPLIT 8                        // split-K for proj gemm
#define KSP6 4                          // split-K for out gemm

typedef unsigned short u16;
typedef unsigned int u32;
typedef __attribute__((ext_vector_type(8))) short short8;
typedef __attribute__((ext_vector_type(4))) float floatx4;

#define LOG2E 1.44269504089f

__device__ __forceinline__ float bf2f(u16 u) {
    union { u32 i; float f; } v; v.i = ((u32)u) << 16; return v.f;
}
__device__ __forceinline__ u16 f2bf(float f) {
    union { float f; u32 i; } v; v.f = f;
    u32 x = v.i;
    u32 r = x + 0x7fffu + ((x >> 16) & 1u);   // round to nearest even
    return (u16)(r >> 16);
}
// fast softplus: hardware exp/log; |err| << bf16 ulp for all finite x
__device__ __forceinline__ float softplus_fast(float x) {
    float l = __logf(1.f + __expf(-fabsf(x)));
    return x > 0.f ? x + l : l;
}
// fast sigmoid: v_exp + v_rcp (1 ulp), no exact-division sequence
__device__ __forceinline__ float sigmoid_fast(float x) {
    return __builtin_amdgcn_rcpf(1.f + __expf(-x));
}
// raw hardware 2^x (single v_exp_f32; caller pre-scales by log2e)
__device__ __forceinline__ float exp2_hw(float x) {
    float r;
    asm("v_exp_f32 %0, %1" : "=v"(r) : "v"(x));
    return r;
}
// async global->LDS 16B DMA (dest = wave-uniform base + lane*16)
__device__ __forceinline__ void async_cp16(const u16* g, u16* l) {
    __builtin_amdgcn_global_load_lds((const __attribute__((address_space(1))) void*)g,
                                     (__attribute__((address_space(3))) void*)l, 16, 0, 0);
}

// ---------------------------------------------------------------------------
// D0: detect input dtype (bf16 vs fp32) from exponent-field statistics.
__global__ __launch_bounds__(256) void detect_dtype(const u16* __restrict__ x, int* __restrict__ flag) {
    __shared__ int cnt;
    if (threadIdx.x == 0) cnt = 0;
    __syncthreads();
    int local = 0;
    for (int k = 0; k < 16; k++) {
        int e = threadIdx.x * 8192 + k * 512;
        u16 v = x[2 * e];
        int ex = (v >> 7) & 0xFF;
        if (ex >= 0x68 && ex <= 0x8F) local++;
    }
    atomicAdd(&cnt, local);
    __syncthreads();
    if (threadIdx.x == 0) *flag = (cnt >= 2458) ? 1 : 0;
}

// ---------------------------------------------------------------------------
__global__ __launch_bounds__(256) void ingest16(const void* __restrict__ src, u16* __restrict__ dst,
                                                int n, const int* __restrict__ flag) {
    int i = blockIdx.x * 256 + threadIdx.x;
    if (i >= n) return;
    if (*flag) dst[i] = ((const u16*)src)[i];
    else       dst[i] = f2bf(((const float*)src)[i]);
}

// ---------------------------------------------------------------------------
// Fused small-tensor prologue: conv_w, conv_b, dt_proj_b, D ingest + A=-exp(A_log).
__global__ __launch_bounds__(256) void prep_small(const void* __restrict__ cw, const void* __restrict__ cb,
                                                  const void* __restrict__ dtb, const void* __restrict__ Dv,
                                                  const void* __restrict__ Alog,
                                                  u16* __restrict__ cw16, u16* __restrict__ cb16,
                                                  u16* __restrict__ dtb16, u16* __restrict__ D16,
                                                  float* __restrict__ A, const int* __restrict__ flag) {
    int i = blockIdx.x * 256 + threadIdx.x;   // grid covers 65536
    int isb = *flag;
    if (i < D_INNER * D_CONV)
        cw16[i] = isb ? ((const u16*)cw)[i] : f2bf(((const float*)cw)[i]);
    if (i < D_INNER) {
        cb16[i]  = isb ? ((const u16*)cb)[i]  : f2bf(((const float*)cb)[i]);
        dtb16[i] = isb ? ((const u16*)dtb)[i] : f2bf(((const float*)dtb)[i]);
        D16[i]   = isb ? ((const u16*)Dv)[i]  : f2bf(((const float*)Dv)[i]);
    }
    if (i < D_INNER * D_STATE) {
        float v = isb ? bf2f(((const u16*)Alog)[i]) : ((const float*)Alog)[i];
        A[i] = -expf(v);
    }
}

// ---------------------------------------------------------------------------
// Transpose-ingest: W [K][N] (dual dtype) -> WT [N][K] bf16.
__global__ __launch_bounds__(256) void transpose_w(const void* __restrict__ W, u16* __restrict__ WT,
                                                   int K, int N, const int* __restrict__ flag) {
    __shared__ float t[32][33];
    int k0 = blockIdx.y * 32, n0 = blockIdx.x * 32;
    int tid = threadIdx.x;
    int r = tid >> 3, c4 = (tid & 7) * 4;
    int isb = *flag;
    size_t base = (size_t)(k0 + r) * N + n0 + c4;
    float4 v;
    if (isb) { ushort4 u4 = *(const ushort4*)((const u16*)W + base);
               v = make_float4(bf2f(u4.x), bf2f(u4.y), bf2f(u4.z), bf2f(u4.w)); }
    else     { v = *(const float4*)((const float*)W + base); }
    t[c4 + 0][r] = v.x; t[c4 + 1][r] = v.y; t[c4 + 2][r] = v.z; t[c4 + 3][r] = v.w;
    __syncthreads();
    u16* o = WT + (size_t)(n0 + r) * K + k0 + c4;
    o[0] = f2bf(t[r][c4 + 0]);
    o[1] = f2bf(t[r][c4 + 1]);
    o[2] = f2bf(t[r][c4 + 2]);
    o[3] = f2bf(t[r][c4 + 3]);
}

// ---------------------------------------------------------------------------
// 256x256-tile 4-phase GEMM with the m201 read/barrier sandwich.
//
// A [M][KS] bf16 row-major, Bt [N][KS] bf16 row-major.
// 512 threads = 8 waves (2M x 4N); per-wave output 128x64, chunk-interleaved:
//   M-frag i: row = wr*64 + (i&3)*16 + (i>>2)*128  -> A-chunk (i>>2)
//   N-frag j: col = wc*32 + (j&1)*16 + (j>>1)*128  -> B-chunk (j>>1)
// K-tile = 64; each tile = 4 chunks (A0,A1,B0,B1) of 128x64 bf16 = 16 KB.
//
// Per-phase skeleton (m201 sandwich): {ds_read subtile; stage 1 chunk;
// sched_barrier(0); s_barrier; s_waitcnt lgkmcnt(0); sched_barrier(0);
// setprio(1); 16 MFMA; setprio(0); counted vmcnt; s_barrier}.
// The mid-phase barrier lets ds_read latency drain during barrier-arrival
// skew instead of serializing in front of the MFMA cluster (the ~950cyc/phase
// stall that held r0/r3 variants at 34% MfmaUtil).
//
// vmcnt ledger (2 loads/chunk, stage order per tile A0',B0',B1',A1' into the
// dead buffer, matching next tile's consumption order):
//   boundary VMW(4): forces A0',B0'  (staged 4 and 3 phases ago)
//   end-ph0 VMW(4): forces B1(t)     (staged 3 phases ago)
//   end-ph1 VMW(4): forces A1(t)     (staged 3 phases ago)
//   ph2/ph3: no wait; ph3 has no mid-barrier (no LDS reads).
// Every wait forces only >=3-phase-old loads -> ~free. Epilogue drains 2->0.
// LDS reads XOR-swizzled (col ^= (row&7)*8 elems); global_load_lds dest stays
// linear, the *global source* is inverse-swizzled (both-sides rule, m173).
//
// MODE 0: C bf16, split to o0/o1 at col D_INNER (in-proj). KS=1024, grid 512,
//         bijective XCD swizzle. MODE 1: fp32 split-K partials Pp[z][M][1024]
//         (out-proj). KS=4096, grid (4,16,KSP6).
template<int KS, int MODE>
__global__ __launch_bounds__(512, 2) void gemm8p(const u16* __restrict__ A, const u16* __restrict__ Bt,
                                                 u16* __restrict__ o0, u16* __restrict__ o1,
                                                 float* __restrict__ Pp) {
    __shared__ __align__(16) u16 lds[65536];   // 128 KB: A = 2buf x 2chunk x 8192 u16; B at +32768
    const int tid = threadIdx.x;
    const int lane = tid & 63;
    const int wave = tid >> 6;
    const int wr = wave >> 2, wc = wave & 3;
    const int quad = lane >> 4, l15 = lane & 15;

    int m0, n0, kbase, kz;
    if (MODE == 0) {
        int wgid = (blockIdx.x & 7) * 64 + (blockIdx.x >> 3);   // bijective (512 % 8 == 0)
        m0 = (wgid & 15) * 256;
        n0 = (wgid >> 4) * 256;
        kbase = 0; kz = 0;
    } else {
        m0 = blockIdx.y * 256;
        n0 = blockIdx.x * 256;
        kz = blockIdx.z;
        kbase = kz * 1024;
    }
    const int NT = 1024 / 64;   // 16 k-tiles per block (both modes sweep 1024 of K)

    // ---- staging addressing: linear LDS dest, inverse-swizzled global source
    const int srow = tid >> 3;                              // 0..63 (chunk row, rho adds 64)
    const int kswz = (((tid & 7) ^ (srow & 7)) << 3);       // element offset within 64-wide k
    const u16* pA = A + (size_t)(m0 + srow) * KS + kbase + kswz;
    const u16* pB = Bt + (size_t)(n0 + srow) * KS + kbase + kswz;

    // ---- fragment-read addressing (swizzle term is per-thread constant)
    const int rsw = (l15 & 7) << 3;
    const int ksel0 = (quad * 8) ^ rsw;
    const int ksel1 = (32 + quad * 8) ^ rsw;
    const int aoff = (wr * 64 + l15) * 64;
    const int boff = (wc * 32 + l15) * 64;

    floatx4 acc[8][4];
#pragma unroll
    for (int i = 0; i < 8; i++)
#pragma unroll
        for (int j = 0; j < 4; j++) acc[i][j] = (floatx4)0.f;
    short8 af[4][2];        // current A-chunk frags [ii][ksub]
    short8 bf[2][2][2];     // both B-chunk frags    [chunk][jj][ksub]

#define STAGE_A(nb, h, kt) do { \
    const u16* g_ = pA + (size_t)(h) * 128 * KS + (kt) * 64; \
    u16* l_ = &lds[((nb) * 2 + (h)) * 8192 + tid * 8]; \
    async_cp16(g_, l_); \
    async_cp16(g_ + (size_t)64 * KS, l_ + 4096); \
} while (0)
#define STAGE_B(nb, h, kt) do { \
    const u16* g_ = pB + (size_t)(h) * 128 * KS + (kt) * 64; \
    u16* l_ = &lds[32768 + ((nb) * 2 + (h)) * 8192 + tid * 8]; \
    async_cp16(g_, l_); \
    async_cp16(g_ + (size_t)64 * KS, l_ + 4096); \
} while (0)
#define LOADA(b, h) do { \
    const u16* p_ = &lds[((b) * 2 + (h)) * 8192 + aoff]; \
    _Pragma("unroll") \
    for (int ii = 0; ii < 4; ii++) { \
        af[ii][0] = *(const short8*)(p_ + ii * 1024 + ksel0); \
        af[ii][1] = *(const short8*)(p_ + ii * 1024 + ksel1); \
    } \
} while (0)
#define LOADB(b, h) do { \
    const u16* p_ = &lds[32768 + ((b) * 2 + (h)) * 8192 + boff]; \
    _Pragma("unroll") \
    for (int jj = 0; jj < 2; jj++) { \
        bf[h][jj][0] = *(const short8*)(p_ + jj * 1024 + ksel0); \
        bf[h][jj][1] = *(const short8*)(p_ + jj * 1024 + ksel1); \
    } \
} while (0)
#define MFMAQ(qa, qb) do { \
    __builtin_amdgcn_s_setprio(1); \
    _Pragma("unroll") \
    for (int ii = 0; ii < 4; ii++) \
    _Pragma("unroll") \
    for (int jj = 0; jj < 2; jj++) { \
        floatx4 c_ = acc[(qa) * 4 + ii][(qb) * 2 + jj]; \
        c_ = __builtin_amdgcn_mfma_f32_16x16x32_bf16(af[ii][0], bf[qb][jj][0], c_, 0, 0, 0); \
        c_ = __builtin_amdgcn_mfma_f32_16x16x32_bf16(af[ii][1], bf[qb][jj][1], c_, 0, 0, 0); \
        acc[(qa) * 4 + ii][(qb) * 2 + jj] = c_; \
    } \
    __builtin_amdgcn_s_setprio(0); \
} while (0)
#define VMW(N) asm volatile("s_waitcnt vmcnt(" #N ")" ::: "memory")
#define BARX() do { __builtin_amdgcn_s_barrier(); asm volatile("" ::: "memory"); } while (0)
// m201 sandwich: pin reads before the barrier, MFMA after the lgkm drain.
#define SANDWICH() do { \
    __builtin_amdgcn_sched_barrier(0); \
    __builtin_amdgcn_s_barrier(); \
    asm volatile("s_waitcnt lgkmcnt(0)" ::: "memory"); \
    __builtin_amdgcn_sched_barrier(0); \
} while (0)

    // prologue: stage tile 0 -> buf 0, issue order [A0, B0, B1, A1]
    STAGE_A(0, 0, 0);
    STAGE_B(0, 0, 0);
    STAGE_B(0, 1, 0);
    STAGE_A(0, 1, 0);
    VMW(4); BARX();                 // A0,B0 resident; B1,A1 (4 loads) in flight

    for (int t = 0; t < NT - 1; ++t) {
        const int b = t & 1, nb = b ^ 1;
        // phase 0: quadrant (A0,B0); stage A0(t+1)
        LOADA(b, 0);
        LOADB(b, 0);
        STAGE_A(nb, 0, t + 1);
        SANDWICH();
        MFMAQ(0, 0);
        VMW(4); BARX();             // forces B1(t)
        // phase 1: quadrant (A0,B1); stage B0(t+1)
        LOADB(b, 1);
        STAGE_B(nb, 0, t + 1);
        SANDWICH();
        MFMAQ(0, 1);
        VMW(4); BARX();             // forces A1(t)
        // phase 2: quadrant (A1,B1); stage B1(t+1)
        LOADA(b, 1);
        STAGE_B(nb, 1, t + 1);
        SANDWICH();
        MFMAQ(1, 1);
        // phase 3: quadrant (A1,B0); stage A1(t+1); no mid-barrier (no reads)
        STAGE_A(nb, 1, t + 1);
        MFMAQ(1, 0);
        VMW(4); BARX();             // forces A0(t+1),B0(t+1) for next tile
    }
    {   // last k-tile: no stages, drain 2 -> 0
        const int b = (NT - 1) & 1;
        LOADA(b, 0);
        LOADB(b, 0);
        SANDWICH();
        MFMAQ(0, 0);
        VMW(2); BARX();             // forces B1
        LOADB(b, 1);
        SANDWICH();
        MFMAQ(0, 1);
        VMW(0); BARX();             // forces A1
        LOADA(b, 1);
        MFMAQ(1, 1);
        MFMAQ(1, 0);
    }

    if constexpr (MODE == 0) {
        (void)kz; (void)Pp;
        u16* d = (n0 < D_INNER) ? o0 : o1;
        const int nb0 = (n0 < D_INNER) ? n0 : n0 - D_INNER;
#pragma unroll
        for (int i = 0; i < 8; i++) {
            const int mrow = m0 + wr * 64 + (i & 3) * 16 + (i >> 2) * 128 + quad * 4;
#pragma unroll
            for (int j = 0; j < 4; j++) {
                const int ncol = nb0 + wc * 32 + (j & 1) * 16 + (j >> 1) * 128 + l15;
#pragma unroll
                for (int r = 0; r < 4; r++)
                    d[(size_t)(mrow + r) * D_INNER + ncol] = f2bf(acc[i][j][r]);
            }
        }
    } else {
        (void)o0; (void)o1;
        float* d = Pp + (size_t)kz * MROWS * D_MODEL;
#pragma unroll
        for (int i = 0; i < 8; i++) {
            const int mrow = m0 + wr * 64 + (i & 3) * 16 + (i >> 2) * 128 + quad * 4;
#pragma unroll
            for (int j = 0; j < 4; j++) {
                const int ncol = n0 + wc * 32 + (j & 1) * 16 + (j >> 1) * 128 + l15;
#pragma unroll
                for (int r = 0; r < 4; r++)
                    d[(size_t)(mrow + r) * D_MODEL + ncol] = acc[i][j][r];
            }
        }
    }
#undef STAGE_A
#undef STAGE_B
#undef LOADA
#undef LOADB
#undef MFMAQ
#undef VMW
#undef BARX
#undef SANDWICH
}

// ---------------------------------------------------------------------------
__global__ __launch_bounds__(256) void reduce_out(const float* __restrict__ Pp, void* __restrict__ out,
                                                  const int* __restrict__ flag) {
    int i = blockIdx.x * 256 + threadIdx.x;   // < MROWS*D_MODEL
    float s = 0.f;
#pragma unroll
    for (int z = 0; z < KSP6; z++) s += Pp[(size_t)z * MROWS * D_MODEL + i];
    if (*flag) ((u16*)out)[i] = f2bf(s);
    else       ((float*)out)[i] = s;
}

// ---------------------------------------------------------------------------
// K3: proj split-K MFMA.  A = xs [4096][4096], Bt = xpwT [128(pad)][4096].
__global__ __launch_bounds__(256) void gemm_proj(const u16* __restrict__ A, const u16* __restrict__ Bt,
                                                 float* __restrict__ Pp) {
    const int K = D_INNER;
    __shared__ __align__(16) u16 sA[128 * 32];
    __shared__ __align__(16) u16 sB[128 * 32];
    int tid = threadIdx.x;
    int lane = tid & 63;
    int wave = tid >> 6;
    int wm = (wave >> 1) * 64, wn = (wave & 1) * 64;
    int quad = lane >> 4, l15 = lane & 15;
    int m0 = blockIdx.y * 128;
    int kz = blockIdx.x;
    int kbase = kz * (K / KSPLIT);

    floatx4 acc[4][4];
#pragma unroll
    for (int i = 0; i < 4; i++)
#pragma unroll
        for (int j = 0; j < 4; j++) acc[i][j] = (floatx4)0.f;

    const u16* ga0 = A + (size_t)(m0 + (tid >> 2)) * K + (tid & 3) * 8;
    const u16* ga1 = A + (size_t)(m0 + 64 + (tid >> 2)) * K + (tid & 3) * 8;
    const u16* gb0 = Bt + (size_t)(tid >> 2) * K + (tid & 3) * 8;
    const u16* gb1 = Bt + (size_t)(64 + (tid >> 2)) * K + (tid & 3) * 8;
    u16* la0 = &sA[tid * 8];
    u16* la1 = &sA[(256 + tid) * 8];
    u16* lb0 = &sB[tid * 8];
    u16* lb1 = &sB[(256 + tid) * 8];

    for (int k0 = kbase; k0 < kbase + K / KSPLIT; k0 += 32) {
        async_cp16(ga0 + k0, la0);
        async_cp16(ga1 + k0, la1);
        async_cp16(gb0 + k0, lb0);
        async_cp16(gb1 + k0, lb1);
        __syncthreads();
        short8 af[4], bf[4];
#pragma unroll
        for (int i = 0; i < 4; i++) {
            af[i] = *(const short8*)&sA[(wm + i * 16 + l15) * 32 + quad * 8];
            bf[i] = *(const short8*)&sB[(wn + i * 16 + l15) * 32 + quad * 8];
        }
#pragma unroll
        for (int i = 0; i < 4; i++)
#pragma unroll
            for (int j = 0; j < 4; j++)
                acc[i][j] = __builtin_amdgcn_mfma_f32_16x16x32_bf16(af[i], bf[j], acc[i][j], 0, 0, 0);
        __syncthreads();
    }

    float* d = Pp + (size_t)kz * MROWS * PST;
#pragma unroll
    for (int i = 0; i < 4; i++)
#pragma unroll
        for (int j = 0; j < 4; j++)
#pragma unroll
            for (int r = 0; r < 4; r++) {
                int mm = m0 + wm + i * 16 + quad * 4 + r;
                int nn = wn + j * 16 + l15;
                d[(size_t)mm * PST + nn] = acc[i][j][r];
            }
}

// ---------------------------------------------------------------------------
// reduce split-K partials -> proj fp32 [4096][PST]; also emit proj_lo bf16.
__global__ __launch_bounds__(256) void reduce_proj(const float* __restrict__ Pp, float* __restrict__ proj,
                                                   u16* __restrict__ proj_lo) {
    int i = blockIdx.x * 256 + threadIdx.x;    // < MROWS*PST
    float s = 0.f;
#pragma unroll
    for (int z = 0; z < KSPLIT; z++) s += Pp[(size_t)z * MROWS * PST + i];
    proj[i] = s;
    int col = i & (PST - 1);
    if (col < DT_RANK) proj_lo[(size_t)(i >> 7) * DT_RANK + col] = f2bf(s);
}

// ---------------------------------------------------------------------------
// K4: dt = softplus(proj_lo @ dtwT^T + b) via MFMA.  M=4096, N=4096, K=64.
// Epilogue: fast softplus + LDS bounce (stride-132 pad) -> coalesced 16B stores.
__global__ __launch_bounds__(256) void gemm_dt(const u16* __restrict__ A, const u16* __restrict__ Bt,
                                               const u16* __restrict__ dtb, u16* __restrict__ dt) {
    const int K = DT_RANK;   // 64
    __shared__ __align__(16) u16 smem[64 * 132];   // 16.9 KB; k-loop uses first 16 KB
    u16* sA = smem;
    u16* sB = smem + 128 * 32;
    int tid = threadIdx.x;
    int lane = tid & 63;
    int wave = tid >> 6;
    int wm = (wave >> 1) * 64, wn = (wave & 1) * 64;
    int quad = lane >> 4, l15 = lane & 15;
    int m0 = blockIdx.y * 128, n0 = blockIdx.x * 128;

    floatx4 acc[4][4];
#pragma unroll
    for (int i = 0; i < 4; i++)
#pragma unroll
        for (int j = 0; j < 4; j++) acc[i][j] = (floatx4)0.f;

    const u16* ga0 = A + (size_t)(m0 + (tid >> 2)) * K + (tid & 3) * 8;
    const u16* ga1 = A + (size_t)(m0 + 64 + (tid >> 2)) * K + (tid & 3) * 8;
    const u16* gb0 = Bt + (size_t)(n0 + (tid >> 2)) * K + (tid & 3) * 8;
    const u16* gb1 = Bt + (size_t)(n0 + 64 + (tid >> 2)) * K + (tid & 3) * 8;
    u16* la0 = &sA[tid * 8];
    u16* la1 = &sA[(256 + tid) * 8];
    u16* lb0 = &sB[tid * 8];
    u16* lb1 = &sB[(256 + tid) * 8];

    for (int k0 = 0; k0 < K; k0 += 32) {
        async_cp16(ga0 + k0, la0);
        async_cp16(ga1 + k0, la1);
        async_cp16(gb0 + k0, lb0);
        async_cp16(gb1 + k0, lb1);
        __syncthreads();
        short8 af[4], bf[4];
#pragma unroll
        for (int i = 0; i < 4; i++) {
            af[i] = *(const short8*)&sA[(wm + i * 16 + l15) * 32 + quad * 8];
            bf[i] = *(const short8*)&sB[(wn + i * 16 + l15) * 32 + quad * 8];
        }
#pragma unroll
        for (int i = 0; i < 4; i++)
#pragma unroll
            for (int j = 0; j < 4; j++)
                acc[i][j] = __builtin_amdgcn_mfma_f32_16x16x32_bf16(af[i], bf[j], acc[i][j], 0, 0, 0);
        __syncthreads();
    }

#pragma unroll
    for (int h = 0; h < 2; h++) {
        __syncthreads();
        if (wm == h * 64) {
#pragma unroll
            for (int j = 0; j < 4; j++) {
                int col = wn + j * 16 + l15;
                float b = bf2f(dtb[n0 + col]);
#pragma unroll
                for (int i = 0; i < 4; i++)
#pragma unroll
                    for (int r = 0; r < 4; r++) {
                        int row = i * 16 + quad * 4 + r;   // 0..63 within half
                        smem[row * 132 + col] = f2bf(softplus_fast(acc[i][j][r] + b));
                    }
            }
        }
        __syncthreads();
#pragma unroll
        for (int p = 0; p < 4; p++) {
            int row = p * 16 + (tid >> 4);
            int chunk = tid & 15;
            uint4 v = *(const uint4*)&smem[row * 132 + chunk * 8];
            *(uint4*)&dt[(size_t)(m0 + h * 64 + row) * D_INNER + n0 + chunk * 8] = v;
        }
    }
}

// ---------------------------------------------------------------------------
// K2: causal depthwise conv1d + silu (bf16 in/out)
__global__ __launch_bounds__(256) void conv_silu(const u16* __restrict__ xc, const u16* __restrict__ cw,
                                                 const u16* __restrict__ cb, u16* __restrict__ xs) {
    int idx = blockIdx.x * 256 + threadIdx.x;
    int d = idx & (D_INNER - 1);
    int t = (idx >> 12) & (SEQLEN - 1);
    int b = idx >> 23;
    float w0 = bf2f(cw[d * 4 + 0]), w1 = bf2f(cw[d * 4 + 1]);
    float w2 = bf2f(cw[d * 4 + 2]), w3 = bf2f(cw[d * 4 + 3]);
    float acc = bf2f(cb[d]);
    size_t base = (size_t)b * SEQLEN * D_INNER + d;
    if (t >= 3) acc += bf2f(xc[base + (size_t)(t - 3) * D_INNER]) * w0;
    if (t >= 2) acc += bf2f(xc[base + (size_t)(t - 2) * D_INNER]) * w1;
    if (t >= 1) acc += bf2f(xc[base + (size_t)(t - 1) * D_INNER]) * w2;
    acc += bf2f(xc[base + (size_t)t * D_INNER]) * w3;
    xs[idx] = f2bf(acc * sigmoid_fast(acc));
}

// ---------------------------------------------------------------------------
// K5a: chunked scan phase 1 — per (b,d,chunk) thread, 16 states in registers.
// B row is wave-uniform (depends on t only) -> read direct from global
// (compiler promotes to s_load); dt/xs HBM streams prefetched 1 step ahead.
__global__ __launch_bounds__(256) void scan_phase1(const float* __restrict__ proj, const u16* __restrict__ dt,
                                                   const float* __restrict__ A, const u16* __restrict__ xs,
                                                   float* __restrict__ hloc, float* __restrict__ Ssum) {
    int d = blockIdx.x * 256 + threadIdx.x;
    int c = blockIdx.y, b = blockIdx.z;
    int t0 = c * TC;
    float Areg[16];   // prescaled by log2e for raw v_exp_f32
    {
        const float4* Ap = (const float4*)(A + (size_t)d * 16);
#pragma unroll
        for (int n = 0; n < 4; n++) {
            float4 v = Ap[n];
            Areg[n * 4 + 0] = v.x * LOG2E; Areg[n * 4 + 1] = v.y * LOG2E;
            Areg[n * 4 + 2] = v.z * LOG2E; Areg[n * 4 + 3] = v.w * LOG2E;
        }
    }
    float h[16];
#pragma unroll
    for (int n = 0; n < 16; n++) h[n] = 0.f;
    float S = 0.f;
    size_t base = ((size_t)b * SEQLEN + t0) * D_INNER + d;
    const float* prow = proj + ((size_t)b * SEQLEN + t0) * PST + DT_RANK;
    u16 dcur = dt[base], ucur = xs[base];
    for (int t = 0; t < TC; t++) {
        size_t nidx = base + (size_t)((t + 1 < TC) ? t + 1 : t) * D_INNER;
        u16 dnxt = dt[nidx];
        u16 unxt = xs[nidx];
        float4 B0 = *(const float4*)(prow + t * PST + 0);
        float4 B1 = *(const float4*)(prow + t * PST + 4);
        float4 B2 = *(const float4*)(prow + t * PST + 8);
        float4 B3 = *(const float4*)(prow + t * PST + 12);
        float dtv = bf2f(dcur), u = bf2f(ucur);
        S += dtv;
        float du = dtv * u;
        float Bf[16] = {B0.x, B0.y, B0.z, B0.w, B1.x, B1.y, B1.z, B1.w,
                        B2.x, B2.y, B2.z, B2.w, B3.x, B3.y, B3.z, B3.w};
#pragma unroll
        for (int n = 0; n < 16; n++)
            h[n] = h[n] * exp2_hw(dtv * Areg[n]) + du * Bf[n];
        dcur = dnxt; ucur = unxt;
    }
    float* hp = &hloc[(((size_t)b * NC + c) * D_INNER + d) * 16];
#pragma unroll
    for (int n = 0; n < 16; n += 4)
        *(float4*)&hp[n] = make_float4(h[n], h[n + 1], h[n + 2], h[n + 3]);
    Ssum[((size_t)b * NC + c) * D_INNER + d] = S;
}

// ---------------------------------------------------------------------------
// K5b: combine chunks serially (in place: hloc becomes h_init per chunk).
__global__ __launch_bounds__(256) void scan_phase2(const float* __restrict__ A, const float* __restrict__ Ssum,
                                                   float* __restrict__ hloc) {
    int tid = blockIdx.x * 256 + threadIdx.x;
    int n = tid & 15;
    int d = (tid >> 4) & (D_INNER - 1);
    int b = tid >> 16;
    float An2 = A[d * 16 + n] * LOG2E;
    float h = 0.f;
    for (int c = 0; c < NC; c++) {
        size_t idx = (((size_t)b * NC + c) * D_INNER + d) * 16 + n;
        float hl = hloc[idx];
        float S = Ssum[((size_t)b * NC + c) * D_INNER + d];
        hloc[idx] = h;
        h = hl + h * exp2_hw(An2 * S);
    }
}

// ---------------------------------------------------------------------------
// K5c: phase 3 — rerun chunk with h_init, compute y, D-residual, silu(z) gate.
// B/C rows wave-uniform -> direct global (s_load); dt/xs/z prefetched 1 ahead.
__global__ __launch_bounds__(256) void scan_phase3(const float* __restrict__ proj, const u16* __restrict__ dt,
                                                   const float* __restrict__ A, const u16* __restrict__ D16,
                                                   const float* __restrict__ hinit, const u16* __restrict__ z16,
                                                   u16* __restrict__ xs) {
    int d = blockIdx.x * 256 + threadIdx.x;
    int c = blockIdx.y, b = blockIdx.z;
    int t0 = c * TC;
    float Areg[16];   // prescaled by log2e
    {
        const float4* Ap = (const float4*)(A + (size_t)d * 16);
#pragma unroll
        for (int n = 0; n < 4; n++) {
            float4 v = Ap[n];
            Areg[n * 4 + 0] = v.x * LOG2E; Areg[n * 4 + 1] = v.y * LOG2E;
            Areg[n * 4 + 2] = v.z * LOG2E; Areg[n * 4 + 3] = v.w * LOG2E;
        }
    }
    float h[16];
    {
        const float* hp = &hinit[(((size_t)b * NC + c) * D_INNER + d) * 16];
#pragma unroll
        for (int n = 0; n < 16; n += 4) {
            float4 v = *(const float4*)&hp[n];
            h[n] = v.x; h[n + 1] = v.y; h[n + 2] = v.z; h[n + 3] = v.w;
        }
    }
    float Dd = bf2f(D16[d]);
    size_t base = ((size_t)b * SEQLEN + t0) * D_INNER + d;
    const float* prow = proj + ((size_t)b * SEQLEN + t0) * PST + DT_RANK;
    u16 dcur = dt[base], ucur = xs[base], zcur = z16[base];
    for (int t = 0; t < TC; t++) {
        size_t nidx = base + (size_t)((t + 1 < TC) ? t + 1 : t) * D_INNER;
        u16 dnxt = dt[nidx];
        u16 unxt = xs[nidx];
        u16 znxt = z16[nidx];
        float4 B0 = *(const float4*)(prow + t * PST + 0);
        float4 B1 = *(const float4*)(prow + t * PST + 4);
        float4 B2 = *(const float4*)(prow + t * PST + 8);
        float4 B3 = *(const float4*)(prow + t * PST + 12);
        float4 C0 = *(const float4*)(prow + t * PST + 16);
        float4 C1 = *(const float4*)(prow + t * PST + 20);
        float4 C2 = *(const float4*)(prow + t * PST + 24);
        float4 C3 = *(const float4*)(prow + t * PST + 28);
        float dtv = bf2f(dcur), u = bf2f(ucur), zv = bf2f(zcur);
        float du = dtv * u;
        float Bf[16] = {B0.x, B0.y, B0.z, B0.w, B1.x, B1.y, B1.z, B1.w,
                        B2.x, B2.y, B2.z, B2.w, B3.x, B3.y, B3.z, B3.w};
        float Cf[16] = {C0.x, C0.y, C0.z, C0.w, C1.x, C1.y, C1.z, C1.w,
                        C2.x, C2.y, C2.z, C2.w, C3.x, C3.y, C3.z, C3.w};
        float y = 0.f;
#pragma unroll
        for (int n = 0; n < 16; n++) {
            h[n] = h[n] * exp2_hw(dtv * Areg[n]) + du * Bf[n];
            y += h[n] * Cf[n];
        }
        float gate = zv * sigmoid_fast(zv);
        xs[base + (size_t)t * D_INNER] = f2bf((y + u * Dd) * gate);
        dcur = dnxt; ucur = unxt; zcur = znxt;
    }
}

// ---------------------------------------------------------------------------
extern "C" void kernel_launch(void* const* d_in, const int* in_sizes, int n_in,
                              void* d_out, int out_size, void* d_ws, size_t ws_size,
                              hipStream_t stream) {
    const void* x          = d_in[0];
    const void* in_proj_w  = d_in[1];
    const void* conv_w     = d_in[2];
    const void* conv_b     = d_in[3];
    const void* x_proj_w   = d_in[4];
    const void* dt_proj_w  = d_in[5];
    const void* dt_proj_b  = d_in[6];
    const void* A_log      = d_in[7];
    const void* Dvec       = d_in[8];
    const void* out_proj_w = d_in[9];

    char* w = (char*)d_ws;
    const size_t MB = 1024 * 1024;
    const size_t KB = 1024;
    // Overlay plan (stream order guarantees safety):
    //   5-37 MB  : xc (K1 out, dead after conv) -> dt16 -> Pp6 lower half
    //  37-69 MB  : z (dead after scan_phase3)   -> Pp6 upper half
    //  69-101 MB : xs (conv out) -> gated y (K6 A operand)
    // 101-126 MB : x16+ipwT (dead after K1) -> Pp (dead after reduce) -> hloc
    int*   flag    = (int*)(w + 0);
    float* Aws     = (float*)(w + 1 * KB);          // 256 KB
    float* proj    = (float*)(w + 1 * MB);          // 2 MB fp32 [4096][PST=128]
    u16*   cw16    = (u16*)(w + 3 * MB);            // 32 KB
    u16*   cb16    = (u16*)(w + 3 * MB + 64 * KB);  // 8 KB
    u16*   dtb16   = (u16*)(w + 3 * MB + 128 * KB); // 8 KB
    u16*   D16     = (u16*)(w + 3 * MB + 192 * KB); // 8 KB
    u16*   proj_lo = (u16*)(w + 3 * MB + 512 * KB); // 512 KB bf16 [4096][64]
    u16*   dtwT    = (u16*)(w + 4 * MB);            // 512 KB bf16 [4096][64]
    u16*   buf1    = (u16*)(w + 5 * MB);            // 32 MB: xc then dt16
    u16*   dt16    = buf1;
    u16*   zbuf    = (u16*)(w + 37 * MB);           // 32 MB: z
    float* Pp6     = (float*)(w + 5 * MB);          // 64 MB: K6 partials (post-scan)
    u16*   xs      = (u16*)(w + 69 * MB);           // 32 MB: xs then gated y
    u16*   x16     = (u16*)(w + 101 * MB);          // 8.4 MB  (dead after K1)
    u16*   ipwT    = (u16*)(w + 110 * MB);          // 16.8 MB (dead after K1)
    float* Pp      = (float*)(w + 101 * MB);        // 16 MB (post-K1, dead after reduce)
    float* hloc    = (float*)(w + 101 * MB);        // 16 MB (post-reduce, NC=32)
    float* Ssum    = (float*)(w + 117 * MB);        // 1 MB  (post-K1)
    u16*   opwT    = (u16*)(w + 127 * MB);          // 8.4 MB: out_proj_w^T [1024][4096]
    u16*   xpwT    = (u16*)(w + 136 * MB);          // 1 MB: x_proj_w^T [96(pad128)][4096]
    // total 137 MB (<150 MB proven available)

    detect_dtype<<<dim3(1), dim3(256), 0, stream>>>((const u16*)x, flag);
    prep_small<<<dim3(256), dim3(256), 0, stream>>>(conv_w, conv_b, dt_proj_b, Dvec, A_log,
                                                    cw16, cb16, dtb16, D16, Aws, flag);
    ingest16<<<dim3(MROWS * D_MODEL / 256), dim3(256), 0, stream>>>(x, x16, MROWS * D_MODEL, flag);
    transpose_w<<<dim3(2 * D_INNER / 32, D_MODEL / 32), dim3(256), 0, stream>>>(in_proj_w, ipwT, D_MODEL, 2 * D_INNER, flag);
    transpose_w<<<dim3(D_MODEL / 32, D_INNER / 32), dim3(256), 0, stream>>>(out_proj_w, opwT, D_INNER, D_MODEL, flag);
    transpose_w<<<dim3(NPROJ / 32, D_INNER / 32), dim3(256), 0, stream>>>(x_proj_w, xpwT, D_INNER, NPROJ, flag);
    transpose_w<<<dim3(D_INNER / 32, DT_RANK / 32), dim3(256), 0, stream>>>(dt_proj_w, dtwT, DT_RANK, D_INNER, flag);

    // K1: xz = x @ Win -> xc (buf1) + z (zbuf); 256^2-tile sandwich-phase, 512 blocks
    gemm8p<1024, 0><<<dim3(512), dim3(512), 0, stream>>>(x16, ipwT, buf1, zbuf, nullptr);
    // K2: conv + silu -> xs
    conv_silu<<<dim3(MROWS * D_INNER / 256), dim3(256), 0, stream>>>(buf1, cw16, cb16, xs);
    // K3: proj via split-K MFMA + reduce (also emits proj_lo bf16)
    gemm_proj<<<dim3(KSPLIT, MROWS / 128), dim3(256), 0, stream>>>(xs, xpwT, Pp);
    reduce_proj<<<dim3(MROWS * PST / 256), dim3(256), 0, stream>>>(Pp, proj, proj_lo);
    // K4: dt via MFMA, fused bias+fast-softplus (dt16 overlays dead xc)
    gemm_dt<<<dim3(D_INNER / 128, MROWS / 128), dim3(256), 0, stream>>>(proj_lo, dtwT, dtb16, dt16);
    // K5: chunked scan (NC=32; uniform B/C reads, no LDS, 1-step prefetch)
    scan_phase1<<<dim3(D_INNER / 256, NC, BATCH), dim3(256), 0, stream>>>(proj, dt16, Aws, xs, hloc, Ssum);
    scan_phase2<<<dim3(BATCH * D_INNER * D_STATE / 256), dim3(256), 0, stream>>>(Aws, Ssum, hloc);
    scan_phase3<<<dim3(D_INNER / 256, NC, BATCH), dim3(256), 0, stream>>>(proj, dt16, Aws, D16, hloc, zbuf, xs);
    // K6: out = y @ out_proj_w; 256^2-tile sandwich-phase split-K (dt16/zbuf dead -> Pp6) + reduce
    gemm8p<4096, 1><<<dim3(D_MODEL / 256, MROWS / 256, KSP6), dim3(512), 0, stream>>>(xs, opwT, nullptr, nullptr, Pp6);
    reduce_out<<<dim3(MROWS * D_MODEL / 256), dim3(256), 0, stream>>>(Pp6, d_out, flag);
}

// Round 6
// 461.130 us; speedup vs baseline: 1.1810x; 1.0631x over previous
//
#include <hip/hip_runtime.h>
#include <hip/hip_bf16.h>

// Problem constants
#define D_MODEL 1024
#define D_INNER 4096
#define D_STATE 16
#define D_CONV 4
#define DT_RANK 64
#define BATCH 2
#define SEQLEN 2048
#define MROWS (BATCH * SEQLEN)          // 4096
#define NPROJ (DT_RANK + 2 * D_STATE)   // 96
#define PST 128                         // proj row stride (padded, fp32)
#define NC 32                           // scan chunks
#define TC (SEQLEN / NC)                // 64 steps per chunk
#define KSPLIT 8                        // split-K for proj gemm
#define KSP6 4                          // split-K for out gemm

typedef unsigned short u16;
typedef unsigned int u32;
typedef __attribute__((ext_vector_type(8))) short short8;
typedef __attribute__((ext_vector_type(4))) float floatx4;

#define LOG2E 1.44269504089f

__device__ __forceinline__ float bf2f(u16 u) {
    union { u32 i; float f; } v; v.i = ((u32)u) << 16; return v.f;
}
__device__ __forceinline__ u16 f2bf(float f) {
    union { float f; u32 i; } v; v.f = f;
    u32 x = v.i;
    u32 r = x + 0x7fffu + ((x >> 16) & 1u);   // round to nearest even
    return (u16)(r >> 16);
}
// fast softplus: hardware exp/log; |err| << bf16 ulp for all finite x
__device__ __forceinline__ float softplus_fast(float x) {
    float l = __logf(1.f + __expf(-fabsf(x)));
    return x > 0.f ? x + l : l;
}
// fast sigmoid: v_exp + v_rcp (1 ulp), no exact-division sequence
__device__ __forceinline__ float sigmoid_fast(float x) {
    return __builtin_amdgcn_rcpf(1.f + __expf(-x));
}
// raw hardware 2^x (single v_exp_f32; caller pre-scales by log2e)
__device__ __forceinline__ float exp2_hw(float x) {
    float r;
    asm("v_exp_f32 %0, %1" : "=v"(r) : "v"(x));
    return r;
}
// powers r^1..r^16 via depth-4 multiply tree (structured-A fast path)
__device__ __forceinline__ void pow_tree16(float r, float* pw) {
    pw[0] = r;
    pw[1] = r * r;
    pw[2] = pw[1] * r;
    pw[3] = pw[1] * pw[1];
    pw[4] = pw[3] * r;
    pw[5] = pw[3] * pw[1];
    pw[6] = pw[3] * pw[2];
    pw[7] = pw[3] * pw[3];
#pragma unroll
    for (int k = 0; k < 8; k++) pw[8 + k] = pw[7] * pw[k];
}
// async global->LDS 16B DMA (dest = wave-uniform base + lane*16)
__device__ __forceinline__ void async_cp16(const u16* g, u16* l) {
    __builtin_amdgcn_global_load_lds((const __attribute__((address_space(1))) void*)g,
                                     (__attribute__((address_space(3))) void*)l, 16, 0, 0);
}

// ---------------------------------------------------------------------------
// D0: detect input dtype (bf16 vs fp32) from exponent-field statistics.
// Also zero-inits the A-structure flag (prep_small raises it on mismatch).
__global__ __launch_bounds__(256) void detect_dtype(const u16* __restrict__ x, int* __restrict__ flag,
                                                    int* __restrict__ sflag) {
    __shared__ int cnt;
    if (threadIdx.x == 0) { cnt = 0; *sflag = 0; }
    __syncthreads();
    int local = 0;
    for (int k = 0; k < 16; k++) {
        int e = threadIdx.x * 8192 + k * 512;
        u16 v = x[2 * e];
        int ex = (v >> 7) & 0xFF;
        if (ex >= 0x68 && ex <= 0x8F) local++;
    }
    atomicAdd(&cnt, local);
    __syncthreads();
    if (threadIdx.x == 0) *flag = (cnt >= 2458) ? 1 : 0;
}

// ---------------------------------------------------------------------------
__global__ __launch_bounds__(256) void ingest16(const void* __restrict__ src, u16* __restrict__ dst,
                                                int n, const int* __restrict__ flag) {
    int i = blockIdx.x * 256 + threadIdx.x;
    if (i >= n) return;
    if (*flag) dst[i] = ((const u16*)src)[i];
    else       dst[i] = f2bf(((const float*)src)[i]);
}

// ---------------------------------------------------------------------------
// Fused small-tensor prologue: conv_w, conv_b, dt_proj_b, D ingest + A=-exp(A_log).
// Verifies the mamba A-structure A[d][n] == -(n+1) (fp32-exact inputs);
// raises *sflag if violated (e.g. bf16-quantized A_log) -> scan fallback path.
__global__ __launch_bounds__(256) void prep_small(const void* __restrict__ cw, const void* __restrict__ cb,
                                                  const void* __restrict__ dtb, const void* __restrict__ Dv,
                                                  const void* __restrict__ Alog,
                                                  u16* __restrict__ cw16, u16* __restrict__ cb16,
                                                  u16* __restrict__ dtb16, u16* __restrict__ D16,
                                                  float* __restrict__ A, const int* __restrict__ flag,
                                                  int* __restrict__ sflag) {
    int i = blockIdx.x * 256 + threadIdx.x;   // grid covers 65536
    int isb = *flag;
    if (i < D_INNER * D_CONV)
        cw16[i] = isb ? ((const u16*)cw)[i] : f2bf(((const float*)cw)[i]);
    if (i < D_INNER) {
        cb16[i]  = isb ? ((const u16*)cb)[i]  : f2bf(((const float*)cb)[i]);
        dtb16[i] = isb ? ((const u16*)dtb)[i] : f2bf(((const float*)dtb)[i]);
        D16[i]   = isb ? ((const u16*)Dv)[i]  : f2bf(((const float*)Dv)[i]);
    }
    if (i < D_INNER * D_STATE) {
        float v = isb ? bf2f(((const u16*)Alog)[i]) : ((const float*)Alog)[i];
        float a = -expf(v);
        A[i] = a;
        float tgt = (float)((i & 15) + 1);
        if (fabsf(a + tgt) > 4e-6f * tgt) atomicOr(sflag, 1);
    }
}

// ---------------------------------------------------------------------------
// Transpose-ingest: W [K][N] (dual dtype) -> WT [N][K] bf16.
__global__ __launch_bounds__(256) void transpose_w(const void* __restrict__ W, u16* __restrict__ WT,
                                                   int K, int N, const int* __restrict__ flag) {
    __shared__ float t[32][33];
    int k0 = blockIdx.y * 32, n0 = blockIdx.x * 32;
    int tid = threadIdx.x;
    int r = tid >> 3, c4 = (tid & 7) * 4;
    int isb = *flag;
    size_t base = (size_t)(k0 + r) * N + n0 + c4;
    float4 v;
    if (isb) { ushort4 u4 = *(const ushort4*)((const u16*)W + base);
               v = make_float4(bf2f(u4.x), bf2f(u4.y), bf2f(u4.z), bf2f(u4.w)); }
    else     { v = *(const float4*)((const float*)W + base); }
    t[c4 + 0][r] = v.x; t[c4 + 1][r] = v.y; t[c4 + 2][r] = v.z; t[c4 + 3][r] = v.w;
    __syncthreads();
    u16* o = WT + (size_t)(n0 + r) * K + k0 + c4;
    o[0] = f2bf(t[r][c4 + 0]);
    o[1] = f2bf(t[r][c4 + 1]);
    o[2] = f2bf(t[r][c4 + 2]);
    o[3] = f2bf(t[r][c4 + 3]);
}

// ---------------------------------------------------------------------------
// 256x256-tile 4-phase GEMM with the m201 read/barrier sandwich.
// (Schedule lane exhausted at ~34% MfmaUtil: LDS pipe = 260KB/k-tile vs
// 256B/cyc is the structural ceiling for this 16x16 fragment shape; kept.)
//
// A [M][KS] bf16 row-major, Bt [N][KS] bf16 row-major.
// 512 threads = 8 waves (2M x 4N); per-wave output 128x64, chunk-interleaved:
//   M-frag i: row = wr*64 + (i&3)*16 + (i>>2)*128  -> A-chunk (i>>2)
//   N-frag j: col = wc*32 + (j&1)*16 + (j>>1)*128  -> B-chunk (j>>1)
// K-tile = 64; each tile = 4 chunks (A0,A1,B0,B1) of 128x64 bf16 = 16 KB.
// Per-phase skeleton: {ds_read subtile; stage 1 chunk; sched_barrier;
// s_barrier; lgkmcnt(0); sched_barrier; setprio(1); 16 MFMA; setprio(0);
// counted vmcnt; s_barrier}.  vmcnt ledger: every wait forces only
// >=3-phase-old loads.  LDS XOR-swizzled; linear gload_lds dest with
// inverse-swizzled global source (both-sides rule).
//
// MODE 0: C bf16, split to o0/o1 at col D_INNER (in-proj). KS=1024, grid 512,
//         bijective XCD swizzle. MODE 1: fp32 split-K partials Pp[z][M][1024]
//         (out-proj). KS=4096, grid (4,16,KSP6).
template<int KS, int MODE>
__global__ __launch_bounds__(512, 2) void gemm8p(const u16* __restrict__ A, const u16* __restrict__ Bt,
                                                 u16* __restrict__ o0, u16* __restrict__ o1,
                                                 float* __restrict__ Pp) {
    __shared__ __align__(16) u16 lds[65536];   // 128 KB: A = 2buf x 2chunk x 8192 u16; B at +32768
    const int tid = threadIdx.x;
    const int lane = tid & 63;
    const int wave = tid >> 6;
    const int wr = wave >> 2, wc = wave & 3;
    const int quad = lane >> 4, l15 = lane & 15;

    int m0, n0, kbase, kz;
    if (MODE == 0) {
        int wgid = (blockIdx.x & 7) * 64 + (blockIdx.x >> 3);   // bijective (512 % 8 == 0)
        m0 = (wgid & 15) * 256;
        n0 = (wgid >> 4) * 256;
        kbase = 0; kz = 0;
    } else {
        m0 = blockIdx.y * 256;
        n0 = blockIdx.x * 256;
        kz = blockIdx.z;
        kbase = kz * 1024;
    }
    const int NT = 1024 / 64;   // 16 k-tiles per block (both modes sweep 1024 of K)

    // ---- staging addressing: linear LDS dest, inverse-swizzled global source
    const int srow = tid >> 3;                              // 0..63 (chunk row, rho adds 64)
    const int kswz = (((tid & 7) ^ (srow & 7)) << 3);       // element offset within 64-wide k
    const u16* pA = A + (size_t)(m0 + srow) * KS + kbase + kswz;
    const u16* pB = Bt + (size_t)(n0 + srow) * KS + kbase + kswz;

    // ---- fragment-read addressing (swizzle term is per-thread constant)
    const int rsw = (l15 & 7) << 3;
    const int ksel0 = (quad * 8) ^ rsw;
    const int ksel1 = (32 + quad * 8) ^ rsw;
    const int aoff = (wr * 64 + l15) * 64;
    const int boff = (wc * 32 + l15) * 64;

    floatx4 acc[8][4];
#pragma unroll
    for (int i = 0; i < 8; i++)
#pragma unroll
        for (int j = 0; j < 4; j++) acc[i][j] = (floatx4)0.f;
    short8 af[4][2];        // current A-chunk frags [ii][ksub]
    short8 bf[2][2][2];     // both B-chunk frags    [chunk][jj][ksub]

#define STAGE_A(nb, h, kt) do { \
    const u16* g_ = pA + (size_t)(h) * 128 * KS + (kt) * 64; \
    u16* l_ = &lds[((nb) * 2 + (h)) * 8192 + tid * 8]; \
    async_cp16(g_, l_); \
    async_cp16(g_ + (size_t)64 * KS, l_ + 4096); \
} while (0)
#define STAGE_B(nb, h, kt) do { \
    const u16* g_ = pB + (size_t)(h) * 128 * KS + (kt) * 64; \
    u16* l_ = &lds[32768 + ((nb) * 2 + (h)) * 8192 + tid * 8]; \
    async_cp16(g_, l_); \
    async_cp16(g_ + (size_t)64 * KS, l_ + 4096); \
} while (0)
#define LOADA(b, h) do { \
    const u16* p_ = &lds[((b) * 2 + (h)) * 8192 + aoff]; \
    _Pragma("unroll") \
    for (int ii = 0; ii < 4; ii++) { \
        af[ii][0] = *(const short8*)(p_ + ii * 1024 + ksel0); \
        af[ii][1] = *(const short8*)(p_ + ii * 1024 + ksel1); \
    } \
} while (0)
#define LOADB(b, h) do { \
    const u16* p_ = &lds[32768 + ((b) * 2 + (h)) * 8192 + boff]; \
    _Pragma("unroll") \
    for (int jj = 0; jj < 2; jj++) { \
        bf[h][jj][0] = *(const short8*)(p_ + jj * 1024 + ksel0); \
        bf[h][jj][1] = *(const short8*)(p_ + jj * 1024 + ksel1); \
    } \
} while (0)
#define MFMAQ(qa, qb) do { \
    __builtin_amdgcn_s_setprio(1); \
    _Pragma("unroll") \
    for (int ii = 0; ii < 4; ii++) \
    _Pragma("unroll") \
    for (int jj = 0; jj < 2; jj++) { \
        floatx4 c_ = acc[(qa) * 4 + ii][(qb) * 2 + jj]; \
        c_ = __builtin_amdgcn_mfma_f32_16x16x32_bf16(af[ii][0], bf[qb][jj][0], c_, 0, 0, 0); \
        c_ = __builtin_amdgcn_mfma_f32_16x16x32_bf16(af[ii][1], bf[qb][jj][1], c_, 0, 0, 0); \
        acc[(qa) * 4 + ii][(qb) * 2 + jj] = c_; \
    } \
    __builtin_amdgcn_s_setprio(0); \
} while (0)
#define VMW(N) asm volatile("s_waitcnt vmcnt(" #N ")" ::: "memory")
#define BARX() do { __builtin_amdgcn_s_barrier(); asm volatile("" ::: "memory"); } while (0)
// m201 sandwich: pin reads before the barrier, MFMA after the lgkm drain.
#define SANDWICH() do { \
    __builtin_amdgcn_sched_barrier(0); \
    __builtin_amdgcn_s_barrier(); \
    asm volatile("s_waitcnt lgkmcnt(0)" ::: "memory"); \
    __builtin_amdgcn_sched_barrier(0); \
} while (0)

    // prologue: stage tile 0 -> buf 0, issue order [A0, B0, B1, A1]
    STAGE_A(0, 0, 0);
    STAGE_B(0, 0, 0);
    STAGE_B(0, 1, 0);
    STAGE_A(0, 1, 0);
    VMW(4); BARX();                 // A0,B0 resident; B1,A1 (4 loads) in flight

    for (int t = 0; t < NT - 1; ++t) {
        const int b = t & 1, nb = b ^ 1;
        // phase 0: quadrant (A0,B0); stage A0(t+1)
        LOADA(b, 0);
        LOADB(b, 0);
        STAGE_A(nb, 0, t + 1);
        SANDWICH();
        MFMAQ(0, 0);
        VMW(4); BARX();             // forces B1(t)
        // phase 1: quadrant (A0,B1); stage B0(t+1)
        LOADB(b, 1);
        STAGE_B(nb, 0, t + 1);
        SANDWICH();
        MFMAQ(0, 1);
        VMW(4); BARX();             // forces A1(t)
        // phase 2: quadrant (A1,B1); stage B1(t+1)
        LOADA(b, 1);
        STAGE_B(nb, 1, t + 1);
        SANDWICH();
        MFMAQ(1, 1);
        // phase 3: quadrant (A1,B0); stage A1(t+1); no mid-barrier (no reads)
        STAGE_A(nb, 1, t + 1);
        MFMAQ(1, 0);
        VMW(4); BARX();             // forces A0(t+1),B0(t+1) for next tile
    }
    {   // last k-tile: no stages, drain 2 -> 0
        const int b = (NT - 1) & 1;
        LOADA(b, 0);
        LOADB(b, 0);
        SANDWICH();
        MFMAQ(0, 0);
        VMW(2); BARX();             // forces B1
        LOADB(b, 1);
        SANDWICH();
        MFMAQ(0, 1);
        VMW(0); BARX();             // forces A1
        LOADA(b, 1);
        MFMAQ(1, 1);
        MFMAQ(1, 0);
    }

    if constexpr (MODE == 0) {
        (void)kz; (void)Pp;
        u16* d = (n0 < D_INNER) ? o0 : o1;
        const int nb0 = (n0 < D_INNER) ? n0 : n0 - D_INNER;
#pragma unroll
        for (int i = 0; i < 8; i++) {
            const int mrow = m0 + wr * 64 + (i & 3) * 16 + (i >> 2) * 128 + quad * 4;
#pragma unroll
            for (int j = 0; j < 4; j++) {
                const int ncol = nb0 + wc * 32 + (j & 1) * 16 + (j >> 1) * 128 + l15;
#pragma unroll
                for (int r = 0; r < 4; r++)
                    d[(size_t)(mrow + r) * D_INNER + ncol] = f2bf(acc[i][j][r]);
            }
        }
    } else {
        (void)o0; (void)o1;
        float* d = Pp + (size_t)kz * MROWS * D_MODEL;
#pragma unroll
        for (int i = 0; i < 8; i++) {
            const int mrow = m0 + wr * 64 + (i & 3) * 16 + (i >> 2) * 128 + quad * 4;
#pragma unroll
            for (int j = 0; j < 4; j++) {
                const int ncol = n0 + wc * 32 + (j & 1) * 16 + (j >> 1) * 128 + l15;
#pragma unroll
                for (int r = 0; r < 4; r++)
                    d[(size_t)(mrow + r) * D_MODEL + ncol] = acc[i][j][r];
            }
        }
    }
#undef STAGE_A
#undef STAGE_B
#undef LOADA
#undef LOADB
#undef MFMAQ
#undef VMW
#undef BARX
#undef SANDWICH
}

// ---------------------------------------------------------------------------
__global__ __launch_bounds__(256) void reduce_out(const float* __restrict__ Pp, void* __restrict__ out,
                                                  const int* __restrict__ flag) {
    int i = blockIdx.x * 256 + threadIdx.x;   // < MROWS*D_MODEL
    float s = 0.f;
#pragma unroll
    for (int z = 0; z < KSP6; z++) s += Pp[(size_t)z * MROWS * D_MODEL + i];
    if (*flag) ((u16*)out)[i] = f2bf(s);
    else       ((float*)out)[i] = s;
}

// ---------------------------------------------------------------------------
// K3: proj split-K MFMA.  A = xs [4096][4096], Bt = xpwT [128(pad)][4096].
__global__ __launch_bounds__(256) void gemm_proj(const u16* __restrict__ A, const u16* __restrict__ Bt,
                                                 float* __restrict__ Pp) {
    const int K = D_INNER;
    __shared__ __align__(16) u16 sA[128 * 32];
    __shared__ __align__(16) u16 sB[128 * 32];
    int tid = threadIdx.x;
    int lane = tid & 63;
    int wave = tid >> 6;
    int wm = (wave >> 1) * 64, wn = (wave & 1) * 64;
    int quad = lane >> 4, l15 = lane & 15;
    int m0 = blockIdx.y * 128;
    int kz = blockIdx.x;
    int kbase = kz * (K / KSPLIT);

    floatx4 acc[4][4];
#pragma unroll
    for (int i = 0; i < 4; i++)
#pragma unroll
        for (int j = 0; j < 4; j++) acc[i][j] = (floatx4)0.f;

    const u16* ga0 = A + (size_t)(m0 + (tid >> 2)) * K + (tid & 3) * 8;
    const u16* ga1 = A + (size_t)(m0 + 64 + (tid >> 2)) * K + (tid & 3) * 8;
    const u16* gb0 = Bt + (size_t)(tid >> 2) * K + (tid & 3) * 8;
    const u16* gb1 = Bt + (size_t)(64 + (tid >> 2)) * K + (tid & 3) * 8;
    u16* la0 = &sA[tid * 8];
    u16* la1 = &sA[(256 + tid) * 8];
    u16* lb0 = &sB[tid * 8];
    u16* lb1 = &sB[(256 + tid) * 8];

    for (int k0 = kbase; k0 < kbase + K / KSPLIT; k0 += 32) {
        async_cp16(ga0 + k0, la0);
        async_cp16(ga1 + k0, la1);
        async_cp16(gb0 + k0, lb0);
        async_cp16(gb1 + k0, lb1);
        __syncthreads();
        short8 af[4], bf[4];
#pragma unroll
        for (int i = 0; i < 4; i++) {
            af[i] = *(const short8*)&sA[(wm + i * 16 + l15) * 32 + quad * 8];
            bf[i] = *(const short8*)&sB[(wn + i * 16 + l15) * 32 + quad * 8];
        }
#pragma unroll
        for (int i = 0; i < 4; i++)
#pragma unroll
            for (int j = 0; j < 4; j++)
                acc[i][j] = __builtin_amdgcn_mfma_f32_16x16x32_bf16(af[i], bf[j], acc[i][j], 0, 0, 0);
        __syncthreads();
    }

    float* d = Pp + (size_t)kz * MROWS * PST;
#pragma unroll
    for (int i = 0; i < 4; i++)
#pragma unroll
        for (int j = 0; j < 4; j++)
#pragma unroll
            for (int r = 0; r < 4; r++) {
                int mm = m0 + wm + i * 16 + quad * 4 + r;
                int nn = wn + j * 16 + l15;
                d[(size_t)mm * PST + nn] = acc[i][j][r];
            }
}

// ---------------------------------------------------------------------------
// reduce split-K partials -> proj fp32 [4096][PST]; also emit proj_lo bf16.
__global__ __launch_bounds__(256) void reduce_proj(const float* __restrict__ Pp, float* __restrict__ proj,
                                                   u16* __restrict__ proj_lo) {
    int i = blockIdx.x * 256 + threadIdx.x;    // < MROWS*PST
    float s = 0.f;
#pragma unroll
    for (int z = 0; z < KSPLIT; z++) s += Pp[(size_t)z * MROWS * PST + i];
    proj[i] = s;
    int col = i & (PST - 1);
    if (col < DT_RANK) proj_lo[(size_t)(i >> 7) * DT_RANK + col] = f2bf(s);
}

// ---------------------------------------------------------------------------
// K4: dt = softplus(proj_lo @ dtwT^T + b) via MFMA.  M=4096, N=4096, K=64.
// Epilogue: fast softplus + LDS bounce (stride-132 pad) -> coalesced 16B stores.
__global__ __launch_bounds__(256) void gemm_dt(const u16* __restrict__ A, const u16* __restrict__ Bt,
                                               const u16* __restrict__ dtb, u16* __restrict__ dt) {
    const int K = DT_RANK;   // 64
    __shared__ __align__(16) u16 smem[64 * 132];   // 16.9 KB; k-loop uses first 16 KB
    u16* sA = smem;
    u16* sB = smem + 128 * 32;
    int tid = threadIdx.x;
    int lane = tid & 63;
    int wave = tid >> 6;
    int wm = (wave >> 1) * 64, wn = (wave & 1) * 64;
    int quad = lane >> 4, l15 = lane & 15;
    int m0 = blockIdx.y * 128, n0 = blockIdx.x * 128;

    floatx4 acc[4][4];
#pragma unroll
    for (int i = 0; i < 4; i++)
#pragma unroll
        for (int j = 0; j < 4; j++) acc[i][j] = (floatx4)0.f;

    const u16* ga0 = A + (size_t)(m0 + (tid >> 2)) * K + (tid & 3) * 8;
    const u16* ga1 = A + (size_t)(m0 + 64 + (tid >> 2)) * K + (tid & 3) * 8;
    const u16* gb0 = Bt + (size_t)(n0 + (tid >> 2)) * K + (tid & 3) * 8;
    const u16* gb1 = Bt + (size_t)(n0 + 64 + (tid >> 2)) * K + (tid & 3) * 8;
    u16* la0 = &sA[tid * 8];
    u16* la1 = &sA[(256 + tid) * 8];
    u16* lb0 = &sB[tid * 8];
    u16* lb1 = &sB[(256 + tid) * 8];

    for (int k0 = 0; k0 < K; k0 += 32) {
        async_cp16(ga0 + k0, la0);
        async_cp16(ga1 + k0, la1);
        async_cp16(gb0 + k0, lb0);
        async_cp16(gb1 + k0, lb1);
        __syncthreads();
        short8 af[4], bf[4];
#pragma unroll
        for (int i = 0; i < 4; i++) {
            af[i] = *(const short8*)&sA[(wm + i * 16 + l15) * 32 + quad * 8];
            bf[i] = *(const short8*)&sB[(wn + i * 16 + l15) * 32 + quad * 8];
        }
#pragma unroll
        for (int i = 0; i < 4; i++)
#pragma unroll
            for (int j = 0; j < 4; j++)
                acc[i][j] = __builtin_amdgcn_mfma_f32_16x16x32_bf16(af[i], bf[j], acc[i][j], 0, 0, 0);
        __syncthreads();
    }

#pragma unroll
    for (int h = 0; h < 2; h++) {
        __syncthreads();
        if (wm == h * 64) {
#pragma unroll
            for (int j = 0; j < 4; j++) {
                int col = wn + j * 16 + l15;
                float b = bf2f(dtb[n0 + col]);
#pragma unroll
                for (int i = 0; i < 4; i++)
#pragma unroll
                    for (int r = 0; r < 4; r++) {
                        int row = i * 16 + quad * 4 + r;   // 0..63 within half
                        smem[row * 132 + col] = f2bf(softplus_fast(acc[i][j][r] + b));
                    }
            }
        }
        __syncthreads();
#pragma unroll
        for (int p = 0; p < 4; p++) {
            int row = p * 16 + (tid >> 4);
            int chunk = tid & 15;
            uint4 v = *(const uint4*)&smem[row * 132 + chunk * 8];
            *(uint4*)&dt[(size_t)(m0 + h * 64 + row) * D_INNER + n0 + chunk * 8] = v;
        }
    }
}

// ---------------------------------------------------------------------------
// K2: causal depthwise conv1d + silu (bf16 in/out)
__global__ __launch_bounds__(256) void conv_silu(const u16* __restrict__ xc, const u16* __restrict__ cw,
                                                 const u16* __restrict__ cb, u16* __restrict__ xs) {
    int idx = blockIdx.x * 256 + threadIdx.x;
    int d = idx & (D_INNER - 1);
    int t = (idx >> 12) & (SEQLEN - 1);
    int b = idx >> 23;
    float w0 = bf2f(cw[d * 4 + 0]), w1 = bf2f(cw[d * 4 + 1]);
    float w2 = bf2f(cw[d * 4 + 2]), w3 = bf2f(cw[d * 4 + 3]);
    float acc = bf2f(cb[d]);
    size_t base = (size_t)b * SEQLEN * D_INNER + d;
    if (t >= 3) acc += bf2f(xc[base + (size_t)(t - 3) * D_INNER]) * w0;
    if (t >= 2) acc += bf2f(xc[base + (size_t)(t - 2) * D_INNER]) * w1;
    if (t >= 1) acc += bf2f(xc[base + (size_t)(t - 1) * D_INNER]) * w2;
    acc += bf2f(xc[base + (size_t)t * D_INNER]) * w3;
    xs[idx] = f2bf(acc * sigmoid_fast(acc));
}

// ---------------------------------------------------------------------------
// K5a: chunked scan phase 1 — per (b,d,chunk) thread, 16 states in registers.
// Structured-A fast path (sflag==0): dA[n] = r^(n+1), r = exp2(-dt*log2e):
// 1 trans + 16 full-rate muls replaces 16 quarter-rate v_exp per step.
// B row wave-uniform -> direct global; dt/xs streams prefetched 1 ahead.
__global__ __launch_bounds__(256) void scan_phase1(const float* __restrict__ proj, const u16* __restrict__ dt,
                                                   const float* __restrict__ A, const u16* __restrict__ xs,
                                                   float* __restrict__ hloc, float* __restrict__ Ssum,
                                                   const int* __restrict__ sflag) {
    int d = blockIdx.x * 256 + threadIdx.x;
    int c = blockIdx.y, b = blockIdx.z;
    int t0 = c * TC;
    int structured = (*sflag == 0);
    float h[16];
#pragma unroll
    for (int n = 0; n < 16; n++) h[n] = 0.f;
    float S = 0.f;
    size_t base = ((size_t)b * SEQLEN + t0) * D_INNER + d;
    const float* prow = proj + ((size_t)b * SEQLEN + t0) * PST + DT_RANK;
    u16 dcur = dt[base], ucur = xs[base];
    if (structured) {
        for (int t = 0; t < TC; t++) {
            size_t nidx = base + (size_t)((t + 1 < TC) ? t + 1 : t) * D_INNER;
            u16 dnxt = dt[nidx];
            u16 unxt = xs[nidx];
            float4 B0 = *(const float4*)(prow + t * PST + 0);
            float4 B1 = *(const float4*)(prow + t * PST + 4);
            float4 B2 = *(const float4*)(prow + t * PST + 8);
            float4 B3 = *(const float4*)(prow + t * PST + 12);
            float dtv = bf2f(dcur), u = bf2f(ucur);
            S += dtv;
            float du = dtv * u;
            float Bf[16] = {B0.x, B0.y, B0.z, B0.w, B1.x, B1.y, B1.z, B1.w,
                            B2.x, B2.y, B2.z, B2.w, B3.x, B3.y, B3.z, B3.w};
            float pw[16];
            pow_tree16(exp2_hw(-LOG2E * dtv), pw);
#pragma unroll
            for (int n = 0; n < 16; n++)
                h[n] = h[n] * pw[n] + du * Bf[n];
            dcur = dnxt; ucur = unxt;
        }
    } else {
        float Areg[16];   // prescaled by log2e for raw v_exp_f32
        const float4* Ap = (const float4*)(A + (size_t)d * 16);
#pragma unroll
        for (int n = 0; n < 4; n++) {
            float4 v = Ap[n];
            Areg[n * 4 + 0] = v.x * LOG2E; Areg[n * 4 + 1] = v.y * LOG2E;
            Areg[n * 4 + 2] = v.z * LOG2E; Areg[n * 4 + 3] = v.w * LOG2E;
        }
        for (int t = 0; t < TC; t++) {
            size_t nidx = base + (size_t)((t + 1 < TC) ? t + 1 : t) * D_INNER;
            u16 dnxt = dt[nidx];
            u16 unxt = xs[nidx];
            float4 B0 = *(const float4*)(prow + t * PST + 0);
            float4 B1 = *(const float4*)(prow + t * PST + 4);
            float4 B2 = *(const float4*)(prow + t * PST + 8);
            float4 B3 = *(const float4*)(prow + t * PST + 12);
            float dtv = bf2f(dcur), u = bf2f(ucur);
            S += dtv;
            float du = dtv * u;
            float Bf[16] = {B0.x, B0.y, B0.z, B0.w, B1.x, B1.y, B1.z, B1.w,
                            B2.x, B2.y, B2.z, B2.w, B3.x, B3.y, B3.z, B3.w};
#pragma unroll
            for (int n = 0; n < 16; n++)
                h[n] = h[n] * exp2_hw(dtv * Areg[n]) + du * Bf[n];
            dcur = dnxt; ucur = unxt;
        }
    }
    float* hp = &hloc[(((size_t)b * NC + c) * D_INNER + d) * 16];
#pragma unroll
    for (int n = 0; n < 16; n += 4)
        *(float4*)&hp[n] = make_float4(h[n], h[n + 1], h[n + 2], h[n + 3]);
    Ssum[((size_t)b * NC + c) * D_INNER + d] = S;
}

// ---------------------------------------------------------------------------
// K5b: combine chunks serially (in place: hloc becomes h_init per chunk).
__global__ __launch_bounds__(256) void scan_phase2(const float* __restrict__ A, const float* __restrict__ Ssum,
                                                   float* __restrict__ hloc) {
    int tid = blockIdx.x * 256 + threadIdx.x;
    int n = tid & 15;
    int d = (tid >> 4) & (D_INNER - 1);
    int b = tid >> 16;
    float An2 = A[d * 16 + n] * LOG2E;
    float h = 0.f;
    for (int c = 0; c < NC; c++) {
        size_t idx = (((size_t)b * NC + c) * D_INNER + d) * 16 + n;
        float hl = hloc[idx];
        float S = Ssum[((size_t)b * NC + c) * D_INNER + d];
        hloc[idx] = h;
        h = hl + h * exp2_hw(An2 * S);
    }
}

// ---------------------------------------------------------------------------
// K5c: phase 3 — rerun chunk with h_init, compute y, D-residual, silu(z) gate.
// Structured-A fast path as phase1. B/C rows wave-uniform -> direct global;
// dt/xs/z prefetched 1 ahead.
__global__ __launch_bounds__(256) void scan_phase3(const float* __restrict__ proj, const u16* __restrict__ dt,
                                                   const float* __restrict__ A, const u16* __restrict__ D16,
                                                   const float* __restrict__ hinit, const u16* __restrict__ z16,
                                                   u16* __restrict__ xs, const int* __restrict__ sflag) {
    int d = blockIdx.x * 256 + threadIdx.x;
    int c = blockIdx.y, b = blockIdx.z;
    int t0 = c * TC;
    int structured = (*sflag == 0);
    float h[16];
    {
        const float* hp = &hinit[(((size_t)b * NC + c) * D_INNER + d) * 16];
#pragma unroll
        for (int n = 0; n < 16; n += 4) {
            float4 v = *(const float4*)&hp[n];
            h[n] = v.x; h[n + 1] = v.y; h[n + 2] = v.z; h[n + 3] = v.w;
        }
    }
    float Dd = bf2f(D16[d]);
    size_t base = ((size_t)b * SEQLEN + t0) * D_INNER + d;
    const float* prow = proj + ((size_t)b * SEQLEN + t0) * PST + DT_RANK;
    u16 dcur = dt[base], ucur = xs[base], zcur = z16[base];
    if (structured) {
        for (int t = 0; t < TC; t++) {
            size_t nidx = base + (size_t)((t + 1 < TC) ? t + 1 : t) * D_INNER;
            u16 dnxt = dt[nidx];
            u16 unxt = xs[nidx];
            u16 znxt = z16[nidx];
            float4 B0 = *(const float4*)(prow + t * PST + 0);
            float4 B1 = *(const float4*)(prow + t * PST + 4);
            float4 B2 = *(const float4*)(prow + t * PST + 8);
            float4 B3 = *(const float4*)(prow + t * PST + 12);
            float4 C0 = *(const float4*)(prow + t * PST + 16);
            float4 C1 = *(const float4*)(prow + t * PST + 20);
            float4 C2 = *(const float4*)(prow + t * PST + 24);
            float4 C3 = *(const float4*)(prow + t * PST + 28);
            float dtv = bf2f(dcur), u = bf2f(ucur), zv = bf2f(zcur);
            float du = dtv * u;
            float Bf[16] = {B0.x, B0.y, B0.z, B0.w, B1.x, B1.y, B1.z, B1.w,
                            B2.x, B2.y, B2.z, B2.w, B3.x, B3.y, B3.z, B3.w};
            float Cf[16] = {C0.x, C0.y, C0.z, C0.w, C1.x, C1.y, C1.z, C1.w,
                            C2.x, C2.y, C2.z, C2.w, C3.x, C3.y, C3.z, C3.w};
            float pw[16];
            pow_tree16(exp2_hw(-LOG2E * dtv), pw);
            float y = 0.f;
#pragma unroll
            for (int n = 0; n < 16; n++) {
                h[n] = h[n] * pw[n] + du * Bf[n];
                y += h[n] * Cf[n];
            }
            float gate = zv * sigmoid_fast(zv);
            xs[base + (size_t)t * D_INNER] = f2bf((y + u * Dd) * gate);
            dcur = dnxt; ucur = unxt; zcur = znxt;
        }
    } else {
        float Areg[16];   // prescaled by log2e
        const float4* Ap = (const float4*)(A + (size_t)d * 16);
#pragma unroll
        for (int n = 0; n < 4; n++) {
            float4 v = Ap[n];
            Areg[n * 4 + 0] = v.x * LOG2E; Areg[n * 4 + 1] = v.y * LOG2E;
            Areg[n * 4 + 2] = v.z * LOG2E; Areg[n * 4 + 3] = v.w * LOG2E;
        }
        for (int t = 0; t < TC; t++) {
            size_t nidx = base + (size_t)((t + 1 < TC) ? t + 1 : t) * D_INNER;
            u16 dnxt = dt[nidx];
            u16 unxt = xs[nidx];
            u16 znxt = z16[nidx];
            float4 B0 = *(const float4*)(prow + t * PST + 0);
            float4 B1 = *(const float4*)(prow + t * PST + 4);
            float4 B2 = *(const float4*)(prow + t * PST + 8);
            float4 B3 = *(const float4*)(prow + t * PST + 12);
            float4 C0 = *(const float4*)(prow + t * PST + 16);
            float4 C1 = *(const float4*)(prow + t * PST + 20);
            float4 C2 = *(const float4*)(prow + t * PST + 24);
            float4 C3 = *(const float4*)(prow + t * PST + 28);
            float dtv = bf2f(dcur), u = bf2f(ucur), zv = bf2f(zcur);
            float du = dtv * u;
            float Bf[16] = {B0.x, B0.y, B0.z, B0.w, B1.x, B1.y, B1.z, B1.w,
                            B2.x, B2.y, B2.z, B2.w, B3.x, B3.y, B3.z, B3.w};
            float Cf[16] = {C0.x, C0.y, C0.z, C0.w, C1.x, C1.y, C1.z, C1.w,
                            C2.x, C2.y, C2.z, C2.w, C3.x, C3.y, C3.z, C3.w};
            float y = 0.f;
#pragma unroll
            for (int n = 0; n < 16; n++) {
                h[n] = h[n] * exp2_hw(dtv * Areg[n]) + du * Bf[n];
                y += h[n] * Cf[n];
            }
            float gate = zv * sigmoid_fast(zv);
            xs[base + (size_t)t * D_INNER] = f2bf((y + u * Dd) * gate);
            dcur = dnxt; ucur = unxt; zcur = znxt;
        }
    }
}

// ---------------------------------------------------------------------------
extern "C" void kernel_launch(void* const* d_in, const int* in_sizes, int n_in,
                              void* d_out, int out_size, void* d_ws, size_t ws_size,
                              hipStream_t stream) {
    const void* x          = d_in[0];
    const void* in_proj_w  = d_in[1];
    const void* conv_w     = d_in[2];
    const void* conv_b     = d_in[3];
    const void* x_proj_w   = d_in[4];
    const void* dt_proj_w  = d_in[5];
    const void* dt_proj_b  = d_in[6];
    const void* A_log      = d_in[7];
    const void* Dvec       = d_in[8];
    const void* out_proj_w = d_in[9];

    char* w = (char*)d_ws;
    const size_t MB = 1024 * 1024;
    const size_t KB = 1024;
    // Overlay plan (stream order guarantees safety):
    //   5-37 MB  : xc (K1 out, dead after conv) -> dt16 -> Pp6 lower half
    //  37-69 MB  : z (dead after scan_phase3)   -> Pp6 upper half
    //  69-101 MB : xs (conv out) -> gated y (K6 A operand)
    // 101-126 MB : x16+ipwT (dead after K1) -> Pp (dead after reduce) -> hloc
    int*   flag    = (int*)(w + 0);
    int*   sflag   = (int*)(w + 16);                // A-structure flag (0 = structured)
    float* Aws     = (float*)(w + 1 * KB);          // 256 KB
    float* proj    = (float*)(w + 1 * MB);          // 2 MB fp32 [4096][PST=128]
    u16*   cw16    = (u16*)(w + 3 * MB);            // 32 KB
    u16*   cb16    = (u16*)(w + 3 * MB + 64 * KB);  // 8 KB
    u16*   dtb16   = (u16*)(w + 3 * MB + 128 * KB); // 8 KB
    u16*   D16     = (u16*)(w + 3 * MB + 192 * KB); // 8 KB
    u16*   proj_lo = (u16*)(w + 3 * MB + 512 * KB); // 512 KB bf16 [4096][64]
    u16*   dtwT    = (u16*)(w + 4 * MB);            // 512 KB bf16 [4096][64]
    u16*   buf1    = (u16*)(w + 5 * MB);            // 32 MB: xc then dt16
    u16*   dt16    = buf1;
    u16*   zbuf    = (u16*)(w + 37 * MB);           // 32 MB: z
    float* Pp6     = (float*)(w + 5 * MB);          // 64 MB: K6 partials (post-scan)
    u16*   xs      = (u16*)(w + 69 * MB);           // 32 MB: xs then gated y
    u16*   x16     = (u16*)(w + 101 * MB);          // 8.4 MB  (dead after K1)
    u16*   ipwT    = (u16*)(w + 110 * MB);          // 16.8 MB (dead after K1)
    float* Pp      = (float*)(w + 101 * MB);        // 16 MB (post-K1, dead after reduce)
    float* hloc    = (float*)(w + 101 * MB);        // 16 MB (post-reduce, NC=32)
    float* Ssum    = (float*)(w + 117 * MB);        // 1 MB  (post-K1)
    u16*   opwT    = (u16*)(w + 127 * MB);          // 8.4 MB: out_proj_w^T [1024][4096]
    u16*   xpwT    = (u16*)(w + 136 * MB);          // 1 MB: x_proj_w^T [96(pad128)][4096]
    // total 137 MB (<150 MB proven available)

    detect_dtype<<<dim3(1), dim3(256), 0, stream>>>((const u16*)x, flag, sflag);
    prep_small<<<dim3(256), dim3(256), 0, stream>>>(conv_w, conv_b, dt_proj_b, Dvec, A_log,
                                                    cw16, cb16, dtb16, D16, Aws, flag, sflag);
    ingest16<<<dim3(MROWS * D_MODEL / 256), dim3(256), 0, stream>>>(x, x16, MROWS * D_MODEL, flag);
    transpose_w<<<dim3(2 * D_INNER / 32, D_MODEL / 32), dim3(256), 0, stream>>>(in_proj_w, ipwT, D_MODEL, 2 * D_INNER, flag);
    transpose_w<<<dim3(D_MODEL / 32, D_INNER / 32), dim3(256), 0, stream>>>(out_proj_w, opwT, D_INNER, D_MODEL, flag);
    transpose_w<<<dim3(NPROJ / 32, D_INNER / 32), dim3(256), 0, stream>>>(x_proj_w, xpwT, D_INNER, NPROJ, flag);
    transpose_w<<<dim3(D_INNER / 32, DT_RANK / 32), dim3(256), 0, stream>>>(dt_proj_w, dtwT, DT_RANK, D_INNER, flag);

    // K1: xz = x @ Win -> xc (buf1) + z (zbuf); 256^2-tile sandwich-phase, 512 blocks
    gemm8p<1024, 0><<<dim3(512), dim3(512), 0, stream>>>(x16, ipwT, buf1, zbuf, nullptr);
    // K2: conv + silu -> xs
    conv_silu<<<dim3(MROWS * D_INNER / 256), dim3(256), 0, stream>>>(buf1, cw16, cb16, xs);
    // K3: proj via split-K MFMA + reduce (also emits proj_lo bf16)
    gemm_proj<<<dim3(KSPLIT, MROWS / 128), dim3(256), 0, stream>>>(xs, xpwT, Pp);
    reduce_proj<<<dim3(MROWS * PST / 256), dim3(256), 0, stream>>>(Pp, proj, proj_lo);
    // K4: dt via MFMA, fused bias+fast-softplus (dt16 overlays dead xc)
    gemm_dt<<<dim3(D_INNER / 128, MROWS / 128), dim3(256), 0, stream>>>(proj_lo, dtwT, dtb16, dt16);
    // K5: chunked scan (structured-A powering fast path; uniform B/C reads)
    scan_phase1<<<dim3(D_INNER / 256, NC, BATCH), dim3(256), 0, stream>>>(proj, dt16, Aws, xs, hloc, Ssum, sflag);
    scan_phase2<<<dim3(BATCH * D_INNER * D_STATE / 256), dim3(256), 0, stream>>>(Aws, Ssum, hloc);
    scan_phase3<<<dim3(D_INNER / 256, NC, BATCH), dim3(256), 0, stream>>>(proj, dt16, Aws, D16, hloc, zbuf, xs, sflag);
    // K6: out = y @ out_proj_w; 256^2-tile sandwich-phase split-K (dt16/zbuf dead -> Pp6) + reduce
    gemm8p<4096, 1><<<dim3(D_MODEL / 256, MROWS / 256, KSP6), dim3(512), 0, stream>>>(xs, opwT, nullptr, nullptr, Pp6);
    reduce_out<<<dim3(MROWS * D_MODEL / 256), dim3(256), 0, stream>>>(Pp6, d_out, flag);
}

// Round 7
// 430.404 us; speedup vs baseline: 1.2653x; 1.0714x over previous
//
#include <hip/hip_runtime.h>
#include <hip/hip_bf16.h>

// Problem constants
#define D_MODEL 1024
#define D_INNER 4096
#define D_STATE 16
#define D_CONV 4
#define DT_RANK 64
#define BATCH 2
#define SEQLEN 2048
#define MROWS (BATCH * SEQLEN)          // 4096
#define NPROJ (DT_RANK + 2 * D_STATE)   // 96
#define PST 128                         // proj row stride (padded, fp32)
#define NC 32                           // scan chunks
#define TC (SEQLEN / NC)                // 64 steps per chunk
#define KSPLIT 8                        // split-K for proj gemm
#define KSP6 4                          // split-K for out gemm

typedef unsigned short u16;
typedef unsigned int u32;
typedef __attribute__((ext_vector_type(8))) short short8;
typedef __attribute__((ext_vector_type(4))) float floatx4;
typedef __attribute__((ext_vector_type(16))) float floatx16;

#define LOG2E 1.44269504089f

__device__ __forceinline__ float bf2f(u16 u) {
    union { u32 i; float f; } v; v.i = ((u32)u) << 16; return v.f;
}
__device__ __forceinline__ u16 f2bf(float f) {
    union { float f; u32 i; } v; v.f = f;
    u32 x = v.i;
    u32 r = x + 0x7fffu + ((x >> 16) & 1u);   // round to nearest even
    return (u16)(r >> 16);
}
// fast softplus: hardware exp/log; |err| << bf16 ulp for all finite x
__device__ __forceinline__ float softplus_fast(float x) {
    float l = __logf(1.f + __expf(-fabsf(x)));
    return x > 0.f ? x + l : l;
}
// fast sigmoid: v_exp + v_rcp (1 ulp), no exact-division sequence
__device__ __forceinline__ float sigmoid_fast(float x) {
    return __builtin_amdgcn_rcpf(1.f + __expf(-x));
}
// raw hardware 2^x (single v_exp_f32; caller pre-scales by log2e)
__device__ __forceinline__ float exp2_hw(float x) {
    float r;
    asm("v_exp_f32 %0, %1" : "=v"(r) : "v"(x));
    return r;
}
// powers r^1..r^16 via depth-4 multiply tree (structured-A fast path)
__device__ __forceinline__ void pow_tree16(float r, float* pw) {
    pw[0] = r;
    pw[1] = r * r;
    pw[2] = pw[1] * r;
    pw[3] = pw[1] * pw[1];
    pw[4] = pw[3] * r;
    pw[5] = pw[3] * pw[1];
    pw[6] = pw[3] * pw[2];
    pw[7] = pw[3] * pw[3];
#pragma unroll
    for (int k = 0; k < 8; k++) pw[8 + k] = pw[7] * pw[k];
}
// async global->LDS 16B DMA (dest = wave-uniform base + lane*16)
__device__ __forceinline__ void async_cp16(const u16* g, u16* l) {
    __builtin_amdgcn_global_load_lds((const __attribute__((address_space(1))) void*)g,
                                     (__attribute__((address_space(3))) void*)l, 16, 0, 0);
}

// ---------------------------------------------------------------------------
// D0: detect input dtype (bf16 vs fp32) from exponent-field statistics.
// Also zero-inits the A-structure flag (prep_small raises it on mismatch).
__global__ __launch_bounds__(256) void detect_dtype(const u16* __restrict__ x, int* __restrict__ flag,
                                                    int* __restrict__ sflag) {
    __shared__ int cnt;
    if (threadIdx.x == 0) { cnt = 0; *sflag = 0; }
    __syncthreads();
    int local = 0;
    for (int k = 0; k < 16; k++) {
        int e = threadIdx.x * 8192 + k * 512;
        u16 v = x[2 * e];
        int ex = (v >> 7) & 0xFF;
        if (ex >= 0x68 && ex <= 0x8F) local++;
    }
    atomicAdd(&cnt, local);
    __syncthreads();
    if (threadIdx.x == 0) *flag = (cnt >= 2458) ? 1 : 0;
}

// ---------------------------------------------------------------------------
__global__ __launch_bounds__(256) void ingest16(const void* __restrict__ src, u16* __restrict__ dst,
                                                int n, const int* __restrict__ flag) {
    int i = blockIdx.x * 256 + threadIdx.x;
    if (i >= n) return;
    if (*flag) dst[i] = ((const u16*)src)[i];
    else       dst[i] = f2bf(((const float*)src)[i]);
}

// ---------------------------------------------------------------------------
// Fused small-tensor prologue: conv_w, conv_b, dt_proj_b, D ingest + A=-exp(A_log).
// Verifies the mamba A-structure A[d][n] == -(n+1) (fp32-exact inputs);
// raises *sflag if violated (e.g. bf16-quantized A_log) -> scan fallback path.
__global__ __launch_bounds__(256) void prep_small(const void* __restrict__ cw, const void* __restrict__ cb,
                                                  const void* __restrict__ dtb, const void* __restrict__ Dv,
                                                  const void* __restrict__ Alog,
                                                  u16* __restrict__ cw16, u16* __restrict__ cb16,
                                                  u16* __restrict__ dtb16, u16* __restrict__ D16,
                                                  float* __restrict__ A, const int* __restrict__ flag,
                                                  int* __restrict__ sflag) {
    int i = blockIdx.x * 256 + threadIdx.x;   // grid covers 65536
    int isb = *flag;
    if (i < D_INNER * D_CONV)
        cw16[i] = isb ? ((const u16*)cw)[i] : f2bf(((const float*)cw)[i]);
    if (i < D_INNER) {
        cb16[i]  = isb ? ((const u16*)cb)[i]  : f2bf(((const float*)cb)[i]);
        dtb16[i] = isb ? ((const u16*)dtb)[i] : f2bf(((const float*)dtb)[i]);
        D16[i]   = isb ? ((const u16*)Dv)[i]  : f2bf(((const float*)Dv)[i]);
    }
    if (i < D_INNER * D_STATE) {
        float v = isb ? bf2f(((const u16*)Alog)[i]) : ((const float*)Alog)[i];
        float a = -expf(v);
        A[i] = a;
        float tgt = (float)((i & 15) + 1);
        if (fabsf(a + tgt) > 4e-6f * tgt) atomicOr(sflag, 1);
    }
}

// ---------------------------------------------------------------------------
// Transpose-ingest: W [K][N] (dual dtype) -> WT [N][K] bf16.
__global__ __launch_bounds__(256) void transpose_w(const void* __restrict__ W, u16* __restrict__ WT,
                                                   int K, int N, const int* __restrict__ flag) {
    __shared__ float t[32][33];
    int k0 = blockIdx.y * 32, n0 = blockIdx.x * 32;
    int tid = threadIdx.x;
    int r = tid >> 3, c4 = (tid & 7) * 4;
    int isb = *flag;
    size_t base = (size_t)(k0 + r) * N + n0 + c4;
    float4 v;
    if (isb) { ushort4 u4 = *(const ushort4*)((const u16*)W + base);
               v = make_float4(bf2f(u4.x), bf2f(u4.y), bf2f(u4.z), bf2f(u4.w)); }
    else     { v = *(const float4*)((const float*)W + base); }
    t[c4 + 0][r] = v.x; t[c4 + 1][r] = v.y; t[c4 + 2][r] = v.z; t[c4 + 3][r] = v.w;
    __syncthreads();
    u16* o = WT + (size_t)(n0 + r) * K + k0 + c4;
    o[0] = f2bf(t[r][c4 + 0]);
    o[1] = f2bf(t[r][c4 + 1]);
    o[2] = f2bf(t[r][c4 + 2]);
    o[3] = f2bf(t[r][c4 + 3]);
}

// ---------------------------------------------------------------------------
// 256x256-tile 4-phase GEMM, 32x32x16 MFMA (round 6: halves MFMA instruction
// count, -17% MFMA floor per m119 vs m06; LDS traffic identical to 16x16).
//
// A [M][KS] bf16 row-major, Bt [N][KS] bf16 row-major.
// 512 threads = 8 waves (2M x 4N); per-wave output 128x64, chunk-interleaved:
//   M-frag i (32 rows): row = (i>>1)*128 + wr*64 + (i&1)*32  -> A-chunk (i>>1)
//   N-frag j (32 cols): col = j*128 + wc*32                   -> B-chunk j
// K-tile = 64 = 4 MFMA k-steps; chunks (A0,A1,B0,B1) of 128x64 bf16 = 16 KB.
//
// 32x32x16 operand mapping: A row = lane&31, k = (lane>>5)*8 + [0,8);
// B col = lane&31, same k.  C/D: col = lane&31,
// row = (reg&3) + 8*(reg>>2) + 4*(lane>>5)  [measured m74/m101].
//
// Per-phase skeleton (unchanged from r5): {ds_read subtile; stage 1 chunk;
// sched_barrier; s_barrier; lgkmcnt(0); sched_barrier; setprio(1); 8 MFMA;
// setprio(0); counted vmcnt; s_barrier}.  vmcnt ledger unchanged: every wait
// forces only >=3-phase-old loads.  LDS XOR-swizzled (8-elem k-granule ^
// (row&7)); linear gload_lds dest with inverse-swizzled global source.
//
// MODE 0: C bf16, split to o0/o1 at col D_INNER (in-proj). KS=1024, grid 512,
//         bijective XCD swizzle. MODE 1: fp32 split-K partials Pp[z][M][1024]
//         (out-proj). KS=4096, grid (4,16,KSP6).
template<int KS, int MODE>
__global__ __launch_bounds__(512, 2) void gemm8p(const u16* __restrict__ A, const u16* __restrict__ Bt,
                                                 u16* __restrict__ o0, u16* __restrict__ o1,
                                                 float* __restrict__ Pp) {
    __shared__ __align__(16) u16 lds[65536];   // 128 KB: A = 2buf x 2chunk x 8192 u16; B at +32768
    const int tid = threadIdx.x;
    const int lane = tid & 63;
    const int wave = tid >> 6;
    const int wr = wave >> 2, wc = wave & 3;
    const int l31 = lane & 31, lhi = lane >> 5, sw = lane & 7;

    int m0, n0, kbase, kz;
    if (MODE == 0) {
        int wgid = (blockIdx.x & 7) * 64 + (blockIdx.x >> 3);   // bijective (512 % 8 == 0)
        m0 = (wgid & 15) * 256;
        n0 = (wgid >> 4) * 256;
        kbase = 0; kz = 0;
    } else {
        m0 = blockIdx.y * 256;
        n0 = blockIdx.x * 256;
        kz = blockIdx.z;
        kbase = kz * 1024;
    }
    const int NT = 1024 / 64;   // 16 k-tiles per block (both modes sweep 1024 of K)

    // ---- staging addressing: linear LDS dest, inverse-swizzled global source
    const int srow = tid >> 3;                              // 0..63 (chunk row, rho adds 64)
    const int kswz = (((tid & 7) ^ (srow & 7)) << 3);       // element offset within 64-wide k
    const u16* pA = A + (size_t)(m0 + srow) * KS + kbase + kswz;
    const u16* pB = Bt + (size_t)(n0 + srow) * KS + kbase + kswz;

    // ---- fragment-read addressing (swizzle term is per-thread constant)
    // k-step s reads 8-elem granule (s*2 + lhi), XOR-swizzled by row&7 == lane&7
    const int k0f = (((0 + lhi) ^ sw) << 3);
    const int k1f = (((2 + lhi) ^ sw) << 3);
    const int k2f = (((4 + lhi) ^ sw) << 3);
    const int k3f = (((6 + lhi) ^ sw) << 3);
    const int aoff = (wr * 64 + l31) * 64;
    const int boff = (wc * 32 + l31) * 64;

    floatx16 acc[4][2];
#pragma unroll
    for (int i = 0; i < 4; i++)
#pragma unroll
        for (int j = 0; j < 2; j++) acc[i][j] = (floatx16)0.f;
    short8 af[2][4];        // current A-chunk frags [ii][s]
    short8 bfr[2][4];       // both B-chunk frags    [chunk][s]

#define STAGE_A(nb, h, kt) do { \
    const u16* g_ = pA + (size_t)(h) * 128 * KS + (kt) * 64; \
    u16* l_ = &lds[((nb) * 2 + (h)) * 8192 + tid * 8]; \
    async_cp16(g_, l_); \
    async_cp16(g_ + (size_t)64 * KS, l_ + 4096); \
} while (0)
#define STAGE_B(nb, h, kt) do { \
    const u16* g_ = pB + (size_t)(h) * 128 * KS + (kt) * 64; \
    u16* l_ = &lds[32768 + ((nb) * 2 + (h)) * 8192 + tid * 8]; \
    async_cp16(g_, l_); \
    async_cp16(g_ + (size_t)64 * KS, l_ + 4096); \
} while (0)
#define LOADA(b, h) do { \
    const u16* p_ = &lds[((b) * 2 + (h)) * 8192 + aoff]; \
    af[0][0] = *(const short8*)(p_ + k0f); \
    af[0][1] = *(const short8*)(p_ + k1f); \
    af[0][2] = *(const short8*)(p_ + k2f); \
    af[0][3] = *(const short8*)(p_ + k3f); \
    af[1][0] = *(const short8*)(p_ + 2048 + k0f); \
    af[1][1] = *(const short8*)(p_ + 2048 + k1f); \
    af[1][2] = *(const short8*)(p_ + 2048 + k2f); \
    af[1][3] = *(const short8*)(p_ + 2048 + k3f); \
} while (0)
#define LOADB(b, h) do { \
    const u16* p_ = &lds[32768 + ((b) * 2 + (h)) * 8192 + boff]; \
    bfr[h][0] = *(const short8*)(p_ + k0f); \
    bfr[h][1] = *(const short8*)(p_ + k1f); \
    bfr[h][2] = *(const short8*)(p_ + k2f); \
    bfr[h][3] = *(const short8*)(p_ + k3f); \
} while (0)
#define MFMAQ(qa, qb) do { \
    __builtin_amdgcn_s_setprio(1); \
    _Pragma("unroll") \
    for (int ii = 0; ii < 2; ii++) { \
        floatx16 c_ = acc[(qa) * 2 + ii][qb]; \
        c_ = __builtin_amdgcn_mfma_f32_32x32x16_bf16(af[ii][0], bfr[qb][0], c_, 0, 0, 0); \
        c_ = __builtin_amdgcn_mfma_f32_32x32x16_bf16(af[ii][1], bfr[qb][1], c_, 0, 0, 0); \
        c_ = __builtin_amdgcn_mfma_f32_32x32x16_bf16(af[ii][2], bfr[qb][2], c_, 0, 0, 0); \
        c_ = __builtin_amdgcn_mfma_f32_32x32x16_bf16(af[ii][3], bfr[qb][3], c_, 0, 0, 0); \
        acc[(qa) * 2 + ii][qb] = c_; \
    } \
    __builtin_amdgcn_s_setprio(0); \
} while (0)
#define VMW(N) asm volatile("s_waitcnt vmcnt(" #N ")" ::: "memory")
#define BARX() do { __builtin_amdgcn_s_barrier(); asm volatile("" ::: "memory"); } while (0)
// m201 sandwich: pin reads before the barrier, MFMA after the lgkm drain.
#define SANDWICH() do { \
    __builtin_amdgcn_sched_barrier(0); \
    __builtin_amdgcn_s_barrier(); \
    asm volatile("s_waitcnt lgkmcnt(0)" ::: "memory"); \
    __builtin_amdgcn_sched_barrier(0); \
} while (0)

    // prologue: stage tile 0 -> buf 0, issue order [A0, B0, B1, A1]
    STAGE_A(0, 0, 0);
    STAGE_B(0, 0, 0);
    STAGE_B(0, 1, 0);
    STAGE_A(0, 1, 0);
    VMW(4); BARX();                 // A0,B0 resident; B1,A1 (4 loads) in flight

    for (int t = 0; t < NT - 1; ++t) {
        const int b = t & 1, nb = b ^ 1;
        // phase 0: quadrant (A0,B0); stage A0(t+1)
        LOADA(b, 0);
        LOADB(b, 0);
        STAGE_A(nb, 0, t + 1);
        SANDWICH();
        MFMAQ(0, 0);
        VMW(4); BARX();             // forces B1(t)
        // phase 1: quadrant (A0,B1); stage B0(t+1)
        LOADB(b, 1);
        STAGE_B(nb, 0, t + 1);
        SANDWICH();
        MFMAQ(0, 1);
        VMW(4); BARX();             // forces A1(t)
        // phase 2: quadrant (A1,B1); stage B1(t+1)
        LOADA(b, 1);
        STAGE_B(nb, 1, t + 1);
        SANDWICH();
        MFMAQ(1, 1);
        // phase 3: quadrant (A1,B0); stage A1(t+1); no mid-barrier (no reads)
        STAGE_A(nb, 1, t + 1);
        MFMAQ(1, 0);
        VMW(4); BARX();             // forces A0(t+1),B0(t+1) for next tile
    }
    {   // last k-tile: no stages, drain 2 -> 0
        const int b = (NT - 1) & 1;
        LOADA(b, 0);
        LOADB(b, 0);
        SANDWICH();
        MFMAQ(0, 0);
        VMW(2); BARX();             // forces B1
        LOADB(b, 1);
        SANDWICH();
        MFMAQ(0, 1);
        VMW(0); BARX();             // forces A1
        LOADA(b, 1);
        MFMAQ(1, 1);
        MFMAQ(1, 0);
    }

    // epilogue: 32x32 C/D mapping col=lane&31, row=(reg&3)+8*(reg>>2)+4*lhi
    if constexpr (MODE == 0) {
        (void)kz; (void)Pp;
        u16* d = (n0 < D_INNER) ? o0 : o1;
        const int nb0 = (n0 < D_INNER) ? n0 : n0 - D_INNER;
#pragma unroll
        for (int i = 0; i < 4; i++) {
            const int rbase = m0 + (i >> 1) * 128 + wr * 64 + (i & 1) * 32 + lhi * 4;
#pragma unroll
            for (int j = 0; j < 2; j++) {
                const int ncol = nb0 + j * 128 + wc * 32 + l31;
#pragma unroll
                for (int reg = 0; reg < 16; reg++) {
                    const int row = rbase + (reg & 3) + ((reg >> 2) << 3);
                    d[(size_t)row * D_INNER + ncol] = f2bf(acc[i][j][reg]);
                }
            }
        }
    } else {
        (void)o0; (void)o1;
        float* d = Pp + (size_t)kz * MROWS * D_MODEL;
#pragma unroll
        for (int i = 0; i < 4; i++) {
            const int rbase = m0 + (i >> 1) * 128 + wr * 64 + (i & 1) * 32 + lhi * 4;
#pragma unroll
            for (int j = 0; j < 2; j++) {
                const int ncol = n0 + j * 128 + wc * 32 + l31;
#pragma unroll
                for (int reg = 0; reg < 16; reg++) {
                    const int row = rbase + (reg & 3) + ((reg >> 2) << 3);
                    d[(size_t)row * D_MODEL + ncol] = acc[i][j][reg];
                }
            }
        }
    }
#undef STAGE_A
#undef STAGE_B
#undef LOADA
#undef LOADB
#undef MFMAQ
#undef VMW
#undef BARX
#undef SANDWICH
}

// ---------------------------------------------------------------------------
// reduce split-K partials -> out, float4-vectorized (4 elems/thread).
__global__ __launch_bounds__(256) void reduce_out(const float* __restrict__ Pp, void* __restrict__ out,
                                                  const int* __restrict__ flag) {
    int i = (blockIdx.x * 256 + threadIdx.x) * 4;   // < MROWS*D_MODEL
    float4 s = *(const float4*)&Pp[i];
#pragma unroll
    for (int z = 1; z < KSP6; z++) {
        float4 p = *(const float4*)&Pp[(size_t)z * MROWS * D_MODEL + i];
        s.x += p.x; s.y += p.y; s.z += p.z; s.w += p.w;
    }
    if (*flag) {
        ushort4 o = make_ushort4(f2bf(s.x), f2bf(s.y), f2bf(s.z), f2bf(s.w));
        *(ushort4*)((u16*)out + i) = o;
    } else {
        *(float4*)((float*)out + i) = s;
    }
}

// ---------------------------------------------------------------------------
// K3: proj split-K MFMA.  A = xs [4096][4096], Bt = xpwT [128(pad)][4096].
__global__ __launch_bounds__(256) void gemm_proj(const u16* __restrict__ A, const u16* __restrict__ Bt,
                                                 float* __restrict__ Pp) {
    const int K = D_INNER;
    __shared__ __align__(16) u16 sA[128 * 32];
    __shared__ __align__(16) u16 sB[128 * 32];
    int tid = threadIdx.x;
    int lane = tid & 63;
    int wave = tid >> 6;
    int wm = (wave >> 1) * 64, wn = (wave & 1) * 64;
    int quad = lane >> 4, l15 = lane & 15;
    int m0 = blockIdx.y * 128;
    int kz = blockIdx.x;
    int kbase = kz * (K / KSPLIT);

    floatx4 acc[4][4];
#pragma unroll
    for (int i = 0; i < 4; i++)
#pragma unroll
        for (int j = 0; j < 4; j++) acc[i][j] = (floatx4)0.f;

    const u16* ga0 = A + (size_t)(m0 + (tid >> 2)) * K + (tid & 3) * 8;
    const u16* ga1 = A + (size_t)(m0 + 64 + (tid >> 2)) * K + (tid & 3) * 8;
    const u16* gb0 = Bt + (size_t)(tid >> 2) * K + (tid & 3) * 8;
    const u16* gb1 = Bt + (size_t)(64 + (tid >> 2)) * K + (tid & 3) * 8;
    u16* la0 = &sA[tid * 8];
    u16* la1 = &sA[(256 + tid) * 8];
    u16* lb0 = &sB[tid * 8];
    u16* lb1 = &sB[(256 + tid) * 8];

    for (int k0 = kbase; k0 < kbase + K / KSPLIT; k0 += 32) {
        async_cp16(ga0 + k0, la0);
        async_cp16(ga1 + k0, la1);
        async_cp16(gb0 + k0, lb0);
        async_cp16(gb1 + k0, lb1);
        __syncthreads();
        short8 af[4], bf[4];
#pragma unroll
        for (int i = 0; i < 4; i++) {
            af[i] = *(const short8*)&sA[(wm + i * 16 + l15) * 32 + quad * 8];
            bf[i] = *(const short8*)&sB[(wn + i * 16 + l15) * 32 + quad * 8];
        }
#pragma unroll
        for (int i = 0; i < 4; i++)
#pragma unroll
            for (int j = 0; j < 4; j++)
                acc[i][j] = __builtin_amdgcn_mfma_f32_16x16x32_bf16(af[i], bf[j], acc[i][j], 0, 0, 0);
        __syncthreads();
    }

    float* d = Pp + (size_t)kz * MROWS * PST;
#pragma unroll
    for (int i = 0; i < 4; i++)
#pragma unroll
        for (int j = 0; j < 4; j++)
#pragma unroll
            for (int r = 0; r < 4; r++) {
                int mm = m0 + wm + i * 16 + quad * 4 + r;
                int nn = wn + j * 16 + l15;
                d[(size_t)mm * PST + nn] = acc[i][j][r];
            }
}

// ---------------------------------------------------------------------------
// reduce split-K partials -> proj fp32 [4096][PST]; also emit proj_lo bf16.
__global__ __launch_bounds__(256) void reduce_proj(const float* __restrict__ Pp, float* __restrict__ proj,
                                                   u16* __restrict__ proj_lo) {
    int i = blockIdx.x * 256 + threadIdx.x;    // < MROWS*PST
    float s = 0.f;
#pragma unroll
    for (int z = 0; z < KSPLIT; z++) s += Pp[(size_t)z * MROWS * PST + i];
    proj[i] = s;
    int col = i & (PST - 1);
    if (col < DT_RANK) proj_lo[(size_t)(i >> 7) * DT_RANK + col] = f2bf(s);
}

// ---------------------------------------------------------------------------
// K4: dt = softplus(proj_lo @ dtwT^T + b) via MFMA.  M=4096, N=4096, K=64.
// Epilogue: fast softplus + LDS bounce (stride-132 pad) -> coalesced 16B stores.
__global__ __launch_bounds__(256) void gemm_dt(const u16* __restrict__ A, const u16* __restrict__ Bt,
                                               const u16* __restrict__ dtb, u16* __restrict__ dt) {
    const int K = DT_RANK;   // 64
    __shared__ __align__(16) u16 smem[64 * 132];   // 16.9 KB; k-loop uses first 16 KB
    u16* sA = smem;
    u16* sB = smem + 128 * 32;
    int tid = threadIdx.x;
    int lane = tid & 63;
    int wave = tid >> 6;
    int wm = (wave >> 1) * 64, wn = (wave & 1) * 64;
    int quad = lane >> 4, l15 = lane & 15;
    int m0 = blockIdx.y * 128, n0 = blockIdx.x * 128;

    floatx4 acc[4][4];
#pragma unroll
    for (int i = 0; i < 4; i++)
#pragma unroll
        for (int j = 0; j < 4; j++) acc[i][j] = (floatx4)0.f;

    const u16* ga0 = A + (size_t)(m0 + (tid >> 2)) * K + (tid & 3) * 8;
    const u16* ga1 = A + (size_t)(m0 + 64 + (tid >> 2)) * K + (tid & 3) * 8;
    const u16* gb0 = Bt + (size_t)(n0 + (tid >> 2)) * K + (tid & 3) * 8;
    const u16* gb1 = Bt + (size_t)(n0 + 64 + (tid >> 2)) * K + (tid & 3) * 8;
    u16* la0 = &sA[tid * 8];
    u16* la1 = &sA[(256 + tid) * 8];
    u16* lb0 = &sB[tid * 8];
    u16* lb1 = &sB[(256 + tid) * 8];

    for (int k0 = 0; k0 < K; k0 += 32) {
        async_cp16(ga0 + k0, la0);
        async_cp16(ga1 + k0, la1);
        async_cp16(gb0 + k0, lb0);
        async_cp16(gb1 + k0, lb1);
        __syncthreads();
        short8 af[4], bf[4];
#pragma unroll
        for (int i = 0; i < 4; i++) {
            af[i] = *(const short8*)&sA[(wm + i * 16 + l15) * 32 + quad * 8];
            bf[i] = *(const short8*)&sB[(wn + i * 16 + l15) * 32 + quad * 8];
        }
#pragma unroll
        for (int i = 0; i < 4; i++)
#pragma unroll
            for (int j = 0; j < 4; j++)
                acc[i][j] = __builtin_amdgcn_mfma_f32_16x16x32_bf16(af[i], bf[j], acc[i][j], 0, 0, 0);
        __syncthreads();
    }

#pragma unroll
    for (int h = 0; h < 2; h++) {
        __syncthreads();
        if (wm == h * 64) {
#pragma unroll
            for (int j = 0; j < 4; j++) {
                int col = wn + j * 16 + l15;
                float b = bf2f(dtb[n0 + col]);
#pragma unroll
                for (int i = 0; i < 4; i++)
#pragma unroll
                    for (int r = 0; r < 4; r++) {
                        int row = i * 16 + quad * 4 + r;   // 0..63 within half
                        smem[row * 132 + col] = f2bf(softplus_fast(acc[i][j][r] + b));
                    }
            }
        }
        __syncthreads();
#pragma unroll
        for (int p = 0; p < 4; p++) {
            int row = p * 16 + (tid >> 4);
            int chunk = tid & 15;
            uint4 v = *(const uint4*)&smem[row * 132 + chunk * 8];
            *(uint4*)&dt[(size_t)(m0 + h * 64 + row) * D_INNER + n0 + chunk * 8] = v;
        }
    }
}

// ---------------------------------------------------------------------------
// K2: causal depthwise conv1d + silu, vectorized: 8 channels/thread (16B I/O).
__global__ __launch_bounds__(256) void conv_silu(const u16* __restrict__ xc, const u16* __restrict__ cw,
                                                 const u16* __restrict__ cb, u16* __restrict__ xs) {
    int idx = blockIdx.x * 256 + threadIdx.x;       // < MROWS * D_INNER/8
    int g = idx & (D_INNER / 8 - 1);                // channel-group
    int bt = idx >> 9;                              // b*SEQLEN + t
    int t = bt & (SEQLEN - 1);
    int d0 = g * 8;
    size_t row = (size_t)bt * D_INNER + d0;
    u16 wv[32];
    *(uint4*)&wv[0]  = *(const uint4*)&cw[d0 * 4];
    *(uint4*)&wv[8]  = *(const uint4*)&cw[d0 * 4 + 8];
    *(uint4*)&wv[16] = *(const uint4*)&cw[d0 * 4 + 16];
    *(uint4*)&wv[24] = *(const uint4*)&cw[d0 * 4 + 24];
    u16 cbv[8];
    *(uint4*)&cbv[0] = *(const uint4*)&cb[d0];
    u16 x0[8] = {0, 0, 0, 0, 0, 0, 0, 0};
    u16 x1[8] = {0, 0, 0, 0, 0, 0, 0, 0};
    u16 x2[8] = {0, 0, 0, 0, 0, 0, 0, 0};
    u16 x3[8];
    if (t >= 3) *(uint4*)x0 = *(const uint4*)&xc[row - 3 * (size_t)D_INNER];
    if (t >= 2) *(uint4*)x1 = *(const uint4*)&xc[row - 2 * (size_t)D_INNER];
    if (t >= 1) *(uint4*)x2 = *(const uint4*)&xc[row - 1 * (size_t)D_INNER];
    *(uint4*)x3 = *(const uint4*)&xc[row];
    u16 out[8];
#pragma unroll
    for (int ch = 0; ch < 8; ch++) {
        float a = bf2f(cbv[ch]);
        a += bf2f(x0[ch]) * bf2f(wv[ch * 4 + 0]);
        a += bf2f(x1[ch]) * bf2f(wv[ch * 4 + 1]);
        a += bf2f(x2[ch]) * bf2f(wv[ch * 4 + 2]);
        a += bf2f(x3[ch]) * bf2f(wv[ch * 4 + 3]);
        out[ch] = f2bf(a * sigmoid_fast(a));
    }
    *(uint4*)&xs[row] = *(const uint4*)&out[0];
}

// ---------------------------------------------------------------------------
// K5a: chunked scan phase 1 — per (b,d,chunk) thread, 16 states in registers.
// Structured-A fast path (sflag==0): dA[n] = r^(n+1), r = exp2(-dt*log2e):
// 1 trans + 16 full-rate muls replaces 16 quarter-rate v_exp per step.
// B row wave-uniform -> direct global; dt/xs streams prefetched 1 ahead.
__global__ __launch_bounds__(256) void scan_phase1(const float* __restrict__ proj, const u16* __restrict__ dt,
                                                   const float* __restrict__ A, const u16* __restrict__ xs,
                                                   float* __restrict__ hloc, float* __restrict__ Ssum,
                                                   const int* __restrict__ sflag) {
    int d = blockIdx.x * 256 + threadIdx.x;
    int c = blockIdx.y, b = blockIdx.z;
    int t0 = c * TC;
    int structured = (*sflag == 0);
    float h[16];
#pragma unroll
    for (int n = 0; n < 16; n++) h[n] = 0.f;
    float S = 0.f;
    size_t base = ((size_t)b * SEQLEN + t0) * D_INNER + d;
    const float* prow = proj + ((size_t)b * SEQLEN + t0) * PST + DT_RANK;
    u16 dcur = dt[base], ucur = xs[base];
    if (structured) {
        for (int t = 0; t < TC; t++) {
            size_t nidx = base + (size_t)((t + 1 < TC) ? t + 1 : t) * D_INNER;
            u16 dnxt = dt[nidx];
            u16 unxt = xs[nidx];
            float4 B0 = *(const float4*)(prow + t * PST + 0);
            float4 B1 = *(const float4*)(prow + t * PST + 4);
            float4 B2 = *(const float4*)(prow + t * PST + 8);
            float4 B3 = *(const float4*)(prow + t * PST + 12);
            float dtv = bf2f(dcur), u = bf2f(ucur);
            S += dtv;
            float du = dtv * u;
            float Bf[16] = {B0.x, B0.y, B0.z, B0.w, B1.x, B1.y, B1.z, B1.w,
                            B2.x, B2.y, B2.z, B2.w, B3.x, B3.y, B3.z, B3.w};
            float pw[16];
            pow_tree16(exp2_hw(-LOG2E * dtv), pw);
#pragma unroll
            for (int n = 0; n < 16; n++)
                h[n] = h[n] * pw[n] + du * Bf[n];
            dcur = dnxt; ucur = unxt;
        }
    } else {
        float Areg[16];   // prescaled by log2e for raw v_exp_f32
        const float4* Ap = (const float4*)(A + (size_t)d * 16);
#pragma unroll
        for (int n = 0; n < 4; n++) {
            float4 v = Ap[n];
            Areg[n * 4 + 0] = v.x * LOG2E; Areg[n * 4 + 1] = v.y * LOG2E;
            Areg[n * 4 + 2] = v.z * LOG2E; Areg[n * 4 + 3] = v.w * LOG2E;
        }
        for (int t = 0; t < TC; t++) {
            size_t nidx = base + (size_t)((t + 1 < TC) ? t + 1 : t) * D_INNER;
            u16 dnxt = dt[nidx];
            u16 unxt = xs[nidx];
            float4 B0 = *(const float4*)(prow + t * PST + 0);
            float4 B1 = *(const float4*)(prow + t * PST + 4);
            float4 B2 = *(const float4*)(prow + t * PST + 8);
            float4 B3 = *(const float4*)(prow + t * PST + 12);
            float dtv = bf2f(dcur), u = bf2f(ucur);
            S += dtv;
            float du = dtv * u;
            float Bf[16] = {B0.x, B0.y, B0.z, B0.w, B1.x, B1.y, B1.z, B1.w,
                            B2.x, B2.y, B2.z, B2.w, B3.x, B3.y, B3.z, B3.w};
#pragma unroll
            for (int n = 0; n < 16; n++)
                h[n] = h[n] * exp2_hw(dtv * Areg[n]) + du * Bf[n];
            dcur = dnxt; ucur = unxt;
        }
    }
    float* hp = &hloc[(((size_t)b * NC + c) * D_INNER + d) * 16];
#pragma unroll
    for (int n = 0; n < 16; n += 4)
        *(float4*)&hp[n] = make_float4(h[n], h[n + 1], h[n + 2], h[n + 3]);
    Ssum[((size_t)b * NC + c) * D_INNER + d] = S;
}

// ---------------------------------------------------------------------------
// K5b: combine chunks serially (in place: hloc becomes h_init per chunk).
__global__ __launch_bounds__(256) void scan_phase2(const float* __restrict__ A, const float* __restrict__ Ssum,
                                                   float* __restrict__ hloc) {
    int tid = blockIdx.x * 256 + threadIdx.x;
    int n = tid & 15;
    int d = (tid >> 4) & (D_INNER - 1);
    int b = tid >> 16;
    float An2 = A[d * 16 + n] * LOG2E;
    float h = 0.f;
    for (int c = 0; c < NC; c++) {
        size_t idx = (((size_t)b * NC + c) * D_INNER + d) * 16 + n;
        float hl = hloc[idx];
        float S = Ssum[((size_t)b * NC + c) * D_INNER + d];
        hloc[idx] = h;
        h = hl + h * exp2_hw(An2 * S);
    }
}

// ---------------------------------------------------------------------------
// K5c: phase 3 — rerun chunk with h_init, compute y, D-residual, silu(z) gate.
// Structured-A fast path as phase1. B/C rows wave-uniform -> direct global;
// dt/xs/z prefetched 1 ahead.
__global__ __launch_bounds__(256) void scan_phase3(const float* __restrict__ proj, const u16* __restrict__ dt,
                                                   const float* __restrict__ A, const u16* __restrict__ D16,
                                                   const float* __restrict__ hinit, const u16* __restrict__ z16,
                                                   u16* __restrict__ xs, const int* __restrict__ sflag) {
    int d = blockIdx.x * 256 + threadIdx.x;
    int c = blockIdx.y, b = blockIdx.z;
    int t0 = c * TC;
    int structured = (*sflag == 0);
    float h[16];
    {
        const float* hp = &hinit[(((size_t)b * NC + c) * D_INNER + d) * 16];
#pragma unroll
        for (int n = 0; n < 16; n += 4) {
            float4 v = *(const float4*)&hp[n];
            h[n] = v.x; h[n + 1] = v.y; h[n + 2] = v.z; h[n + 3] = v.w;
        }
    }
    float Dd = bf2f(D16[d]);
    size_t base = ((size_t)b * SEQLEN + t0) * D_INNER + d;
    const float* prow = proj + ((size_t)b * SEQLEN + t0) * PST + DT_RANK;
    u16 dcur = dt[base], ucur = xs[base], zcur = z16[base];
    if (structured) {
        for (int t = 0; t < TC; t++) {
            size_t nidx = base + (size_t)((t + 1 < TC) ? t + 1 : t) * D_INNER;
            u16 dnxt = dt[nidx];
            u16 unxt = xs[nidx];
            u16 znxt = z16[nidx];
            float4 B0 = *(const float4*)(prow + t * PST + 0);
            float4 B1 = *(const float4*)(prow + t * PST + 4);
            float4 B2 = *(const float4*)(prow + t * PST + 8);
            float4 B3 = *(const float4*)(prow + t * PST + 12);
            float4 C0 = *(const float4*)(prow + t * PST + 16);
            float4 C1 = *(const float4*)(prow + t * PST + 20);
            float4 C2 = *(const float4*)(prow + t * PST + 24);
            float4 C3 = *(const float4*)(prow + t * PST + 28);
            float dtv = bf2f(dcur), u = bf2f(ucur), zv = bf2f(zcur);
            float du = dtv * u;
            float Bf[16] = {B0.x, B0.y, B0.z, B0.w, B1.x, B1.y, B1.z, B1.w,
                            B2.x, B2.y, B2.z, B2.w, B3.x, B3.y, B3.z, B3.w};
            float Cf[16] = {C0.x, C0.y, C0.z, C0.w, C1.x, C1.y, C1.z, C1.w,
                            C2.x, C2.y, C2.z, C2.w, C3.x, C3.y, C3.z, C3.w};
            float pw[16];
            pow_tree16(exp2_hw(-LOG2E * dtv), pw);
            float y = 0.f;
#pragma unroll
            for (int n = 0; n < 16; n++) {
                h[n] = h[n] * pw[n] + du * Bf[n];
                y += h[n] * Cf[n];
            }
            float gate = zv * sigmoid_fast(zv);
            xs[base + (size_t)t * D_INNER] = f2bf((y + u * Dd) * gate);
            dcur = dnxt; ucur = unxt; zcur = znxt;
        }
    } else {
        float Areg[16];   // prescaled by log2e
        const float4* Ap = (const float4*)(A + (size_t)d * 16);
#pragma unroll
        for (int n = 0; n < 4; n++) {
            float4 v = Ap[n];
            Areg[n * 4 + 0] = v.x * LOG2E; Areg[n * 4 + 1] = v.y * LOG2E;
            Areg[n * 4 + 2] = v.z * LOG2E; Areg[n * 4 + 3] = v.w * LOG2E;
        }
        for (int t = 0; t < TC; t++) {
            size_t nidx = base + (size_t)((t + 1 < TC) ? t + 1 : t) * D_INNER;
            u16 dnxt = dt[nidx];
            u16 unxt = xs[nidx];
            u16 znxt = z16[nidx];
            float4 B0 = *(const float4*)(prow + t * PST + 0);
            float4 B1 = *(const float4*)(prow + t * PST + 4);
            float4 B2 = *(const float4*)(prow + t * PST + 8);
            float4 B3 = *(const float4*)(prow + t * PST + 12);
            float4 C0 = *(const float4*)(prow + t * PST + 16);
            float4 C1 = *(const float4*)(prow + t * PST + 20);
            float4 C2 = *(const float4*)(prow + t * PST + 24);
            float4 C3 = *(const float4*)(prow + t * PST + 28);
            float dtv = bf2f(dcur), u = bf2f(ucur), zv = bf2f(zcur);
            float du = dtv * u;
            float Bf[16] = {B0.x, B0.y, B0.z, B0.w, B1.x, B1.y, B1.z, B1.w,
                            B2.x, B2.y, B2.z, B2.w, B3.x, B3.y, B3.z, B3.w};
            float Cf[16] = {C0.x, C0.y, C0.z, C0.w, C1.x, C1.y, C1.z, C1.w,
                            C2.x, C2.y, C2.z, C2.w, C3.x, C3.y, C3.z, C3.w};
            float y = 0.f;
#pragma unroll
            for (int n = 0; n < 16; n++) {
                h[n] = h[n] * exp2_hw(dtv * Areg[n]) + du * Bf[n];
                y += h[n] * Cf[n];
            }
            float gate = zv * sigmoid_fast(zv);
            xs[base + (size_t)t * D_INNER] = f2bf((y + u * Dd) * gate);
            dcur = dnxt; ucur = unxt; zcur = znxt;
        }
    }
}

// ---------------------------------------------------------------------------
extern "C" void kernel_launch(void* const* d_in, const int* in_sizes, int n_in,
                              void* d_out, int out_size, void* d_ws, size_t ws_size,
                              hipStream_t stream) {
    const void* x          = d_in[0];
    const void* in_proj_w  = d_in[1];
    const void* conv_w     = d_in[2];
    const void* conv_b     = d_in[3];
    const void* x_proj_w   = d_in[4];
    const void* dt_proj_w  = d_in[5];
    const void* dt_proj_b  = d_in[6];
    const void* A_log      = d_in[7];
    const void* Dvec       = d_in[8];
    const void* out_proj_w = d_in[9];

    char* w = (char*)d_ws;
    const size_t MB = 1024 * 1024;
    const size_t KB = 1024;
    // Overlay plan (stream order guarantees safety):
    //   5-37 MB  : xc (K1 out, dead after conv) -> dt16 -> Pp6 lower half
    //  37-69 MB  : z (dead after scan_phase3)   -> Pp6 upper half
    //  69-101 MB : xs (conv out) -> gated y (K6 A operand)
    // 101-126 MB : x16+ipwT (dead after K1) -> Pp (dead after reduce) -> hloc
    int*   flag    = (int*)(w + 0);
    int*   sflag   = (int*)(w + 16);                // A-structure flag (0 = structured)
    float* Aws     = (float*)(w + 1 * KB);          // 256 KB
    float* proj    = (float*)(w + 1 * MB);          // 2 MB fp32 [4096][PST=128]
    u16*   cw16    = (u16*)(w + 3 * MB);            // 32 KB
    u16*   cb16    = (u16*)(w + 3 * MB + 64 * KB);  // 8 KB
    u16*   dtb16   = (u16*)(w + 3 * MB + 128 * KB); // 8 KB
    u16*   D16     = (u16*)(w + 3 * MB + 192 * KB); // 8 KB
    u16*   proj_lo = (u16*)(w + 3 * MB + 512 * KB); // 512 KB bf16 [4096][64]
    u16*   dtwT    = (u16*)(w + 4 * MB);            // 512 KB bf16 [4096][64]
    u16*   buf1    = (u16*)(w + 5 * MB);            // 32 MB: xc then dt16
    u16*   dt16    = buf1;
    u16*   zbuf    = (u16*)(w + 37 * MB);           // 32 MB: z
    float* Pp6     = (float*)(w + 5 * MB);          // 64 MB: K6 partials (post-scan)
    u16*   xs      = (u16*)(w + 69 * MB);           // 32 MB: xs then gated y
    u16*   x16     = (u16*)(w + 101 * MB);          // 8.4 MB  (dead after K1)
    u16*   ipwT    = (u16*)(w + 110 * MB);          // 16.8 MB (dead after K1)
    float* Pp      = (float*)(w + 101 * MB);        // 16 MB (post-K1, dead after reduce)
    float* hloc    = (float*)(w + 101 * MB);        // 16 MB (post-reduce, NC=32)
    float* Ssum    = (float*)(w + 117 * MB);        // 1 MB  (post-K1)
    u16*   opwT    = (u16*)(w + 127 * MB);          // 8.4 MB: out_proj_w^T [1024][4096]
    u16*   xpwT    = (u16*)(w + 136 * MB);          // 1 MB: x_proj_w^T [96(pad128)][4096]
    // total 137 MB (<150 MB proven available)

    detect_dtype<<<dim3(1), dim3(256), 0, stream>>>((const u16*)x, flag, sflag);
    prep_small<<<dim3(256), dim3(256), 0, stream>>>(conv_w, conv_b, dt_proj_b, Dvec, A_log,
                                                    cw16, cb16, dtb16, D16, Aws, flag, sflag);
    ingest16<<<dim3(MROWS * D_MODEL / 256), dim3(256), 0, stream>>>(x, x16, MROWS * D_MODEL, flag);
    transpose_w<<<dim3(2 * D_INNER / 32, D_MODEL / 32), dim3(256), 0, stream>>>(in_proj_w, ipwT, D_MODEL, 2 * D_INNER, flag);
    transpose_w<<<dim3(D_MODEL / 32, D_INNER / 32), dim3(256), 0, stream>>>(out_proj_w, opwT, D_INNER, D_MODEL, flag);
    transpose_w<<<dim3(NPROJ / 32, D_INNER / 32), dim3(256), 0, stream>>>(x_proj_w, xpwT, D_INNER, NPROJ, flag);
    transpose_w<<<dim3(D_INNER / 32, DT_RANK / 32), dim3(256), 0, stream>>>(dt_proj_w, dtwT, DT_RANK, D_INNER, flag);

    // K1: xz = x @ Win -> xc (buf1) + z (zbuf); 256^2-tile, 32x32 MFMA, 512 blocks
    gemm8p<1024, 0><<<dim3(512), dim3(512), 0, stream>>>(x16, ipwT, buf1, zbuf, nullptr);
    // K2: conv + silu -> xs (8 channels/thread, 16B vector I/O)
    conv_silu<<<dim3(MROWS * D_INNER / 8 / 256), dim3(256), 0, stream>>>(buf1, cw16, cb16, xs);
    // K3: proj via split-K MFMA + reduce (also emits proj_lo bf16)
    gemm_proj<<<dim3(KSPLIT, MROWS / 128), dim3(256), 0, stream>>>(xs, xpwT, Pp);
    reduce_proj<<<dim3(MROWS * PST / 256), dim3(256), 0, stream>>>(Pp, proj, proj_lo);
    // K4: dt via MFMA, fused bias+fast-softplus (dt16 overlays dead xc)
    gemm_dt<<<dim3(D_INNER / 128, MROWS / 128), dim3(256), 0, stream>>>(proj_lo, dtwT, dtb16, dt16);
    // K5: chunked scan (structured-A powering fast path; uniform B/C reads)
    scan_phase1<<<dim3(D_INNER / 256, NC, BATCH), dim3(256), 0, stream>>>(proj, dt16, Aws, xs, hloc, Ssum, sflag);
    scan_phase2<<<dim3(BATCH * D_INNER * D_STATE / 256), dim3(256), 0, stream>>>(Aws, Ssum, hloc);
    scan_phase3<<<dim3(D_INNER / 256, NC, BATCH), dim3(256), 0, stream>>>(proj, dt16, Aws, D16, hloc, zbuf, xs, sflag);
    // K6: out = y @ out_proj_w; 256^2-tile 32x32-MFMA split-K (dt16/zbuf dead -> Pp6) + reduce
    gemm8p<4096, 1><<<dim3(D_MODEL / 256, MROWS / 256, KSP6), dim3(512), 0, stream>>>(xs, opwT, nullptr, nullptr, Pp6);
    reduce_out<<<dim3(MROWS * D_MODEL / 1024), dim3(256), 0, stream>>>(Pp6, d_out, flag);
}